// Round 3
// baseline (4075.731 us; speedup 1.0000x reference)
//
#include <hip/hip_runtime.h>
#include <hip/hip_bf16.h>
#include <cstdint>
#include <cstddef>

typedef unsigned short u16;

__device__ __forceinline__ float b2f(u16 u){
  union { uint32_t i; float f; } x; x.i = ((uint32_t)u) << 16; return x.f;
}
__device__ __forceinline__ u16 f2b(float f){
  uint32_t i = __float_as_uint(f);
  uint32_t r = (i + 0x7FFFu + ((i >> 16) & 1u)) >> 16;   // round-nearest-even
  return (u16)r;
}

// dtype-dual loads: isf32 ? fp32 : bf16, both return fp32
__device__ __forceinline__ float load1(const void* p, size_t i, int isf32){
  return isf32 ? ((const float*)p)[i] : b2f(((const u16*)p)[i]);
}
__device__ __forceinline__ float4 load4(const void* p, size_t i, int isf32){
  if (isf32) return *reinterpret_cast<const float4*>((const float*)p + i);
  ushort4 u = *reinterpret_cast<const ushort4*>((const u16*)p + i);
  return make_float4(b2f(u.x), b2f(u.y), b2f(u.z), b2f(u.w));
}

// ---- dtype detector: bits[14:7] of u32 words. bf16 pair -> low elem's exponent
// (never 0x00/0xFF for N(0,1) data); fp32 -> mantissa bits (~uniform). ----
__global__ __launch_bounds__(256) void detect_k(const uint32_t* __restrict__ w,
                                                int* __restrict__ flag){
  __shared__ int hits;
  if (threadIdx.x == 0) hits = 0;
  __syncthreads();
  int h = 0;
  for (int i = threadIdx.x; i < 262144; i += 256){
    uint32_t e = (w[i] >> 7) & 0xFFu;
    h += (e == 0u || e == 0xFFu) ? 1 : 0;
  }
  atomicAdd(&hits, h);
  __syncthreads();
  if (threadIdx.x == 0) *flag = (hits > 16) ? 1 : 0;   // 1 = fp32 inputs
}

// ---- block-wide sum over 256 threads (4 waves) ----
__device__ __forceinline__ float block_sum256(float v, float* sh){
  #pragma unroll
  for (int o = 32; o > 0; o >>= 1) v += __shfl_down(v, o);
  __syncthreads();
  if ((threadIdx.x & 63u) == 0) sh[threadIdx.x >> 6] = v;
  __syncthreads();
  return sh[0] + sh[1] + sh[2] + sh[3];
}

// ---- per-row LN stats of visual_feat, in rearranged row order ----
// out row r = bt*256 + nn  <->  vf row = nn*128 + bt
__global__ __launch_bounds__(256) void stats_x_k(
    const void* __restrict__ vf, float2* __restrict__ st, const int* __restrict__ dtf)
{
  __shared__ float sh[4];
  const int isf32 = *dtf;
  const int r  = blockIdx.x;
  const int nn = r & 255, bt = r >> 8;
  const size_t base = ((size_t)nn * 128 + bt) * 768;
  const int t = threadIdx.x;
  float v0 = load1(vf, base + t, isf32);
  float v1 = load1(vf, base + t + 256, isf32);
  float v2 = load1(vf, base + t + 512, isf32);
  float mean = block_sum256(v0 + v1 + v2, sh) * (1.0f / 768.0f);
  float d0 = v0 - mean, d1 = v1 - mean, d2 = v2 - mean;
  float var = block_sum256(d0*d0 + d1*d1 + d2*d2, sh) * (1.0f / 768.0f);
  if (t == 0) st[r] = make_float2(mean, rsqrtf(var + 1e-5f));
}

// ---- double LayerNorm of latents: ll = LN_pl(LN_nl0(latents)), rows = 8*64 ----
__global__ __launch_bounds__(256) void ln_lat2_k(
    const void* __restrict__ lat, u16* __restrict__ ll,
    const void* __restrict__ g0, const void* __restrict__ b0,
    const void* __restrict__ g1, const void* __restrict__ b1,
    const int* __restrict__ dtf)
{
  __shared__ float sh[4];
  const int isf32 = *dtf;
  const int r = blockIdx.x;
  const int t = threadIdx.x;
  const size_t base = (size_t)r * 768;
  float v[3];
  #pragma unroll
  for (int i = 0; i < 3; i++) v[i] = load1(lat, base + t + 256 * i, isf32);
  #pragma unroll
  for (int pass = 0; pass < 2; ++pass){
    float mean = block_sum256(v[0] + v[1] + v[2], sh) * (1.0f / 768.0f);
    float d0 = v[0] - mean, d1 = v[1] - mean, d2 = v[2] - mean;
    float var = block_sum256(d0*d0 + d1*d1 + d2*d2, sh) * (1.0f / 768.0f);
    float rs = rsqrtf(var + 1e-5f);
    const void* g = pass ? g1 : g0;
    const void* b = pass ? b1 : b0;
    #pragma unroll
    for (int i = 0; i < 3; i++){
      int c = t + 256 * i;
      v[i] = (v[i] - mean) * rs * load1(g, c, isf32) + load1(b, c, isf32);
    }
  }
  #pragma unroll
  for (int i = 0; i < 3; i++) ll[base + t + 256 * i] = f2b(v[i]);
}

// ---- LN of fp32 ws rows -> bf16 ----
__global__ __launch_bounds__(256) void ln_f32_k(
    const float* __restrict__ y, u16* __restrict__ z,
    const void* __restrict__ g, const void* __restrict__ b,
    const int* __restrict__ dtf)
{
  __shared__ float sh[4];
  const int isf32 = *dtf;
  const int r = blockIdx.x;
  const float* in = y + (size_t)r * 768;
  const int t = threadIdx.x;
  float v[3];
  #pragma unroll
  for (int i = 0; i < 3; i++) v[i] = in[t + 256 * i];
  float mean = block_sum256(v[0] + v[1] + v[2], sh) * (1.0f / 768.0f);
  float d0 = v[0] - mean, d1 = v[1] - mean, d2 = v[2] - mean;
  float var = block_sum256(d0*d0 + d1*d1 + d2*d2, sh) * (1.0f / 768.0f);
  float rs = rsqrtf(var + 1e-5f);
  #pragma unroll
  for (int i = 0; i < 3; i++){
    int c = t + 256 * i;
    z[(size_t)r * 768 + c] = f2b((v[i] - mean) * rs * load1(g, c, isf32) + load1(b, c, isf32));
  }
}

// ---- generic tiled GEMM: C[M,N] = act(scale*A@B + bias) + addsrc ----
// B/bias always external (dtype per flag). A: a_ext ? external : ws bf16.
// Ast path: LN A rows on the fly + vf row remap (gm&255)*128+(gm>>8).
// rowperm: out row = (gm&63)*128 + (gm>>6). outmode: 0=f32, 1=bf16, 2=flag.
__global__ __launch_bounds__(256) void gemm_k(
    const void* __restrict__ A, const void* __restrict__ B, void* C,
    int M, int N, int K, float scale,
    const void* __restrict__ bias, int act,
    const float* addsrc, int rowperm, int outmode,
    const float2* __restrict__ Ast, const void* __restrict__ Ag,
    const void* __restrict__ Abeta, int a_ext, const int* __restrict__ dtf)
{
  __shared__ float As[16][65];
  __shared__ float Bs[16][65];
  const int isf32 = *dtf;
  const int a32 = a_ext ? isf32 : 0;
  const int nb = N >> 6;
  const int bx = blockIdx.x % nb;
  const int by = blockIdx.x / nb;
  const int tid = threadIdx.x;
  const int m0 = (tid >> 4) * 4, n0 = (tid & 15) * 4;
  const int arow = tid >> 2, acol = (tid & 3) * 4;
  const int brow = tid >> 4, bcol = (tid & 15) * 4;
  const int gmr = by * 64 + arow;
  const int asrc = Ast ? ((gmr & 255) * 128 + (gmr >> 8)) : gmr;
  float amean = 0.0f, arstd = 1.0f;
  if (Ast){ float2 s = Ast[gmr]; amean = s.x; arstd = s.y; }
  float acc[4][4] = {};
  for (int k0 = 0; k0 < K; k0 += 16){
    float4 a4 = load4(A, (size_t)asrc * K + acol + k0, a32);
    float4 b4 = load4(B, (size_t)(brow + k0) * N + bx * 64 + bcol, isf32);
    if (Ast){
      float4 gv = load4(Ag, (size_t)(k0 + acol), isf32);
      float4 be = load4(Abeta, (size_t)(k0 + acol), isf32);
      a4.x = (a4.x - amean) * arstd * gv.x + be.x;
      a4.y = (a4.y - amean) * arstd * gv.y + be.y;
      a4.z = (a4.z - amean) * arstd * gv.z + be.z;
      a4.w = (a4.w - amean) * arstd * gv.w + be.w;
    }
    As[acol + 0][arow] = a4.x; As[acol + 1][arow] = a4.y;
    As[acol + 2][arow] = a4.z; As[acol + 3][arow] = a4.w;
    Bs[brow][bcol + 0] = b4.x; Bs[brow][bcol + 1] = b4.y;
    Bs[brow][bcol + 2] = b4.z; Bs[brow][bcol + 3] = b4.w;
    __syncthreads();
    #pragma unroll
    for (int k = 0; k < 16; k++){
      float a0_ = As[k][m0+0], a1_ = As[k][m0+1], a2_ = As[k][m0+2], a3_ = As[k][m0+3];
      float c0_ = Bs[k][n0+0], c1_ = Bs[k][n0+1], c2_ = Bs[k][n0+2], c3_ = Bs[k][n0+3];
      acc[0][0] += a0_*c0_; acc[0][1] += a0_*c1_; acc[0][2] += a0_*c2_; acc[0][3] += a0_*c3_;
      acc[1][0] += a1_*c0_; acc[1][1] += a1_*c1_; acc[1][2] += a1_*c2_; acc[1][3] += a1_*c3_;
      acc[2][0] += a2_*c0_; acc[2][1] += a2_*c1_; acc[2][2] += a2_*c2_; acc[2][3] += a2_*c3_;
      acc[3][0] += a3_*c0_; acc[3][1] += a3_*c1_; acc[3][2] += a3_*c2_; acc[3][3] += a3_*c3_;
    }
    __syncthreads();
  }
  const int f32out = (outmode == 0) || (outmode == 2 && isf32);
  #pragma unroll
  for (int ii = 0; ii < 4; ii++){
    int gm = by * 64 + m0 + ii;
    int orow = rowperm ? ((gm & 63) * 128 + (gm >> 6)) : gm;
    #pragma unroll
    for (int jj = 0; jj < 4; jj++){
      int gn = bx * 64 + n0 + jj;
      float v = acc[ii][jj] * scale;
      if (bias) v += load1(bias, gn, isf32);
      if (act)  v = v * (1.0f / (1.0f + expf(-1.702f * v)));   // QuickGELU
      if (addsrc) v += addsrc[(size_t)orow * N + gn];
      if (f32out) ((float*)C)[(size_t)orow * N + gn] = v;
      else        ((u16*)C)[(size_t)orow * N + gn] = f2b(v);
    }
  }
}

// ---- Perceiver attention: one block per (b,t,head); 64 q rows, 320 keys ----
__global__ __launch_bounds__(256) void pattn_k(
    const float* __restrict__ q, const u16* __restrict__ kvx,
    const u16* __restrict__ kvll, u16* __restrict__ o)
{
  __shared__ float qs[64][65];
  __shared__ float ks[64][65];
  __shared__ float ps[64][64];
  const int blk = blockIdx.x;                  // ((bb*8+tt)*8+hh)
  const int hh = blk & 7, tt = (blk >> 3) & 7, bb = blk >> 6;
  const int bt = bb * 8 + tt;
  const int tid = threadIdx.x;
  const int i = tid >> 2;                      // q row 0..63
  const int c0 = (tid & 3) * 16;               // 16-wide column slice
  {
    const float* qr = q + ((size_t)(tt * 64 + i)) * 512 + hh * 64 + c0;
    #pragma unroll
    for (int c = 0; c < 16; c += 4){
      float4 t4 = *(const float4*)(qr + c);
      qs[i][c0+c+0] = t4.x * 0.125f; qs[i][c0+c+1] = t4.y * 0.125f;
      qs[i][c0+c+2] = t4.z * 0.125f; qs[i][c0+c+3] = t4.w * 0.125f;
    }
  }
  float m = -1e30f, l = 0.0f;
  float oacc[16];
  #pragma unroll
  for (int d = 0; d < 16; d++) oacc[d] = 0.0f;

  for (int ch = 0; ch < 5; ++ch){
    const int jg = ch * 64 + i;
    const u16* kbase = (jg < 256)
        ? (kvx  + ((size_t)bt * 256 + jg) * 1024 + hh * 64)
        : (kvll + ((size_t)tt * 64 + (jg - 256)) * 1024 + hh * 64);
    __syncthreads();
    #pragma unroll
    for (int c = 0; c < 16; c += 4){
      ushort4 k4 = *(const ushort4*)(kbase + c0 + c);
      ks[i][c0+c+0] = b2f(k4.x); ks[i][c0+c+1] = b2f(k4.y);
      ks[i][c0+c+2] = b2f(k4.z); ks[i][c0+c+3] = b2f(k4.w);
    }
    __syncthreads();
    float s[16];
    #pragma unroll
    for (int jj = 0; jj < 16; jj++){
      const int j = c0 + jj;
      float a = 0.0f;
      #pragma unroll
      for (int d = 0; d < 64; d++) a += qs[i][d] * ks[j][d];
      s[jj] = a;
    }
    float cm = s[0];
    #pragma unroll
    for (int jj = 1; jj < 16; jj++) cm = fmaxf(cm, s[jj]);
    cm = fmaxf(cm, __shfl_xor(cm, 1));
    cm = fmaxf(cm, __shfl_xor(cm, 2));
    const float mnew = fmaxf(m, cm);
    const float corr = expf(m - mnew);
    float psum = 0.0f;
    #pragma unroll
    for (int jj = 0; jj < 16; jj++){ s[jj] = expf(s[jj] - mnew); psum += s[jj]; }
    psum += __shfl_xor(psum, 1);
    psum += __shfl_xor(psum, 2);
    l = l * corr + psum;
    m = mnew;
    #pragma unroll
    for (int jj = 0; jj < 16; jj++) ps[i][c0 + jj] = s[jj];
    #pragma unroll
    for (int d = 0; d < 16; d++) oacc[d] *= corr;
    __syncthreads();
    const u16* vbase = (jg < 256)
        ? (kvx  + ((size_t)bt * 256 + jg) * 1024 + 512 + hh * 64)
        : (kvll + ((size_t)tt * 64 + (jg - 256)) * 1024 + 512 + hh * 64);
    #pragma unroll
    for (int c = 0; c < 16; c += 4){
      ushort4 v4 = *(const ushort4*)(vbase + c0 + c);
      ks[i][c0+c+0] = b2f(v4.x); ks[i][c0+c+1] = b2f(v4.y);
      ks[i][c0+c+2] = b2f(v4.z); ks[i][c0+c+3] = b2f(v4.w);
    }
    __syncthreads();
    #pragma unroll
    for (int j = 0; j < 64; j++){
      const float p = ps[i][j];
      #pragma unroll
      for (int d = 0; d < 16; d++) oacc[d] += p * ks[j][c0 + d];
    }
  }
  const float inv = 1.0f / l;
  u16* orow = o + ((size_t)bt * 64 + i) * 512 + hh * 64 + c0;
  #pragma unroll
  for (int d = 0; d < 16; d++) orow[d] = f2b(oacc[d] * inv);
}

// ---- self-attention: one block per (bt, head); seq=64, hd=64; qkv ws bf16 ----
__global__ __launch_bounds__(256) void sattn_k(
    const u16* __restrict__ qkv, u16* __restrict__ o2)
{
  __shared__ float qs[64][65];
  __shared__ float ks[64][65];
  __shared__ float ps[64][64];
  const int blk = blockIdx.x;
  const int hh = blk % 12;
  const int bt = blk / 12;
  const int tid = threadIdx.x;
  const int i = tid >> 2;
  const int c0 = (tid & 3) * 16;
  const u16* base = qkv + ((size_t)i * 128 + bt) * 2304 + hh * 64 + c0;
  #pragma unroll
  for (int c = 0; c < 16; c += 4){
    ushort4 t4 = *(const ushort4*)(base + c);
    qs[i][c0+c+0] = b2f(t4.x) * 0.125f; qs[i][c0+c+1] = b2f(t4.y) * 0.125f;
    qs[i][c0+c+2] = b2f(t4.z) * 0.125f; qs[i][c0+c+3] = b2f(t4.w) * 0.125f;
  }
  #pragma unroll
  for (int c = 0; c < 16; c += 4){
    ushort4 t4 = *(const ushort4*)(base + 768 + c);
    ks[i][c0+c+0] = b2f(t4.x); ks[i][c0+c+1] = b2f(t4.y);
    ks[i][c0+c+2] = b2f(t4.z); ks[i][c0+c+3] = b2f(t4.w);
  }
  __syncthreads();
  float s[16];
  #pragma unroll
  for (int jj = 0; jj < 16; jj++){
    const int j = c0 + jj;
    float a = 0.0f;
    #pragma unroll
    for (int d = 0; d < 64; d++) a += qs[i][d] * ks[j][d];
    s[jj] = a;
  }
  float cm = s[0];
  #pragma unroll
  for (int jj = 1; jj < 16; jj++) cm = fmaxf(cm, s[jj]);
  cm = fmaxf(cm, __shfl_xor(cm, 1));
  cm = fmaxf(cm, __shfl_xor(cm, 2));
  float psum = 0.0f;
  #pragma unroll
  for (int jj = 0; jj < 16; jj++){ s[jj] = expf(s[jj] - cm); psum += s[jj]; }
  psum += __shfl_xor(psum, 1);
  psum += __shfl_xor(psum, 2);
  #pragma unroll
  for (int jj = 0; jj < 16; jj++) ps[i][c0 + jj] = s[jj];
  __syncthreads();
  #pragma unroll
  for (int c = 0; c < 16; c += 4){
    ushort4 t4 = *(const ushort4*)(base + 1536 + c);
    ks[i][c0+c+0] = b2f(t4.x); ks[i][c0+c+1] = b2f(t4.y);
    ks[i][c0+c+2] = b2f(t4.z); ks[i][c0+c+3] = b2f(t4.w);
  }
  __syncthreads();
  float oacc[16];
  #pragma unroll
  for (int d = 0; d < 16; d++) oacc[d] = 0.0f;
  #pragma unroll
  for (int j = 0; j < 64; j++){
    const float p = ps[i][j];
    #pragma unroll
    for (int d = 0; d < 16; d++) oacc[d] += p * ks[j][c0 + d];
  }
  const float inv = 1.0f / psum;
  u16* orow = o2 + ((size_t)i * 128 + bt) * 768 + hh * 64 + c0;
  #pragma unroll
  for (int d = 0; d < 16; d++) orow[d] = f2b(oacc[d] * inv);
}

extern "C" void kernel_launch(void* const* d_in, const int* in_sizes, int n_in,
                              void* d_out, int out_size, void* d_ws, size_t ws_size,
                              hipStream_t stream)
{
  const void* vf   = d_in[0];
  const void* lat  = d_in[1];
  const void* nl0g = d_in[2];
  const void* nl0b = d_in[3];
  const void* pmg  = d_in[4];
  const void* pmb  = d_in[5];
  const void* plg  = d_in[6];
  const void* plb  = d_in[7];
  const void* Wq   = d_in[8];
  const void* Wkv  = d_in[9];
  const void* Wo   = d_in[10];
  const void* ln1g = d_in[11];
  const void* ln1b = d_in[12];
  const void* Wqkv = d_in[13];
  const void* bqkv = d_in[14];
  const void* Wout = d_in[15];
  const void* bout = d_in[16];
  const void* ln2g = d_in[17];
  const void* ln2b = d_in[18];
  const void* Wfc  = d_in[19];
  const void* bfc  = d_in[20];
  const void* Wpr  = d_in[21];
  const void* bpr  = d_in[22];

  // ---- workspace layout (high-water 116,391,940 B) ----
  char* ws = (char*)d_ws;
  u16*    kvx  = (u16*)(ws + 0);           // 32768x1024 bf16 (dead after pattn)
  u16*    qkvb = (u16*)(ws + 0);           // 8192x2304 bf16  (dead after sattn)
  u16*    o2b  = (u16*)(ws + 37748736);    // 8192x768 bf16   (dead after Wout gemm)
  u16*    hb   = (u16*)(ws + 0);           // 8192x3072 bf16
  float2* stx  = (float2*)(ws + 67108864); // 32768 x {mean,rstd}
  u16*    ll   = (u16*)(ws + 67371008);    // 512x768 bf16
  float*  qb   = (float*)(ws + 68157440);  // 512x512 f32
  u16*    kvll = (u16*)(ws + 69206016);    // 512x1024 bf16
  u16*    ob   = (u16*)(ws + 70254592);    // 8192x512 bf16
  float*  yb   = (float*)(ws + 78643200);  // 8192x768 f32 (residual stream)
  u16*    zb   = (u16*)(ws + 103809024);   // 8192x768 bf16 (LN out)
  int*    dtf  = (int*)(ws + 116391936);   // dtype flag (1 = fp32 inputs)

  const void* nob = nullptr;
  const float* nof = nullptr;
  const float2* nos = nullptr;

  hipLaunchKernelGGL(detect_k, dim3(1), dim3(256), 0, stream,
                     (const uint32_t*)vf, dtf);
  hipLaunchKernelGGL(stats_x_k, dim3(32768), dim3(256), 0, stream, vf, stx, dtf);
  hipLaunchKernelGGL(ln_lat2_k, dim3(512), dim3(256), 0, stream,
                     lat, ll, nl0g, nl0b, plg, plb, dtf);
  // q = ll @ Wq   (512,768)@(768,512) -> f32 (scale applied in attention)
  hipLaunchKernelGGL(gemm_k, dim3(64), dim3(256), 0, stream,
                     ll, Wq, (void*)qb, 512, 512, 768, 1.0f, nob, 0, nof, 0, 0,
                     nos, nob, nob, 0, dtf);
  // kv_ll = ll @ Wkv (512,768)@(768,1024) -> bf16
  hipLaunchKernelGGL(gemm_k, dim3(128), dim3(256), 0, stream,
                     ll, Wkv, (void*)kvll, 512, 1024, 768, 1.0f, nob, 0, nof, 0, 1,
                     nos, nob, nob, 0, dtf);
  // kv_x = LN(rearrange(vf)) @ Wkv  (32768,768)@(768,1024) -> bf16 (LN fused)
  hipLaunchKernelGGL(gemm_k, dim3(8192), dim3(256), 0, stream,
                     vf, Wkv, (void*)kvx, 32768, 1024, 768, 1.0f, nob, 0, nof, 0, 1,
                     stx, pmg, pmb, 1, dtf);
  // perceiver attention -> o (8192x512 bf16)
  hipLaunchKernelGGL(pattn_k, dim3(1024), dim3(256), 0, stream, qb, kvx, kvll, ob);
  // y = rearrange(o @ Wo) (8192,512)@(512,768) -> f32, row-permuted to (L,bt)
  hipLaunchKernelGGL(gemm_k, dim3(1536), dim3(256), 0, stream,
                     ob, Wo, (void*)yb, 8192, 768, 512, 1.0f, nob, 0, nof, 1, 0,
                     nos, nob, nob, 0, dtf);
  // z = LN(y)
  hipLaunchKernelGGL(ln_f32_k, dim3(8192), dim3(256), 0, stream, yb, zb, ln1g, ln1b, dtf);
  // qkv = z @ in_proj + b (8192,768)@(768,2304) -> bf16
  hipLaunchKernelGGL(gemm_k, dim3(4608), dim3(256), 0, stream,
                     zb, Wqkv, (void*)qkvb, 8192, 2304, 768, 1.0f, bqkv, 0, nof, 0, 1,
                     nos, nob, nob, 0, dtf);
  // self-attention -> o2 (bf16)
  hipLaunchKernelGGL(sattn_k, dim3(1536), dim3(256), 0, stream, qkvb, o2b);
  // y += o2 @ out_w + out_b
  hipLaunchKernelGGL(gemm_k, dim3(1536), dim3(256), 0, stream,
                     o2b, Wout, (void*)yb, 8192, 768, 768, 1.0f, bout, 0, yb, 0, 0,
                     nos, nob, nob, 0, dtf);
  // z2 = LN(y)
  hipLaunchKernelGGL(ln_f32_k, dim3(8192), dim3(256), 0, stream, yb, zb, ln2g, ln2b, dtf);
  // h = QuickGELU(z2 @ fc_w + fc_b) -> bf16
  hipLaunchKernelGGL(gemm_k, dim3(6144), dim3(256), 0, stream,
                     zb, Wfc, (void*)hb, 8192, 3072, 768, 1.0f, bfc, 1, nof, 0, 1,
                     nos, nob, nob, 0, dtf);
  // out = y + h @ proj_w + proj_b -> dtype per flag
  hipLaunchKernelGGL(gemm_k, dim3(1536), dim3(256), 0, stream,
                     hb, Wpr, d_out, 8192, 768, 3072, 1.0f, bpr, 0, yb, 0, 2,
                     nos, nob, nob, 0, dtf);
}

// Round 4
// 995.647 us; speedup vs baseline: 4.0936x; 4.0936x over previous
//
#include <hip/hip_runtime.h>
#include <hip/hip_bf16.h>
#include <cstdint>
#include <cstddef>

typedef unsigned short u16;
typedef __bf16 bhalf8 __attribute__((ext_vector_type(8)));
typedef float floatx4 __attribute__((ext_vector_type(4)));
typedef unsigned short u16x8 __attribute__((ext_vector_type(8)));

__device__ __forceinline__ float b2f(u16 u){
  union { uint32_t i; float f; } x; x.i = ((uint32_t)u) << 16; return x.f;
}
__device__ __forceinline__ u16 f2b(float f){
  uint32_t i = __float_as_uint(f);
  uint32_t r = (i + 0x7FFFu + ((i >> 16) & 1u)) >> 16;   // round-nearest-even
  return (u16)r;
}

// ---- block-wide sum over 256 threads (4 waves) ----
__device__ __forceinline__ float block_sum256(float v, float* sh){
  #pragma unroll
  for (int o = 32; o > 0; o >>= 1) v += __shfl_down(v, o);
  __syncthreads();
  if ((threadIdx.x & 63u) == 0) sh[threadIdx.x >> 6] = v;
  __syncthreads();
  return sh[0] + sh[1] + sh[2] + sh[3];
}

// ---- per-row LN stats of visual_feat (fp32), in rearranged row order ----
// out row r = bt*256 + nn  <->  vf row = nn*128 + bt
__global__ __launch_bounds__(256) void stats_x_k(
    const float* __restrict__ vf, float2* __restrict__ st)
{
  __shared__ float sh[4];
  const int r  = blockIdx.x;
  const int nn = r & 255, bt = r >> 8;
  const float* in = vf + ((size_t)nn * 128 + bt) * 768;
  const int t = threadIdx.x;
  float v0 = in[t], v1 = in[t + 256], v2 = in[t + 512];
  float mean = block_sum256(v0 + v1 + v2, sh) * (1.0f / 768.0f);
  float d0 = v0 - mean, d1 = v1 - mean, d2 = v2 - mean;
  float var = block_sum256(d0*d0 + d1*d1 + d2*d2, sh) * (1.0f / 768.0f);
  if (t == 0) st[r] = make_float2(mean, rsqrtf(var + 1e-5f));
}

// ---- double LayerNorm of latents (fp32 in): ll = LN_pl(LN_nl0(lat)) -> bf16 ----
__global__ __launch_bounds__(256) void ln_lat2_k(
    const float* __restrict__ lat, u16* __restrict__ ll,
    const float* __restrict__ g0, const float* __restrict__ b0,
    const float* __restrict__ g1, const float* __restrict__ b1)
{
  __shared__ float sh[4];
  const int r = blockIdx.x;
  const int t = threadIdx.x;
  const float* in = lat + (size_t)r * 768;
  float v[3];
  #pragma unroll
  for (int i = 0; i < 3; i++) v[i] = in[t + 256 * i];
  #pragma unroll
  for (int pass = 0; pass < 2; ++pass){
    float mean = block_sum256(v[0] + v[1] + v[2], sh) * (1.0f / 768.0f);
    float d0 = v[0] - mean, d1 = v[1] - mean, d2 = v[2] - mean;
    float var = block_sum256(d0*d0 + d1*d1 + d2*d2, sh) * (1.0f / 768.0f);
    float rs = rsqrtf(var + 1e-5f);
    const float* g = pass ? g1 : g0;
    const float* b = pass ? b1 : b0;
    #pragma unroll
    for (int i = 0; i < 3; i++){
      int c = t + 256 * i;
      v[i] = (v[i] - mean) * rs * g[c] + b[c];
    }
  }
  #pragma unroll
  for (int i = 0; i < 3; i++) ll[(size_t)r * 768 + t + 256 * i] = f2b(v[i]);
}

// ---- LN of fp32 ws rows -> bf16 ----
__global__ __launch_bounds__(256) void ln_f32_k(
    const float* __restrict__ y, u16* __restrict__ z,
    const float* __restrict__ g, const float* __restrict__ b)
{
  __shared__ float sh[4];
  const int r = blockIdx.x;
  const float* in = y + (size_t)r * 768;
  const int t = threadIdx.x;
  float v[3];
  #pragma unroll
  for (int i = 0; i < 3; i++) v[i] = in[t + 256 * i];
  float mean = block_sum256(v[0] + v[1] + v[2], sh) * (1.0f / 768.0f);
  float d0 = v[0] - mean, d1 = v[1] - mean, d2 = v[2] - mean;
  float var = block_sum256(d0*d0 + d1*d1 + d2*d2, sh) * (1.0f / 768.0f);
  float rs = rsqrtf(var + 1e-5f);
  #pragma unroll
  for (int i = 0; i < 3; i++){
    int c = t + 256 * i;
    z[(size_t)r * 768 + c] = f2b((v[i] - mean) * rs * g[c] + b[c]);
  }
}

// ---- weight transpose + bf16 convert: src (K,N) f32 -> dst (N,K) bf16 ----
__global__ __launch_bounds__(256) void transp_k(
    const float* __restrict__ src, u16* __restrict__ dst, int K, int N)
{
  __shared__ u16 sh[32][33];
  const int nb = N >> 5;
  const int bx = blockIdx.x % nb, byy = blockIdx.x / nb;
  const int tx = threadIdx.x & 31, ty = threadIdx.x >> 5;   // ty 0..7
  #pragma unroll
  for (int i = 0; i < 4; i++){
    int k = byy * 32 + ty + i * 8, n = bx * 32 + tx;
    sh[tx][ty + i * 8] = f2b(src[(size_t)k * N + n]);
  }
  __syncthreads();
  #pragma unroll
  for (int i = 0; i < 4; i++){
    int n = bx * 32 + ty + i * 8, k = byy * 32 + tx;
    dst[(size_t)n * K + k] = sh[ty + i * 8][tx];
  }
}

// ---- MFMA GEMM: C[M,N] = act(A@B + bias) + addsrc ----
// A: AMODE 0 -> bf16 (M,K) row-major;  AMODE 1 -> fp32 vf with fused LN + row
// remap (gm&255)*128+(gm>>8). BT: bf16 (N,K) row-major (pre-transposed weight).
// 128x128 tile, BK=32, 4 waves (2x2), each wave 64x64 via 4x4 frags 16x16x32.
template<int AMODE>
__global__ __launch_bounds__(256) void mgemm_k(
    const void* __restrict__ A, const u16* __restrict__ BT, void* __restrict__ C,
    int M, int N, int K,
    const float* __restrict__ bias, int act,
    const float* addsrc, int rowperm, int outbf16,
    const float2* __restrict__ stx, const float* __restrict__ gam,
    const float* __restrict__ bet)
{
  __shared__ __align__(16) u16 As[128][40];   // [m][k] pad 32->40: conflict-free
  __shared__ __align__(16) u16 Bs[128][40];   // [n][k]
  const int nb = N >> 7;
  const int bx = blockIdx.x % nb, by = blockIdx.x / nb;
  const int tid  = threadIdx.x;
  const int wave = tid >> 6, lane = tid & 63;
  const int wr = (wave >> 1) * 64, wc = (wave & 1) * 64;
  const int l15 = lane & 15, l4 = lane >> 4;
  const int sr = tid >> 2, sq = (tid & 3) * 8;   // staging: row sr/sr+64, col sq

  const u16*   Abf = (const u16*)A;
  const float* Af  = (const float*)A;

  int   asrc[2]; float mn[2], rs[2];
  #pragma unroll
  for (int p = 0; p < 2; p++){
    int gm = by * 128 + sr + p * 64;
    if (AMODE == 1){
      asrc[p] = (gm & 255) * 128 + (gm >> 8);
      float2 s = stx[gm]; mn[p] = s.x; rs[p] = s.y;
    } else asrc[p] = gm;
  }

  floatx4 acc[4][4];
  #pragma unroll
  for (int i = 0; i < 4; i++)
    #pragma unroll
    for (int j = 0; j < 4; j++) acc[i][j] = (floatx4){0.f, 0.f, 0.f, 0.f};

  for (int k0 = 0; k0 < K; k0 += 32){
    #pragma unroll
    for (int p = 0; p < 2; p++){
      const int r = sr + p * 64;
      if (AMODE == 0){
        u16x8 v = *(const u16x8*)(Abf + (size_t)asrc[p] * K + k0 + sq);
        *(u16x8*)(&As[r][sq]) = v;
      } else {
        const float* ap = Af + (size_t)asrc[p] * K + k0 + sq;
        float4 f0 = *(const float4*)ap, f1 = *(const float4*)(ap + 4);
        float4 g0 = *(const float4*)(gam + k0 + sq), g1 = *(const float4*)(gam + k0 + sq + 4);
        float4 e0 = *(const float4*)(bet + k0 + sq), e1 = *(const float4*)(bet + k0 + sq + 4);
        u16x8 v;
        v[0] = f2b((f0.x - mn[p]) * rs[p] * g0.x + e0.x);
        v[1] = f2b((f0.y - mn[p]) * rs[p] * g0.y + e0.y);
        v[2] = f2b((f0.z - mn[p]) * rs[p] * g0.z + e0.z);
        v[3] = f2b((f0.w - mn[p]) * rs[p] * g0.w + e0.w);
        v[4] = f2b((f1.x - mn[p]) * rs[p] * g1.x + e1.x);
        v[5] = f2b((f1.y - mn[p]) * rs[p] * g1.y + e1.y);
        v[6] = f2b((f1.z - mn[p]) * rs[p] * g1.z + e1.z);
        v[7] = f2b((f1.w - mn[p]) * rs[p] * g1.w + e1.w);
        *(u16x8*)(&As[r][sq]) = v;
      }
      u16x8 w = *(const u16x8*)(BT + (size_t)(bx * 128 + r) * K + k0 + sq);
      *(u16x8*)(&Bs[r][sq]) = w;
    }
    __syncthreads();
    bhalf8 af[4], bfv[4];
    #pragma unroll
    for (int i = 0; i < 4; i++){
      af[i]  = *(const bhalf8*)(&As[wr + i * 16 + l15][l4 * 8]);
      bfv[i] = *(const bhalf8*)(&Bs[wc + i * 16 + l15][l4 * 8]);
    }
    #pragma unroll
    for (int i = 0; i < 4; i++)
      #pragma unroll
      for (int j = 0; j < 4; j++)
        acc[i][j] = __builtin_amdgcn_mfma_f32_16x16x32_bf16(af[i], bfv[j], acc[i][j], 0, 0, 0);
    __syncthreads();
  }

  const int gm0 = by * 128 + wr, gn0 = bx * 128 + wc;
  #pragma unroll
  for (int i = 0; i < 4; i++){
    #pragma unroll
    for (int r = 0; r < 4; r++){
      int gm = gm0 + i * 16 + l4 * 4 + r;
      int orow = rowperm ? ((gm & 63) * 128 + (gm >> 6)) : gm;
      #pragma unroll
      for (int j = 0; j < 4; j++){
        int gn = gn0 + j * 16 + l15;
        float v = acc[i][j][r];
        if (bias) v += bias[gn];
        if (act)  v = v * (1.0f / (1.0f + expf(-1.702f * v)));  // QuickGELU
        if (addsrc) v += addsrc[(size_t)orow * N + gn];
        if (outbf16) ((u16*)C)[(size_t)orow * N + gn] = f2b(v);
        else         ((float*)C)[(size_t)orow * N + gn] = v;
      }
    }
  }
}

// ---- Perceiver attention: one block per (b,t,head); 64 q rows, 320 keys ----
__global__ __launch_bounds__(256) void pattn_k(
    const float* __restrict__ q, const u16* __restrict__ kvx,
    const u16* __restrict__ kvll, u16* __restrict__ o)
{
  __shared__ float qs[64][65];
  __shared__ float ks[64][65];
  __shared__ float ps[64][64];
  const int blk = blockIdx.x;                  // ((bb*8+tt)*8+hh)
  const int hh = blk & 7, tt = (blk >> 3) & 7, bb = blk >> 6;
  const int bt = bb * 8 + tt;
  const int tid = threadIdx.x;
  const int i = tid >> 2;
  const int c0 = (tid & 3) * 16;
  {
    const float* qr = q + ((size_t)(tt * 64 + i)) * 512 + hh * 64 + c0;
    #pragma unroll
    for (int c = 0; c < 16; c += 4){
      float4 t4 = *(const float4*)(qr + c);
      qs[i][c0+c+0] = t4.x * 0.125f; qs[i][c0+c+1] = t4.y * 0.125f;
      qs[i][c0+c+2] = t4.z * 0.125f; qs[i][c0+c+3] = t4.w * 0.125f;
    }
  }
  float m = -1e30f, l = 0.0f;
  float oacc[16];
  #pragma unroll
  for (int d = 0; d < 16; d++) oacc[d] = 0.0f;

  for (int ch = 0; ch < 5; ++ch){
    const int jg = ch * 64 + i;
    const u16* kbase = (jg < 256)
        ? (kvx  + ((size_t)bt * 256 + jg) * 1024 + hh * 64)
        : (kvll + ((size_t)tt * 64 + (jg - 256)) * 1024 + hh * 64);
    __syncthreads();
    #pragma unroll
    for (int c = 0; c < 16; c += 4){
      ushort4 k4 = *(const ushort4*)(kbase + c0 + c);
      ks[i][c0+c+0] = b2f(k4.x); ks[i][c0+c+1] = b2f(k4.y);
      ks[i][c0+c+2] = b2f(k4.z); ks[i][c0+c+3] = b2f(k4.w);
    }
    __syncthreads();
    float s[16];
    #pragma unroll
    for (int jj = 0; jj < 16; jj++){
      const int j = c0 + jj;
      float a = 0.0f;
      #pragma unroll
      for (int d = 0; d < 64; d++) a += qs[i][d] * ks[j][d];
      s[jj] = a;
    }
    float cm = s[0];
    #pragma unroll
    for (int jj = 1; jj < 16; jj++) cm = fmaxf(cm, s[jj]);
    cm = fmaxf(cm, __shfl_xor(cm, 1));
    cm = fmaxf(cm, __shfl_xor(cm, 2));
    const float mnew = fmaxf(m, cm);
    const float corr = expf(m - mnew);
    float psum = 0.0f;
    #pragma unroll
    for (int jj = 0; jj < 16; jj++){ s[jj] = expf(s[jj] - mnew); psum += s[jj]; }
    psum += __shfl_xor(psum, 1);
    psum += __shfl_xor(psum, 2);
    l = l * corr + psum;
    m = mnew;
    #pragma unroll
    for (int jj = 0; jj < 16; jj++) ps[i][c0 + jj] = s[jj];
    #pragma unroll
    for (int d = 0; d < 16; d++) oacc[d] *= corr;
    __syncthreads();
    const u16* vbase = (jg < 256)
        ? (kvx  + ((size_t)bt * 256 + jg) * 1024 + 512 + hh * 64)
        : (kvll + ((size_t)tt * 64 + (jg - 256)) * 1024 + 512 + hh * 64);
    #pragma unroll
    for (int c = 0; c < 16; c += 4){
      ushort4 v4 = *(const ushort4*)(vbase + c0 + c);
      ks[i][c0+c+0] = b2f(v4.x); ks[i][c0+c+1] = b2f(v4.y);
      ks[i][c0+c+2] = b2f(v4.z); ks[i][c0+c+3] = b2f(v4.w);
    }
    __syncthreads();
    #pragma unroll
    for (int j = 0; j < 64; j++){
      const float p = ps[i][j];
      #pragma unroll
      for (int d = 0; d < 16; d++) oacc[d] += p * ks[j][c0 + d];
    }
  }
  const float inv = 1.0f / l;
  u16* orow = o + ((size_t)bt * 64 + i) * 512 + hh * 64 + c0;
  #pragma unroll
  for (int d = 0; d < 16; d++) orow[d] = f2b(oacc[d] * inv);
}

// ---- self-attention: one block per (bt, head); seq=64, hd=64; qkv ws bf16 ----
__global__ __launch_bounds__(256) void sattn_k(
    const u16* __restrict__ qkv, u16* __restrict__ o2)
{
  __shared__ float qs[64][65];
  __shared__ float ks[64][65];
  __shared__ float ps[64][64];
  const int blk = blockIdx.x;
  const int hh = blk % 12;
  const int bt = blk / 12;
  const int tid = threadIdx.x;
  const int i = tid >> 2;
  const int c0 = (tid & 3) * 16;
  const u16* base = qkv + ((size_t)i * 128 + bt) * 2304 + hh * 64 + c0;
  #pragma unroll
  for (int c = 0; c < 16; c += 4){
    ushort4 t4 = *(const ushort4*)(base + c);
    qs[i][c0+c+0] = b2f(t4.x) * 0.125f; qs[i][c0+c+1] = b2f(t4.y) * 0.125f;
    qs[i][c0+c+2] = b2f(t4.z) * 0.125f; qs[i][c0+c+3] = b2f(t4.w) * 0.125f;
  }
  #pragma unroll
  for (int c = 0; c < 16; c += 4){
    ushort4 t4 = *(const ushort4*)(base + 768 + c);
    ks[i][c0+c+0] = b2f(t4.x); ks[i][c0+c+1] = b2f(t4.y);
    ks[i][c0+c+2] = b2f(t4.z); ks[i][c0+c+3] = b2f(t4.w);
  }
  __syncthreads();
  float s[16];
  #pragma unroll
  for (int jj = 0; jj < 16; jj++){
    const int j = c0 + jj;
    float a = 0.0f;
    #pragma unroll
    for (int d = 0; d < 64; d++) a += qs[i][d] * ks[j][d];
    s[jj] = a;
  }
  float cm = s[0];
  #pragma unroll
  for (int jj = 1; jj < 16; jj++) cm = fmaxf(cm, s[jj]);
  cm = fmaxf(cm, __shfl_xor(cm, 1));
  cm = fmaxf(cm, __shfl_xor(cm, 2));
  float psum = 0.0f;
  #pragma unroll
  for (int jj = 0; jj < 16; jj++){ s[jj] = expf(s[jj] - cm); psum += s[jj]; }
  psum += __shfl_xor(psum, 1);
  psum += __shfl_xor(psum, 2);
  #pragma unroll
  for (int jj = 0; jj < 16; jj++) ps[i][c0 + jj] = s[jj];
  __syncthreads();
  #pragma unroll
  for (int c = 0; c < 16; c += 4){
    ushort4 t4 = *(const ushort4*)(base + 1536 + c);
    ks[i][c0+c+0] = b2f(t4.x); ks[i][c0+c+1] = b2f(t4.y);
    ks[i][c0+c+2] = b2f(t4.z); ks[i][c0+c+3] = b2f(t4.w);
  }
  __syncthreads();
  float oacc[16];
  #pragma unroll
  for (int d = 0; d < 16; d++) oacc[d] = 0.0f;
  #pragma unroll
  for (int j = 0; j < 64; j++){
    const float p = ps[i][j];
    #pragma unroll
    for (int d = 0; d < 16; d++) oacc[d] += p * ks[j][c0 + d];
  }
  const float inv = 1.0f / psum;
  u16* orow = o2 + ((size_t)i * 128 + bt) * 768 + hh * 64 + c0;
  #pragma unroll
  for (int d = 0; d < 16; d++) orow[d] = f2b(oacc[d] * inv);
}

extern "C" void kernel_launch(void* const* d_in, const int* in_sizes, int n_in,
                              void* d_out, int out_size, void* d_ws, size_t ws_size,
                              hipStream_t stream)
{
  const float* vf   = (const float*)d_in[0];
  const float* lat  = (const float*)d_in[1];
  const float* nl0g = (const float*)d_in[2];
  const float* nl0b = (const float*)d_in[3];
  const float* pmg  = (const float*)d_in[4];
  const float* pmb  = (const float*)d_in[5];
  const float* plg  = (const float*)d_in[6];
  const float* plb  = (const float*)d_in[7];
  const float* Wq   = (const float*)d_in[8];
  const float* Wkv  = (const float*)d_in[9];
  const float* Wo   = (const float*)d_in[10];
  const float* ln1g = (const float*)d_in[11];
  const float* ln1b = (const float*)d_in[12];
  const float* Wqkv = (const float*)d_in[13];
  const float* bqkv = (const float*)d_in[14];
  const float* Wout = (const float*)d_in[15];
  const float* bout = (const float*)d_in[16];
  const float* ln2g = (const float*)d_in[17];
  const float* ln2b = (const float*)d_in[18];
  const float* Wfc  = (const float*)d_in[19];
  const float* bfc  = (const float*)d_in[20];
  const float* Wpr  = (const float*)d_in[21];
  const float* bpr  = (const float*)d_in[22];

  // ---- ws layout, high-water 104,857,600 B (< proven 116.4 MB) ----
  char* ws = (char*)d_ws;
  u16*    kvx   = (u16*)(ws + 0);          // 67,108,864 (dead after pattn)
  u16*    qkvb  = (u16*)(ws + 0);          // 37,748,736 (dead after sattn)
  u16*    o2b   = (u16*)(ws + 37748736);   // 12,582,912 (dead after Wout gemm)
  u16*    hb    = (u16*)(ws + 0);          // 50,331,648
  u16*    WoT   = (u16*)(ws + 50331648);   // late weights live in dead kvx tail
  u16*    WqkvT = (u16*)(ws + 51118080);
  u16*    WoutT = (u16*)(ws + 54657024);
  u16*    WfcT  = (u16*)(ws + 55836672);
  u16*    WprT  = (u16*)(ws + 60555264);   // ends 65,273,856 < 67,108,864
  u16*    WqT   = (u16*)(ws + 67108864);   // early weights (dead before yb)
  u16*    WkvT  = (u16*)(ws + 67895296);   // ends 69,468,160
  float*  yb    = (float*)(ws + 67108864); // 25,165,824 (written after WqT/WkvT dead)
  u16*    llb   = (u16*)(ws + 92274688);   //   786,432
  float2* stx   = (float2*)(ws + 93061120);//   262,144
  float*  qb    = (float*)(ws + 93323264); // 1,048,576
  u16*    kvll  = (u16*)(ws + 94371840);   // 1,048,576
  u16*    ob    = (u16*)(ws + 95420416);   // 8,388,608 ends 103,809,024
  u16*    zb    = (u16*)(ws + 92274688);   // 12,582,912 (overwrites ll..ob when dead)

  const float* nof = nullptr;
  const float2* nos = nullptr;

  // early weight transposes (WqT/WkvT) + LN stats
  hipLaunchKernelGGL(transp_k, dim3(384), dim3(256), 0, stream, Wq, WqT, 768, 512);
  hipLaunchKernelGGL(transp_k, dim3(768), dim3(256), 0, stream, Wkv, WkvT, 768, 1024);
  hipLaunchKernelGGL(stats_x_k, dim3(32768), dim3(256), 0, stream, vf, stx);
  hipLaunchKernelGGL(ln_lat2_k, dim3(512), dim3(256), 0, stream,
                     lat, llb, nl0g, nl0b, plg, plb);
  // q = ll @ Wq -> f32 qb (scale applied in pattn)
  hipLaunchKernelGGL(mgemm_k<0>, dim3(16), dim3(256), 0, stream,
                     (const void*)llb, WqT, (void*)qb, 512, 512, 768,
                     nof, 0, nof, 0, 0, nos, nof, nof);
  // kv_ll = ll @ Wkv -> bf16
  hipLaunchKernelGGL(mgemm_k<0>, dim3(32), dim3(256), 0, stream,
                     (const void*)llb, WkvT, (void*)kvll, 512, 1024, 768,
                     nof, 0, nof, 0, 1, nos, nof, nof);
  // kv_x = LN(rearrange(vf)) @ Wkv -> bf16 (LN fused in A-stage)
  hipLaunchKernelGGL(mgemm_k<1>, dim3(2048), dim3(256), 0, stream,
                     (const void*)vf, WkvT, (void*)kvx, 32768, 1024, 768,
                     nof, 0, nof, 0, 1, stx, pmg, pmb);
  // perceiver attention -> ob
  hipLaunchKernelGGL(pattn_k, dim3(1024), dim3(256), 0, stream, qb, kvx, kvll, ob);
  // late weight transposes (into dead kvx region)
  hipLaunchKernelGGL(transp_k, dim3(384), dim3(256), 0, stream, Wo, WoT, 512, 768);
  hipLaunchKernelGGL(transp_k, dim3(1728), dim3(256), 0, stream, Wqkv, WqkvT, 768, 2304);
  hipLaunchKernelGGL(transp_k, dim3(576), dim3(256), 0, stream, Wout, WoutT, 768, 768);
  hipLaunchKernelGGL(transp_k, dim3(2304), dim3(256), 0, stream, Wfc, WfcT, 768, 3072);
  hipLaunchKernelGGL(transp_k, dim3(2304), dim3(256), 0, stream, Wpr, WprT, 3072, 768);
  // y = rearrange(ob @ Wo) -> f32 yb (row-permuted)
  hipLaunchKernelGGL(mgemm_k<0>, dim3(384), dim3(256), 0, stream,
                     (const void*)ob, WoT, (void*)yb, 8192, 768, 512,
                     nof, 0, nof, 1, 0, nos, nof, nof);
  // z = LN(y)
  hipLaunchKernelGGL(ln_f32_k, dim3(8192), dim3(256), 0, stream, yb, zb, ln1g, ln1b);
  // qkv = z @ in_proj + b -> bf16
  hipLaunchKernelGGL(mgemm_k<0>, dim3(1152), dim3(256), 0, stream,
                     (const void*)zb, WqkvT, (void*)qkvb, 8192, 2304, 768,
                     bqkv, 0, nof, 0, 1, nos, nof, nof);
  // self-attention -> o2
  hipLaunchKernelGGL(sattn_k, dim3(1536), dim3(256), 0, stream, qkvb, o2b);
  // y += o2 @ out_w + out_b
  hipLaunchKernelGGL(mgemm_k<0>, dim3(384), dim3(256), 0, stream,
                     (const void*)o2b, WoutT, (void*)yb, 8192, 768, 768,
                     bout, 0, yb, 0, 0, nos, nof, nof);
  // z2 = LN(y)
  hipLaunchKernelGGL(ln_f32_k, dim3(8192), dim3(256), 0, stream, yb, zb, ln2g, ln2b);
  // h = QuickGELU(z2 @ fc_w + fc_b) -> bf16
  hipLaunchKernelGGL(mgemm_k<0>, dim3(1536), dim3(256), 0, stream,
                     (const void*)zb, WfcT, (void*)hb, 8192, 3072, 768,
                     bfc, 1, nof, 0, 1, nos, nof, nof);
  // out = y + h @ proj_w + proj_b -> f32 d_out
  hipLaunchKernelGGL(mgemm_k<0>, dim3(384), dim3(256), 0, stream,
                     (const void*)hb, WprT, d_out, 8192, 768, 3072,
                     bpr, 0, yb, 0, 0, nos, nof, nof);
}

// Round 5
// 677.897 us; speedup vs baseline: 6.0123x; 1.4687x over previous
//
#include <hip/hip_runtime.h>
#include <hip/hip_bf16.h>
#include <cstdint>
#include <cstddef>

typedef unsigned short u16;
typedef __bf16 bhalf8 __attribute__((ext_vector_type(8)));
typedef float floatx4 __attribute__((ext_vector_type(4)));
typedef unsigned short u16x8 __attribute__((ext_vector_type(8)));

__device__ __forceinline__ float b2f(u16 u){
  union { uint32_t i; float f; } x; x.i = ((uint32_t)u) << 16; return x.f;
}
__device__ __forceinline__ u16 f2b(float f){
  uint32_t i = __float_as_uint(f);
  uint32_t r = (i + 0x7FFFu + ((i >> 16) & 1u)) >> 16;   // round-nearest-even
  return (u16)r;
}

// ---- block-wide sum over 256 threads (4 waves) ----
__device__ __forceinline__ float block_sum256(float v, float* sh){
  #pragma unroll
  for (int o = 32; o > 0; o >>= 1) v += __shfl_down(v, o);
  __syncthreads();
  if ((threadIdx.x & 63u) == 0) sh[threadIdx.x >> 6] = v;
  __syncthreads();
  return sh[0] + sh[1] + sh[2] + sh[3];
}

// ---- per-row LN stats of visual_feat (fp32), in rearranged row order ----
__global__ __launch_bounds__(256) void stats_x_k(
    const float* __restrict__ vf, float2* __restrict__ st)
{
  __shared__ float sh[4];
  const int r  = blockIdx.x;
  const int nn = r & 255, bt = r >> 8;
  const float* in = vf + ((size_t)nn * 128 + bt) * 768;
  const int t = threadIdx.x;
  float v0 = in[t], v1 = in[t + 256], v2 = in[t + 512];
  float mean = block_sum256(v0 + v1 + v2, sh) * (1.0f / 768.0f);
  float d0 = v0 - mean, d1 = v1 - mean, d2 = v2 - mean;
  float var = block_sum256(d0*d0 + d1*d1 + d2*d2, sh) * (1.0f / 768.0f);
  if (t == 0) st[r] = make_float2(mean, rsqrtf(var + 1e-5f));
}

// ---- double LayerNorm of latents (fp32 in) -> bf16 ----
__global__ __launch_bounds__(256) void ln_lat2_k(
    const float* __restrict__ lat, u16* __restrict__ ll,
    const float* __restrict__ g0, const float* __restrict__ b0,
    const float* __restrict__ g1, const float* __restrict__ b1)
{
  __shared__ float sh[4];
  const int r = blockIdx.x;
  const int t = threadIdx.x;
  const float* in = lat + (size_t)r * 768;
  float v[3];
  #pragma unroll
  for (int i = 0; i < 3; i++) v[i] = in[t + 256 * i];
  #pragma unroll
  for (int pass = 0; pass < 2; ++pass){
    float mean = block_sum256(v[0] + v[1] + v[2], sh) * (1.0f / 768.0f);
    float d0 = v[0] - mean, d1 = v[1] - mean, d2 = v[2] - mean;
    float var = block_sum256(d0*d0 + d1*d1 + d2*d2, sh) * (1.0f / 768.0f);
    float rs = rsqrtf(var + 1e-5f);
    const float* g = pass ? g1 : g0;
    const float* b = pass ? b1 : b0;
    #pragma unroll
    for (int i = 0; i < 3; i++){
      int c = t + 256 * i;
      v[i] = (v[i] - mean) * rs * g[c] + b[c];
    }
  }
  #pragma unroll
  for (int i = 0; i < 3; i++) ll[(size_t)r * 768 + t + 256 * i] = f2b(v[i]);
}

// ---- LN of fp32 ws rows -> bf16 ----
__global__ __launch_bounds__(256) void ln_f32_k(
    const float* __restrict__ y, u16* __restrict__ z,
    const float* __restrict__ g, const float* __restrict__ b)
{
  __shared__ float sh[4];
  const int r = blockIdx.x;
  const float* in = y + (size_t)r * 768;
  const int t = threadIdx.x;
  float v[3];
  #pragma unroll
  for (int i = 0; i < 3; i++) v[i] = in[t + 256 * i];
  float mean = block_sum256(v[0] + v[1] + v[2], sh) * (1.0f / 768.0f);
  float d0 = v[0] - mean, d1 = v[1] - mean, d2 = v[2] - mean;
  float var = block_sum256(d0*d0 + d1*d1 + d2*d2, sh) * (1.0f / 768.0f);
  float rs = rsqrtf(var + 1e-5f);
  #pragma unroll
  for (int i = 0; i < 3; i++){
    int c = t + 256 * i;
    z[(size_t)r * 768 + c] = f2b((v[i] - mean) * rs * g[c] + b[c]);
  }
}

// ---- weight transpose + bf16 convert: src (K,N) f32 -> dst (N,K) bf16 ----
__global__ __launch_bounds__(256) void transp_k(
    const float* __restrict__ src, u16* __restrict__ dst, int K, int N)
{
  __shared__ u16 sh[32][33];
  const int nb = N >> 5;
  const int bx = blockIdx.x % nb, byy = blockIdx.x / nb;
  const int tx = threadIdx.x & 31, ty = threadIdx.x >> 5;
  #pragma unroll
  for (int i = 0; i < 4; i++){
    int k = byy * 32 + ty + i * 8, n = bx * 32 + tx;
    sh[tx][ty + i * 8] = f2b(src[(size_t)k * N + n]);
  }
  __syncthreads();
  #pragma unroll
  for (int i = 0; i < 4; i++){
    int n = bx * 32 + ty + i * 8, k = byy * 32 + tx;
    dst[(size_t)n * K + k] = sh[ty + i * 8][tx];
  }
}

// ---- MFMA GEMM (verified R4): C[M,N] = act(A@B + bias) + addsrc ----
template<int AMODE>
__global__ __launch_bounds__(256) void mgemm_k(
    const void* __restrict__ A, const u16* __restrict__ BT, void* __restrict__ C,
    int M, int N, int K,
    const float* __restrict__ bias, int act,
    const float* addsrc, int rowperm, int outbf16,
    const float2* __restrict__ stx, const float* __restrict__ gam,
    const float* __restrict__ bet)
{
  __shared__ __align__(16) u16 As[128][40];
  __shared__ __align__(16) u16 Bs[128][40];
  const int nb = N >> 7;
  const int bx = blockIdx.x % nb, by = blockIdx.x / nb;
  const int tid  = threadIdx.x;
  const int wave = tid >> 6, lane = tid & 63;
  const int wr = (wave >> 1) * 64, wc = (wave & 1) * 64;
  const int l15 = lane & 15, l4 = lane >> 4;
  const int sr = tid >> 2, sq = (tid & 3) * 8;

  const u16*   Abf = (const u16*)A;
  const float* Af  = (const float*)A;

  int   asrc[2]; float mn[2], rs[2];
  #pragma unroll
  for (int p = 0; p < 2; p++){
    int gm = by * 128 + sr + p * 64;
    if (AMODE == 1){
      asrc[p] = (gm & 255) * 128 + (gm >> 8);
      float2 s = stx[gm]; mn[p] = s.x; rs[p] = s.y;
    } else asrc[p] = gm;
  }

  floatx4 acc[4][4];
  #pragma unroll
  for (int i = 0; i < 4; i++)
    #pragma unroll
    for (int j = 0; j < 4; j++) acc[i][j] = (floatx4){0.f, 0.f, 0.f, 0.f};

  for (int k0 = 0; k0 < K; k0 += 32){
    #pragma unroll
    for (int p = 0; p < 2; p++){
      const int r = sr + p * 64;
      if (AMODE == 0){
        u16x8 v = *(const u16x8*)(Abf + (size_t)asrc[p] * K + k0 + sq);
        *(u16x8*)(&As[r][sq]) = v;
      } else {
        const float* ap = Af + (size_t)asrc[p] * K + k0 + sq;
        float4 f0 = *(const float4*)ap, f1 = *(const float4*)(ap + 4);
        float4 g0 = *(const float4*)(gam + k0 + sq), g1 = *(const float4*)(gam + k0 + sq + 4);
        float4 e0 = *(const float4*)(bet + k0 + sq), e1 = *(const float4*)(bet + k0 + sq + 4);
        u16x8 v;
        v[0] = f2b((f0.x - mn[p]) * rs[p] * g0.x + e0.x);
        v[1] = f2b((f0.y - mn[p]) * rs[p] * g0.y + e0.y);
        v[2] = f2b((f0.z - mn[p]) * rs[p] * g0.z + e0.z);
        v[3] = f2b((f0.w - mn[p]) * rs[p] * g0.w + e0.w);
        v[4] = f2b((f1.x - mn[p]) * rs[p] * g1.x + e1.x);
        v[5] = f2b((f1.y - mn[p]) * rs[p] * g1.y + e1.y);
        v[6] = f2b((f1.z - mn[p]) * rs[p] * g1.z + e1.z);
        v[7] = f2b((f1.w - mn[p]) * rs[p] * g1.w + e1.w);
        *(u16x8*)(&As[r][sq]) = v;
      }
      u16x8 w = *(const u16x8*)(BT + (size_t)(bx * 128 + r) * K + k0 + sq);
      *(u16x8*)(&Bs[r][sq]) = w;
    }
    __syncthreads();
    bhalf8 af[4], bfv[4];
    #pragma unroll
    for (int i = 0; i < 4; i++){
      af[i]  = *(const bhalf8*)(&As[wr + i * 16 + l15][l4 * 8]);
      bfv[i] = *(const bhalf8*)(&Bs[wc + i * 16 + l15][l4 * 8]);
    }
    #pragma unroll
    for (int i = 0; i < 4; i++)
      #pragma unroll
      for (int j = 0; j < 4; j++)
        acc[i][j] = __builtin_amdgcn_mfma_f32_16x16x32_bf16(af[i], bfv[j], acc[i][j], 0, 0, 0);
    __syncthreads();
  }

  const int gm0 = by * 128 + wr, gn0 = bx * 128 + wc;
  #pragma unroll
  for (int i = 0; i < 4; i++){
    #pragma unroll
    for (int r = 0; r < 4; r++){
      int gm = gm0 + i * 16 + l4 * 4 + r;
      int orow = rowperm ? ((gm & 63) * 128 + (gm >> 6)) : gm;
      #pragma unroll
      for (int j = 0; j < 4; j++){
        int gn = gn0 + j * 16 + l15;
        float v = acc[i][j][r];
        if (bias) v += bias[gn];
        if (act)  v = v * (1.0f / (1.0f + expf(-1.702f * v)));  // QuickGELU
        if (addsrc) v += addsrc[(size_t)orow * N + gn];
        if (outbf16) ((u16*)C)[(size_t)orow * N + gn] = f2b(v);
        else         ((float*)C)[(size_t)orow * N + gn] = v;
      }
    }
  }
}

// ---- MFMA Perceiver attention: block=(bt,head), 4 waves x 16 q-rows ----
// q: bf16 (512)[512]; kvx (32768)[1024]; kvll (512)[1024]; o (8192)[512]
__global__ __launch_bounds__(256) void pattn_k(
    const u16* __restrict__ q, const u16* __restrict__ kvx,
    const u16* __restrict__ kvll, u16* __restrict__ o)
{
  __shared__ __align__(16) u16 Ks[64][72];
  __shared__ __align__(16) u16 Vs[64][72];
  __shared__ __align__(16) u16 Ps[64][72];
  const int blk = blockIdx.x;            // bt*8 + h
  const int hh = blk & 7, bt = blk >> 3;
  const int tt = bt & 7;
  const int tid = threadIdx.x;
  const int wv = tid >> 6, ln = tid & 63;
  const int l15 = ln & 15, lg = ln >> 4;
  const int i0 = wv * 16;
  const int sj = tid >> 2, sc = (tid & 3) * 16;

  // Q fragments (2 k-halves of d=64), straight from global bf16
  bhalf8 qf[2];
  {
    const u16* qp = q + ((size_t)(tt * 64 + i0 + l15)) * 512 + hh * 64 + lg * 8;
    qf[0] = *(const bhalf8*)(qp);
    qf[1] = *(const bhalf8*)(qp + 32);
  }

  floatx4 sacc[20];
  #pragma unroll
  for (int t = 0; t < 20; t++) sacc[t] = (floatx4){0.f,0.f,0.f,0.f};

  // ---- pass 1: S = Q @ K^T over 5 chunks of 64 keys ----
  for (int ch = 0; ch < 5; ++ch){
    const u16* src = (ch < 4)
        ? (kvx  + ((size_t)(bt * 256 + ch * 64 + sj)) * 1024 + hh * 64 + sc)
        : (kvll + ((size_t)(tt * 64 + sj)) * 1024 + hh * 64 + sc);
    u16x8 k0 = *(const u16x8*)(src);
    u16x8 k1 = *(const u16x8*)(src + 8);
    __syncthreads();                       // prior mfma reads of Ks done
    *(u16x8*)(&Ks[sj][sc])     = k0;
    *(u16x8*)(&Ks[sj][sc + 8]) = k1;
    __syncthreads();
    #pragma unroll
    for (int jt = 0; jt < 4; jt++){
      bhalf8 kf0 = *(const bhalf8*)(&Ks[jt*16 + l15][lg*8]);
      bhalf8 kf1 = *(const bhalf8*)(&Ks[jt*16 + l15][32 + lg*8]);
      sacc[ch*4+jt] = __builtin_amdgcn_mfma_f32_16x16x32_bf16(qf[0], kf0, sacc[ch*4+jt], 0,0,0);
      sacc[ch*4+jt] = __builtin_amdgcn_mfma_f32_16x16x32_bf16(qf[1], kf1, sacc[ch*4+jt], 0,0,0);
    }
  }

  // ---- exact softmax in registers (scale 0.125 folded) ----
  float inv_l[4];
  float mx[4];
  #pragma unroll
  for (int r = 0; r < 4; r++){
    float m = -1e30f;
    #pragma unroll
    for (int t = 0; t < 20; t++) m = fmaxf(m, sacc[t][r]);
    m = fmaxf(m, __shfl_xor(m, 1));
    m = fmaxf(m, __shfl_xor(m, 2));
    m = fmaxf(m, __shfl_xor(m, 4));
    m = fmaxf(m, __shfl_xor(m, 8));
    mx[r] = m;
  }
  #pragma unroll
  for (int r = 0; r < 4; r++){
    float s = 0.f;
    #pragma unroll
    for (int t = 0; t < 20; t++){
      float p = expf(0.125f * (sacc[t][r] - mx[r]));
      sacc[t][r] = p;
      s += p;
    }
    s += __shfl_xor(s, 1); s += __shfl_xor(s, 2);
    s += __shfl_xor(s, 4); s += __shfl_xor(s, 8);
    inv_l[r] = 1.0f / s;
  }

  // ---- pass 2: O = P @ V over 5 chunks ----
  floatx4 oacc[4];
  #pragma unroll
  for (int dt = 0; dt < 4; dt++) oacc[dt] = (floatx4){0.f,0.f,0.f,0.f};
  for (int ch = 0; ch < 5; ++ch){
    const u16* src = (ch < 4)
        ? (kvx  + ((size_t)(bt * 256 + ch * 64 + sj)) * 1024 + 512 + hh * 64 + sc)
        : (kvll + ((size_t)(tt * 64 + sj)) * 1024 + 512 + hh * 64 + sc);
    u16x8 v0 = *(const u16x8*)(src);
    u16x8 v1 = *(const u16x8*)(src + 8);
    __syncthreads();                       // prior mfma reads of Vs/Ps done
    #pragma unroll
    for (int e = 0; e < 8; e++) Vs[sc + e][sj]     = v0[e];
    #pragma unroll
    for (int e = 0; e < 8; e++) Vs[sc + 8 + e][sj] = v1[e];
    #pragma unroll
    for (int jt = 0; jt < 4; jt++){
      #pragma unroll
      for (int r = 0; r < 4; r++)
        Ps[i0 + 4*lg + r][jt*16 + l15] = f2b(sacc[ch*4+jt][r]);
    }
    __syncthreads();
    #pragma unroll
    for (int kk = 0; kk < 2; kk++){
      bhalf8 pf = *(const bhalf8*)(&Ps[i0 + l15][kk*32 + lg*8]);
      #pragma unroll
      for (int dt = 0; dt < 4; dt++){
        bhalf8 vfr = *(const bhalf8*)(&Vs[dt*16 + l15][kk*32 + lg*8]);
        oacc[dt] = __builtin_amdgcn_mfma_f32_16x16x32_bf16(pf, vfr, oacc[dt], 0,0,0);
      }
    }
  }

  u16* op = o + ((size_t)(bt*64 + i0 + 4*lg)) * 512 + hh*64 + l15;
  #pragma unroll
  for (int dt = 0; dt < 4; dt++)
    #pragma unroll
    for (int r = 0; r < 4; r++)
      op[(size_t)r * 512 + dt*16] = f2b(oacc[dt][r] * inv_l[r]);
}

// ---- MFMA self-attention: block=(bt,head), 4 waves x 16 q-rows, 64 keys ----
// qkv bf16 (8192 rows: i*128+bt)[2304]; o2 (8192 rows: i*128+bt)[768]
__global__ __launch_bounds__(256) void sattn_k(
    const u16* __restrict__ qkv, u16* __restrict__ o2)
{
  __shared__ __align__(16) u16 Ks[64][72];
  __shared__ __align__(16) u16 Vs[64][72];
  __shared__ __align__(16) u16 Ps[64][72];
  const int blk = blockIdx.x;
  const int hh = blk % 12, bt = blk / 12;
  const int tid = threadIdx.x;
  const int wv = tid >> 6, ln = tid & 63;
  const int l15 = ln & 15, lg = ln >> 4;
  const int i0 = wv * 16;
  const int sj = tid >> 2, sc = (tid & 3) * 16;

  // stage K and V^T
  const u16* kp = qkv + ((size_t)sj * 128 + bt) * 2304 + 768 + hh * 64 + sc;
  u16x8 k0 = *(const u16x8*)(kp);
  u16x8 k1 = *(const u16x8*)(kp + 8);
  u16x8 v0 = *(const u16x8*)(kp + 768);
  u16x8 v1 = *(const u16x8*)(kp + 776);
  *(u16x8*)(&Ks[sj][sc])     = k0;
  *(u16x8*)(&Ks[sj][sc + 8]) = k1;
  #pragma unroll
  for (int e = 0; e < 8; e++) Vs[sc + e][sj]     = v0[e];
  #pragma unroll
  for (int e = 0; e < 8; e++) Vs[sc + 8 + e][sj] = v1[e];

  // Q fragments
  bhalf8 qf[2];
  {
    const u16* qp = qkv + ((size_t)(i0 + l15) * 128 + bt) * 2304 + hh * 64 + lg * 8;
    qf[0] = *(const bhalf8*)(qp);
    qf[1] = *(const bhalf8*)(qp + 32);
  }
  __syncthreads();

  floatx4 sacc[4];
  #pragma unroll
  for (int t = 0; t < 4; t++) sacc[t] = (floatx4){0.f,0.f,0.f,0.f};
  #pragma unroll
  for (int jt = 0; jt < 4; jt++){
    bhalf8 kf0 = *(const bhalf8*)(&Ks[jt*16 + l15][lg*8]);
    bhalf8 kf1 = *(const bhalf8*)(&Ks[jt*16 + l15][32 + lg*8]);
    sacc[jt] = __builtin_amdgcn_mfma_f32_16x16x32_bf16(qf[0], kf0, sacc[jt], 0,0,0);
    sacc[jt] = __builtin_amdgcn_mfma_f32_16x16x32_bf16(qf[1], kf1, sacc[jt], 0,0,0);
  }

  float inv_l[4];
  #pragma unroll
  for (int r = 0; r < 4; r++){
    float m = -1e30f;
    #pragma unroll
    for (int t = 0; t < 4; t++) m = fmaxf(m, sacc[t][r]);
    m = fmaxf(m, __shfl_xor(m, 1));
    m = fmaxf(m, __shfl_xor(m, 2));
    m = fmaxf(m, __shfl_xor(m, 4));
    m = fmaxf(m, __shfl_xor(m, 8));
    float s = 0.f;
    #pragma unroll
    for (int t = 0; t < 4; t++){
      float p = expf(0.125f * (sacc[t][r] - m));
      sacc[t][r] = p;
      s += p;
    }
    s += __shfl_xor(s, 1); s += __shfl_xor(s, 2);
    s += __shfl_xor(s, 4); s += __shfl_xor(s, 8);
    inv_l[r] = 1.0f / s;
  }

  #pragma unroll
  for (int jt = 0; jt < 4; jt++){
    #pragma unroll
    for (int r = 0; r < 4; r++)
      Ps[i0 + 4*lg + r][jt*16 + l15] = f2b(sacc[jt][r]);
  }
  __syncthreads();

  floatx4 oacc[4];
  #pragma unroll
  for (int dt = 0; dt < 4; dt++) oacc[dt] = (floatx4){0.f,0.f,0.f,0.f};
  #pragma unroll
  for (int kk = 0; kk < 2; kk++){
    bhalf8 pf = *(const bhalf8*)(&Ps[i0 + l15][kk*32 + lg*8]);
    #pragma unroll
    for (int dt = 0; dt < 4; dt++){
      bhalf8 vfr = *(const bhalf8*)(&Vs[dt*16 + l15][kk*32 + lg*8]);
      oacc[dt] = __builtin_amdgcn_mfma_f32_16x16x32_bf16(pf, vfr, oacc[dt], 0,0,0);
    }
  }

  u16* op = o2 + ((size_t)((i0 + 4*lg) * 128 + bt)) * 768 + hh*64 + l15;
  #pragma unroll
  for (int dt = 0; dt < 4; dt++)
    #pragma unroll
    for (int r = 0; r < 4; r++)
      op[(size_t)r * 128 * 768 + dt*16] = f2b(oacc[dt][r] * inv_l[r]);
}

extern "C" void kernel_launch(void* const* d_in, const int* in_sizes, int n_in,
                              void* d_out, int out_size, void* d_ws, size_t ws_size,
                              hipStream_t stream)
{
  const float* vf   = (const float*)d_in[0];
  const float* lat  = (const float*)d_in[1];
  const float* nl0g = (const float*)d_in[2];
  const float* nl0b = (const float*)d_in[3];
  const float* pmg  = (const float*)d_in[4];
  const float* pmb  = (const float*)d_in[5];
  const float* plg  = (const float*)d_in[6];
  const float* plb  = (const float*)d_in[7];
  const float* Wq   = (const float*)d_in[8];
  const float* Wkv  = (const float*)d_in[9];
  const float* Wo   = (const float*)d_in[10];
  const float* ln1g = (const float*)d_in[11];
  const float* ln1b = (const float*)d_in[12];
  const float* Wqkv = (const float*)d_in[13];
  const float* bqkv = (const float*)d_in[14];
  const float* Wout = (const float*)d_in[15];
  const float* bout = (const float*)d_in[16];
  const float* ln2g = (const float*)d_in[17];
  const float* ln2b = (const float*)d_in[18];
  const float* Wfc  = (const float*)d_in[19];
  const float* bfc  = (const float*)d_in[20];
  const float* Wpr  = (const float*)d_in[21];
  const float* bpr  = (const float*)d_in[22];

  // ---- ws layout, high-water 104,857,600 B ----
  char* ws = (char*)d_ws;
  u16*    kvx   = (u16*)(ws + 0);          // 67,108,864 (dead after pattn)
  u16*    qkvb  = (u16*)(ws + 0);          // 37,748,736 (dead after sattn)
  u16*    o2b   = (u16*)(ws + 37748736);   // 12,582,912 (dead after Wout gemm)
  u16*    hb    = (u16*)(ws + 0);          // 50,331,648
  u16*    WoT   = (u16*)(ws + 50331648);
  u16*    WqkvT = (u16*)(ws + 51118080);
  u16*    WoutT = (u16*)(ws + 54657024);
  u16*    WfcT  = (u16*)(ws + 55836672);
  u16*    WprT  = (u16*)(ws + 60555264);   // ends 65,273,856
  u16*    WqT   = (u16*)(ws + 67108864);
  u16*    WkvT  = (u16*)(ws + 67895296);   // ends 69,468,160
  float*  yb    = (float*)(ws + 67108864); // written after WqT/WkvT dead
  u16*    llb   = (u16*)(ws + 92274688);
  float2* stx   = (float2*)(ws + 93061120);
  u16*    qb    = (u16*)(ws + 93323264);   // 512x512 bf16 now
  u16*    kvll  = (u16*)(ws + 94371840);
  u16*    ob    = (u16*)(ws + 95420416);   // ends 103,809,024
  u16*    zb    = (u16*)(ws + 92274688);   // overlays ll..ob when dead

  const float* nof = nullptr;
  const float2* nos = nullptr;

  hipLaunchKernelGGL(transp_k, dim3(384), dim3(256), 0, stream, Wq, WqT, 768, 512);
  hipLaunchKernelGGL(transp_k, dim3(768), dim3(256), 0, stream, Wkv, WkvT, 768, 1024);
  hipLaunchKernelGGL(stats_x_k, dim3(32768), dim3(256), 0, stream, vf, stx);
  hipLaunchKernelGGL(ln_lat2_k, dim3(512), dim3(256), 0, stream,
                     lat, llb, nl0g, nl0b, plg, plb);
  // q = ll @ Wq -> bf16 (scale applied inside pattn)
  hipLaunchKernelGGL(mgemm_k<0>, dim3(16), dim3(256), 0, stream,
                     (const void*)llb, WqT, (void*)qb, 512, 512, 768,
                     nof, 0, nof, 0, 1, nos, nof, nof);
  hipLaunchKernelGGL(mgemm_k<0>, dim3(32), dim3(256), 0, stream,
                     (const void*)llb, WkvT, (void*)kvll, 512, 1024, 768,
                     nof, 0, nof, 0, 1, nos, nof, nof);
  hipLaunchKernelGGL(mgemm_k<1>, dim3(2048), dim3(256), 0, stream,
                     (const void*)vf, WkvT, (void*)kvx, 32768, 1024, 768,
                     nof, 0, nof, 0, 1, stx, pmg, pmb);
  hipLaunchKernelGGL(pattn_k, dim3(1024), dim3(256), 0, stream, qb, kvx, kvll, ob);
  hipLaunchKernelGGL(transp_k, dim3(384), dim3(256), 0, stream, Wo, WoT, 512, 768);
  hipLaunchKernelGGL(transp_k, dim3(1728), dim3(256), 0, stream, Wqkv, WqkvT, 768, 2304);
  hipLaunchKernelGGL(transp_k, dim3(576), dim3(256), 0, stream, Wout, WoutT, 768, 768);
  hipLaunchKernelGGL(transp_k, dim3(2304), dim3(256), 0, stream, Wfc, WfcT, 768, 3072);
  hipLaunchKernelGGL(transp_k, dim3(2304), dim3(256), 0, stream, Wpr, WprT, 3072, 768);
  hipLaunchKernelGGL(mgemm_k<0>, dim3(384), dim3(256), 0, stream,
                     (const void*)ob, WoT, (void*)yb, 8192, 768, 512,
                     nof, 0, nof, 1, 0, nos, nof, nof);
  hipLaunchKernelGGL(ln_f32_k, dim3(8192), dim3(256), 0, stream, yb, zb, ln1g, ln1b);
  hipLaunchKernelGGL(mgemm_k<0>, dim3(1152), dim3(256), 0, stream,
                     (const void*)zb, WqkvT, (void*)qkvb, 8192, 2304, 768,
                     bqkv, 0, nof, 0, 1, nos, nof, nof);
  hipLaunchKernelGGL(sattn_k, dim3(1536), dim3(256), 0, stream, qkvb, o2b);
  hipLaunchKernelGGL(mgemm_k<0>, dim3(384), dim3(256), 0, stream,
                     (const void*)o2b, WoutT, (void*)yb, 8192, 768, 768,
                     bout, 0, yb, 0, 0, nos, nof, nof);
  hipLaunchKernelGGL(ln_f32_k, dim3(8192), dim3(256), 0, stream, yb, zb, ln2g, ln2b);
  hipLaunchKernelGGL(mgemm_k<0>, dim3(1536), dim3(256), 0, stream,
                     (const void*)zb, WfcT, (void*)hb, 8192, 3072, 768,
                     bfc, 1, nof, 0, 1, nos, nof, nof);
  hipLaunchKernelGGL(mgemm_k<0>, dim3(384), dim3(256), 0, stream,
                     (const void*)hb, WprT, d_out, 8192, 768, 3072,
                     bpr, 0, yb, 0, 0, nos, nof, nof);
}

// Round 6
// 625.704 us; speedup vs baseline: 6.5138x; 1.0834x over previous
//
#include <hip/hip_runtime.h>
#include <hip/hip_bf16.h>
#include <cstdint>
#include <cstddef>

typedef unsigned short u16;
typedef __bf16 bhalf8 __attribute__((ext_vector_type(8)));
typedef float floatx4 __attribute__((ext_vector_type(4)));
typedef unsigned short u16x8 __attribute__((ext_vector_type(8)));

__device__ __forceinline__ float b2f(u16 u){
  union { uint32_t i; float f; } x; x.i = ((uint32_t)u) << 16; return x.f;
}
__device__ __forceinline__ u16 f2b(float f){
  uint32_t i = __float_as_uint(f);
  uint32_t r = (i + 0x7FFFu + ((i >> 16) & 1u)) >> 16;   // round-nearest-even
  return (u16)r;
}

// ---- block-wide sum over 256 threads (4 waves) ----
__device__ __forceinline__ float block_sum256(float v, float* sh){
  #pragma unroll
  for (int o = 32; o > 0; o >>= 1) v += __shfl_down(v, o);
  __syncthreads();
  if ((threadIdx.x & 63u) == 0) sh[threadIdx.x >> 6] = v;
  __syncthreads();
  return sh[0] + sh[1] + sh[2] + sh[3];
}

// ---- per-row LN stats of visual_feat (fp32), rearranged row order ----
__global__ __launch_bounds__(256) void stats_x_k(
    const float* __restrict__ vf, float2* __restrict__ st)
{
  __shared__ float sh[4];
  const int r  = blockIdx.x;
  const int nn = r & 255, bt = r >> 8;
  const float* in = vf + ((size_t)nn * 128 + bt) * 768;
  const int t = threadIdx.x;
  float v0 = in[t], v1 = in[t + 256], v2 = in[t + 512];
  float mean = block_sum256(v0 + v1 + v2, sh) * (1.0f / 768.0f);
  float d0 = v0 - mean, d1 = v1 - mean, d2 = v2 - mean;
  float var = block_sum256(d0*d0 + d1*d1 + d2*d2, sh) * (1.0f / 768.0f);
  if (t == 0) st[r] = make_float2(mean, rsqrtf(var + 1e-5f));
}

// ---- full LN of visual_feat -> bf16 xm, rearranged row order ----
__global__ __launch_bounds__(256) void ln_x_k(
    const float* __restrict__ vf, u16* __restrict__ xm,
    const float* __restrict__ g, const float* __restrict__ b)
{
  __shared__ float sh[4];
  const int r  = blockIdx.x;             // r = bt*256 + nn
  const int nn = r & 255, bt = r >> 8;
  const float* in = vf + ((size_t)nn * 128 + bt) * 768;
  const int t = threadIdx.x;
  float v[3];
  #pragma unroll
  for (int i = 0; i < 3; i++) v[i] = in[t + 256 * i];
  float mean = block_sum256(v[0] + v[1] + v[2], sh) * (1.0f / 768.0f);
  float d0 = v[0] - mean, d1 = v[1] - mean, d2 = v[2] - mean;
  float var = block_sum256(d0*d0 + d1*d1 + d2*d2, sh) * (1.0f / 768.0f);
  float rs = rsqrtf(var + 1e-5f);
  #pragma unroll
  for (int i = 0; i < 3; i++){
    int c = t + 256 * i;
    xm[(size_t)r * 768 + c] = f2b((v[i] - mean) * rs * g[c] + b[c]);
  }
}

// ---- double LayerNorm of latents (fp32 in) -> bf16 ----
__global__ __launch_bounds__(256) void ln_lat2_k(
    const float* __restrict__ lat, u16* __restrict__ ll,
    const float* __restrict__ g0, const float* __restrict__ b0,
    const float* __restrict__ g1, const float* __restrict__ b1)
{
  __shared__ float sh[4];
  const int r = blockIdx.x;
  const int t = threadIdx.x;
  const float* in = lat + (size_t)r * 768;
  float v[3];
  #pragma unroll
  for (int i = 0; i < 3; i++) v[i] = in[t + 256 * i];
  #pragma unroll
  for (int pass = 0; pass < 2; ++pass){
    float mean = block_sum256(v[0] + v[1] + v[2], sh) * (1.0f / 768.0f);
    float d0 = v[0] - mean, d1 = v[1] - mean, d2 = v[2] - mean;
    float var = block_sum256(d0*d0 + d1*d1 + d2*d2, sh) * (1.0f / 768.0f);
    float rs = rsqrtf(var + 1e-5f);
    const float* g = pass ? g1 : g0;
    const float* b = pass ? b1 : b0;
    #pragma unroll
    for (int i = 0; i < 3; i++){
      int c = t + 256 * i;
      v[i] = (v[i] - mean) * rs * g[c] + b[c];
    }
  }
  #pragma unroll
  for (int i = 0; i < 3; i++) ll[(size_t)r * 768 + t + 256 * i] = f2b(v[i]);
}

// ---- LN of fp32 ws rows -> bf16 ----
__global__ __launch_bounds__(256) void ln_f32_k(
    const float* __restrict__ y, u16* __restrict__ z,
    const float* __restrict__ g, const float* __restrict__ b)
{
  __shared__ float sh[4];
  const int r = blockIdx.x;
  const float* in = y + (size_t)r * 768;
  const int t = threadIdx.x;
  float v[3];
  #pragma unroll
  for (int i = 0; i < 3; i++) v[i] = in[t + 256 * i];
  float mean = block_sum256(v[0] + v[1] + v[2], sh) * (1.0f / 768.0f);
  float d0 = v[0] - mean, d1 = v[1] - mean, d2 = v[2] - mean;
  float var = block_sum256(d0*d0 + d1*d1 + d2*d2, sh) * (1.0f / 768.0f);
  float rs = rsqrtf(var + 1e-5f);
  #pragma unroll
  for (int i = 0; i < 3; i++){
    int c = t + 256 * i;
    z[(size_t)r * 768 + c] = f2b((v[i] - mean) * rs * g[c] + b[c]);
  }
}

// ---- weight transpose + bf16 convert: src (K,N) f32 -> dst (N,K) bf16 ----
__global__ __launch_bounds__(256) void transp_k(
    const float* __restrict__ src, u16* __restrict__ dst, int K, int N)
{
  __shared__ u16 sh[32][33];
  const int nb = N >> 5;
  const int bx = blockIdx.x % nb, byy = blockIdx.x / nb;
  const int tx = threadIdx.x & 31, ty = threadIdx.x >> 5;
  #pragma unroll
  for (int i = 0; i < 4; i++){
    int k = byy * 32 + ty + i * 8, n = bx * 32 + tx;
    sh[tx][ty + i * 8] = f2b(src[(size_t)k * N + n]);
  }
  __syncthreads();
  #pragma unroll
  for (int i = 0; i < 4; i++){
    int n = bx * 32 + ty + i * 8, k = byy * 32 + tx;
    dst[(size_t)n * K + k] = sh[ty + i * 8][tx];
  }
}

// ---- MFMA GEMM: C[M,N] = act(A@B + bias) + addsrc ----
// XCD-grouping swizzle: grid must be divisible by 8; grid/8 a multiple of nb.
// AMODE 0: A bf16 (M,K); AMODE 1: A fp32 vf + fused LN + row remap.
template<int AMODE>
__global__ __launch_bounds__(256) void mgemm_k(
    const void* __restrict__ A, const u16* __restrict__ BT, void* __restrict__ C,
    int M, int N, int K,
    const float* __restrict__ bias, int act,
    const float* addsrc, int rowperm, int outbf16,
    const float2* __restrict__ stx, const float* __restrict__ gam,
    const float* __restrict__ bet)
{
  __shared__ __align__(16) u16 As[128][40];
  __shared__ __align__(16) u16 Bs[128][40];
  const int nb = N >> 7;
  const int swz = ((blockIdx.x & 7) * (gridDim.x >> 3)) + (blockIdx.x >> 3);
  const int bx = swz % nb, by = swz / nb;
  const int tid  = threadIdx.x;
  const int wave = tid >> 6, lane = tid & 63;
  const int wr = (wave >> 1) * 64, wc = (wave & 1) * 64;
  const int l15 = lane & 15, l4 = lane >> 4;
  const int sr = tid >> 2, sq = (tid & 3) * 8;

  const u16*   Abf = (const u16*)A;
  const float* Af  = (const float*)A;

  int   asrc[2]; float mn[2], rs[2];
  #pragma unroll
  for (int p = 0; p < 2; p++){
    int gm = by * 128 + sr + p * 64;
    if (AMODE == 1){
      asrc[p] = (gm & 255) * 128 + (gm >> 8);
      float2 s = stx[gm]; mn[p] = s.x; rs[p] = s.y;
    } else asrc[p] = gm;
  }

  floatx4 acc[4][4];
  #pragma unroll
  for (int i = 0; i < 4; i++)
    #pragma unroll
    for (int j = 0; j < 4; j++) acc[i][j] = (floatx4){0.f, 0.f, 0.f, 0.f};

  for (int k0 = 0; k0 < K; k0 += 32){
    #pragma unroll
    for (int p = 0; p < 2; p++){
      const int r = sr + p * 64;
      if (AMODE == 0){
        u16x8 v = *(const u16x8*)(Abf + (size_t)asrc[p] * K + k0 + sq);
        *(u16x8*)(&As[r][sq]) = v;
      } else {
        const float* ap = Af + (size_t)asrc[p] * K + k0 + sq;
        float4 f0 = *(const float4*)ap, f1 = *(const float4*)(ap + 4);
        float4 g0 = *(const float4*)(gam + k0 + sq), g1 = *(const float4*)(gam + k0 + sq + 4);
        float4 e0 = *(const float4*)(bet + k0 + sq), e1 = *(const float4*)(bet + k0 + sq + 4);
        u16x8 v;
        v[0] = f2b((f0.x - mn[p]) * rs[p] * g0.x + e0.x);
        v[1] = f2b((f0.y - mn[p]) * rs[p] * g0.y + e0.y);
        v[2] = f2b((f0.z - mn[p]) * rs[p] * g0.z + e0.z);
        v[3] = f2b((f0.w - mn[p]) * rs[p] * g0.w + e0.w);
        v[4] = f2b((f1.x - mn[p]) * rs[p] * g1.x + e1.x);
        v[5] = f2b((f1.y - mn[p]) * rs[p] * g1.y + e1.y);
        v[6] = f2b((f1.z - mn[p]) * rs[p] * g1.z + e1.z);
        v[7] = f2b((f1.w - mn[p]) * rs[p] * g1.w + e1.w);
        *(u16x8*)(&As[r][sq]) = v;
      }
      u16x8 w = *(const u16x8*)(BT + (size_t)(bx * 128 + r) * K + k0 + sq);
      *(u16x8*)(&Bs[r][sq]) = w;
    }
    __syncthreads();
    bhalf8 af[4], bfv[4];
    #pragma unroll
    for (int i = 0; i < 4; i++){
      af[i]  = *(const bhalf8*)(&As[wr + i * 16 + l15][l4 * 8]);
      bfv[i] = *(const bhalf8*)(&Bs[wc + i * 16 + l15][l4 * 8]);
    }
    #pragma unroll
    for (int i = 0; i < 4; i++)
      #pragma unroll
      for (int j = 0; j < 4; j++)
        acc[i][j] = __builtin_amdgcn_mfma_f32_16x16x32_bf16(af[i], bfv[j], acc[i][j], 0, 0, 0);
    __syncthreads();
  }

  const int gm0 = by * 128 + wr, gn0 = bx * 128 + wc;
  #pragma unroll
  for (int i = 0; i < 4; i++){
    #pragma unroll
    for (int r = 0; r < 4; r++){
      int gm = gm0 + i * 16 + l4 * 4 + r;
      int orow = rowperm ? ((gm & 63) * 128 + (gm >> 6)) : gm;
      #pragma unroll
      for (int j = 0; j < 4; j++){
        int gn = gn0 + j * 16 + l15;
        float v = acc[i][j][r];
        if (bias) v += bias[gn];
        if (act)  v = v * (1.0f / (1.0f + expf(-1.702f * v)));  // QuickGELU
        if (addsrc) v += addsrc[(size_t)orow * N + gn];
        if (outbf16) ((u16*)C)[(size_t)orow * N + gn] = f2b(v);
        else         ((float*)C)[(size_t)orow * N + gn] = v;
      }
    }
  }
}

// ---- MFMA Perceiver attention: block=(bt,head), 4 waves x 16 q-rows ----
__global__ __launch_bounds__(256) void pattn_k(
    const u16* __restrict__ q, const u16* __restrict__ kvx,
    const u16* __restrict__ kvll, u16* __restrict__ o)
{
  __shared__ __align__(16) u16 Ks[64][72];
  __shared__ __align__(16) u16 Vs[64][72];
  __shared__ __align__(16) u16 Ps[64][72];
  const int blk = blockIdx.x;            // bt*8 + h
  const int hh = blk & 7, bt = blk >> 3;
  const int tt = bt & 7;
  const int tid = threadIdx.x;
  const int wv = tid >> 6, ln = tid & 63;
  const int l15 = ln & 15, lg = ln >> 4;
  const int i0 = wv * 16;
  const int sj = tid >> 2, sc = (tid & 3) * 16;

  bhalf8 qf[2];
  {
    const u16* qp = q + ((size_t)(tt * 64 + i0 + l15)) * 512 + hh * 64 + lg * 8;
    qf[0] = *(const bhalf8*)(qp);
    qf[1] = *(const bhalf8*)(qp + 32);
  }

  floatx4 sacc[20];
  #pragma unroll
  for (int t = 0; t < 20; t++) sacc[t] = (floatx4){0.f,0.f,0.f,0.f};

  for (int ch = 0; ch < 5; ++ch){
    const u16* src = (ch < 4)
        ? (kvx  + ((size_t)(bt * 256 + ch * 64 + sj)) * 1024 + hh * 64 + sc)
        : (kvll + ((size_t)(tt * 64 + sj)) * 1024 + hh * 64 + sc);
    u16x8 k0 = *(const u16x8*)(src);
    u16x8 k1 = *(const u16x8*)(src + 8);
    __syncthreads();
    *(u16x8*)(&Ks[sj][sc])     = k0;
    *(u16x8*)(&Ks[sj][sc + 8]) = k1;
    __syncthreads();
    #pragma unroll
    for (int jt = 0; jt < 4; jt++){
      bhalf8 kf0 = *(const bhalf8*)(&Ks[jt*16 + l15][lg*8]);
      bhalf8 kf1 = *(const bhalf8*)(&Ks[jt*16 + l15][32 + lg*8]);
      sacc[ch*4+jt] = __builtin_amdgcn_mfma_f32_16x16x32_bf16(qf[0], kf0, sacc[ch*4+jt], 0,0,0);
      sacc[ch*4+jt] = __builtin_amdgcn_mfma_f32_16x16x32_bf16(qf[1], kf1, sacc[ch*4+jt], 0,0,0);
    }
  }

  float inv_l[4];
  float mx[4];
  #pragma unroll
  for (int r = 0; r < 4; r++){
    float m = -1e30f;
    #pragma unroll
    for (int t = 0; t < 20; t++) m = fmaxf(m, sacc[t][r]);
    m = fmaxf(m, __shfl_xor(m, 1));
    m = fmaxf(m, __shfl_xor(m, 2));
    m = fmaxf(m, __shfl_xor(m, 4));
    m = fmaxf(m, __shfl_xor(m, 8));
    mx[r] = m;
  }
  #pragma unroll
  for (int r = 0; r < 4; r++){
    float s = 0.f;
    #pragma unroll
    for (int t = 0; t < 20; t++){
      float p = expf(0.125f * (sacc[t][r] - mx[r]));
      sacc[t][r] = p;
      s += p;
    }
    s += __shfl_xor(s, 1); s += __shfl_xor(s, 2);
    s += __shfl_xor(s, 4); s += __shfl_xor(s, 8);
    inv_l[r] = 1.0f / s;
  }

  floatx4 oacc[4];
  #pragma unroll
  for (int dt = 0; dt < 4; dt++) oacc[dt] = (floatx4){0.f,0.f,0.f,0.f};
  for (int ch = 0; ch < 5; ++ch){
    const u16* src = (ch < 4)
        ? (kvx  + ((size_t)(bt * 256 + ch * 64 + sj)) * 1024 + 512 + hh * 64 + sc)
        : (kvll + ((size_t)(tt * 64 + sj)) * 1024 + 512 + hh * 64 + sc);
    u16x8 v0 = *(const u16x8*)(src);
    u16x8 v1 = *(const u16x8*)(src + 8);
    __syncthreads();
    #pragma unroll
    for (int e = 0; e < 8; e++) Vs[sc + e][sj]     = v0[e];
    #pragma unroll
    for (int e = 0; e < 8; e++) Vs[sc + 8 + e][sj] = v1[e];
    #pragma unroll
    for (int jt = 0; jt < 4; jt++){
      #pragma unroll
      for (int r = 0; r < 4; r++)
        Ps[i0 + 4*lg + r][jt*16 + l15] = f2b(sacc[ch*4+jt][r]);
    }
    __syncthreads();
    #pragma unroll
    for (int kk = 0; kk < 2; kk++){
      bhalf8 pf = *(const bhalf8*)(&Ps[i0 + l15][kk*32 + lg*8]);
      #pragma unroll
      for (int dt = 0; dt < 4; dt++){
        bhalf8 vfr = *(const bhalf8*)(&Vs[dt*16 + l15][kk*32 + lg*8]);
        oacc[dt] = __builtin_amdgcn_mfma_f32_16x16x32_bf16(pf, vfr, oacc[dt], 0,0,0);
      }
    }
  }

  u16* op = o + ((size_t)(bt*64 + i0 + 4*lg)) * 512 + hh*64 + l15;
  #pragma unroll
  for (int dt = 0; dt < 4; dt++)
    #pragma unroll
    for (int r = 0; r < 4; r++)
      op[(size_t)r * 512 + dt*16] = f2b(oacc[dt][r] * inv_l[r]);
}

// ---- MFMA self-attention: block=(bt,head), 4 waves x 16 q-rows, 64 keys ----
__global__ __launch_bounds__(256) void sattn_k(
    const u16* __restrict__ qkv, u16* __restrict__ o2)
{
  __shared__ __align__(16) u16 Ks[64][72];
  __shared__ __align__(16) u16 Vs[64][72];
  __shared__ __align__(16) u16 Ps[64][72];
  const int blk = blockIdx.x;
  const int hh = blk % 12, bt = blk / 12;
  const int tid = threadIdx.x;
  const int wv = tid >> 6, ln = tid & 63;
  const int l15 = ln & 15, lg = ln >> 4;
  const int i0 = wv * 16;
  const int sj = tid >> 2, sc = (tid & 3) * 16;

  const u16* kp = qkv + ((size_t)sj * 128 + bt) * 2304 + 768 + hh * 64 + sc;
  u16x8 k0 = *(const u16x8*)(kp);
  u16x8 k1 = *(const u16x8*)(kp + 8);
  u16x8 v0 = *(const u16x8*)(kp + 768);
  u16x8 v1 = *(const u16x8*)(kp + 776);
  *(u16x8*)(&Ks[sj][sc])     = k0;
  *(u16x8*)(&Ks[sj][sc + 8]) = k1;
  #pragma unroll
  for (int e = 0; e < 8; e++) Vs[sc + e][sj]     = v0[e];
  #pragma unroll
  for (int e = 0; e < 8; e++) Vs[sc + 8 + e][sj] = v1[e];

  bhalf8 qf[2];
  {
    const u16* qp = qkv + ((size_t)(i0 + l15) * 128 + bt) * 2304 + hh * 64 + lg * 8;
    qf[0] = *(const bhalf8*)(qp);
    qf[1] = *(const bhalf8*)(qp + 32);
  }
  __syncthreads();

  floatx4 sacc[4];
  #pragma unroll
  for (int t = 0; t < 4; t++) sacc[t] = (floatx4){0.f,0.f,0.f,0.f};
  #pragma unroll
  for (int jt = 0; jt < 4; jt++){
    bhalf8 kf0 = *(const bhalf8*)(&Ks[jt*16 + l15][lg*8]);
    bhalf8 kf1 = *(const bhalf8*)(&Ks[jt*16 + l15][32 + lg*8]);
    sacc[jt] = __builtin_amdgcn_mfma_f32_16x16x32_bf16(qf[0], kf0, sacc[jt], 0,0,0);
    sacc[jt] = __builtin_amdgcn_mfma_f32_16x16x32_bf16(qf[1], kf1, sacc[jt], 0,0,0);
  }

  float inv_l[4];
  #pragma unroll
  for (int r = 0; r < 4; r++){
    float m = -1e30f;
    #pragma unroll
    for (int t = 0; t < 4; t++) m = fmaxf(m, sacc[t][r]);
    m = fmaxf(m, __shfl_xor(m, 1));
    m = fmaxf(m, __shfl_xor(m, 2));
    m = fmaxf(m, __shfl_xor(m, 4));
    m = fmaxf(m, __shfl_xor(m, 8));
    float s = 0.f;
    #pragma unroll
    for (int t = 0; t < 4; t++){
      float p = expf(0.125f * (sacc[t][r] - m));
      sacc[t][r] = p;
      s += p;
    }
    s += __shfl_xor(s, 1); s += __shfl_xor(s, 2);
    s += __shfl_xor(s, 4); s += __shfl_xor(s, 8);
    inv_l[r] = 1.0f / s;
  }

  #pragma unroll
  for (int jt = 0; jt < 4; jt++){
    #pragma unroll
    for (int r = 0; r < 4; r++)
      Ps[i0 + 4*lg + r][jt*16 + l15] = f2b(sacc[jt][r]);
  }
  __syncthreads();

  floatx4 oacc[4];
  #pragma unroll
  for (int dt = 0; dt < 4; dt++) oacc[dt] = (floatx4){0.f,0.f,0.f,0.f};
  #pragma unroll
  for (int kk = 0; kk < 2; kk++){
    bhalf8 pf = *(const bhalf8*)(&Ps[i0 + l15][kk*32 + lg*8]);
    #pragma unroll
    for (int dt = 0; dt < 4; dt++){
      bhalf8 vfr = *(const bhalf8*)(&Vs[dt*16 + l15][kk*32 + lg*8]);
      oacc[dt] = __builtin_amdgcn_mfma_f32_16x16x32_bf16(pf, vfr, oacc[dt], 0,0,0);
    }
  }

  u16* op = o2 + ((size_t)((i0 + 4*lg) * 128 + bt)) * 768 + hh*64 + l15;
  #pragma unroll
  for (int dt = 0; dt < 4; dt++)
    #pragma unroll
    for (int r = 0; r < 4; r++)
      op[(size_t)r * 128 * 768 + dt*16] = f2b(oacc[dt][r] * inv_l[r]);
}

extern "C" void kernel_launch(void* const* d_in, const int* in_sizes, int n_in,
                              void* d_out, int out_size, void* d_ws, size_t ws_size,
                              hipStream_t stream)
{
  const float* vf   = (const float*)d_in[0];
  const float* lat  = (const float*)d_in[1];
  const float* nl0g = (const float*)d_in[2];
  const float* nl0b = (const float*)d_in[3];
  const float* pmg  = (const float*)d_in[4];
  const float* pmb  = (const float*)d_in[5];
  const float* plg  = (const float*)d_in[6];
  const float* plb  = (const float*)d_in[7];
  const float* Wq   = (const float*)d_in[8];
  const float* Wkv  = (const float*)d_in[9];
  const float* Wo   = (const float*)d_in[10];
  const float* ln1g = (const float*)d_in[11];
  const float* ln1b = (const float*)d_in[12];
  const float* Wqkv = (const float*)d_in[13];
  const float* bqkv = (const float*)d_in[14];
  const float* Wout = (const float*)d_in[15];
  const float* bout = (const float*)d_in[16];
  const float* ln2g = (const float*)d_in[17];
  const float* ln2b = (const float*)d_in[18];
  const float* Wfc  = (const float*)d_in[19];
  const float* bfc  = (const float*)d_in[20];
  const float* Wpr  = (const float*)d_in[21];
  const float* bpr  = (const float*)d_in[22];

  // ---- ws layout: base high-water 104,857,600 B; optional xm at 117.4M ----
  char* ws = (char*)d_ws;
  u16*    kvx   = (u16*)(ws + 0);          // 67,108,864 (dead after pattn)
  u16*    qkvb  = (u16*)(ws + 0);          // 37,748,736 (dead after sattn)
  u16*    o2b   = (u16*)(ws + 37748736);   // 12,582,912 (dead after Wout gemm)
  u16*    hb    = (u16*)(ws + 0);          // 50,331,648
  u16*    WoT   = (u16*)(ws + 50331648);
  u16*    WqkvT = (u16*)(ws + 51118080);
  u16*    WoutT = (u16*)(ws + 54657024);
  u16*    WfcT  = (u16*)(ws + 55836672);
  u16*    WprT  = (u16*)(ws + 60555264);   // ends 65,273,856
  u16*    WqT   = (u16*)(ws + 67108864);
  u16*    WkvT  = (u16*)(ws + 67895296);   // ends 69,468,160
  float*  yb    = (float*)(ws + 67108864); // written after WqT/WkvT dead
  u16*    llb   = (u16*)(ws + 92274688);
  float2* stx   = (float2*)(ws + 93061120);
  u16*    qb    = (u16*)(ws + 93323264);
  u16*    kvll  = (u16*)(ws + 94371840);
  u16*    ob    = (u16*)(ws + 95420416);   // ends 103,809,024
  u16*    zb    = (u16*)(ws + 92274688);   // overlays ll..ob when dead
  u16*    xm    = (u16*)(ws + 117440512);  // 50,331,648, ends 167,772,160
  const bool use_xm = (ws_size >= 167772160ull);

  const float* nof = nullptr;
  const float2* nos = nullptr;

  hipLaunchKernelGGL(transp_k, dim3(384), dim3(256), 0, stream, Wq, WqT, 768, 512);
  hipLaunchKernelGGL(transp_k, dim3(768), dim3(256), 0, stream, Wkv, WkvT, 768, 1024);
  hipLaunchKernelGGL(ln_lat2_k, dim3(512), dim3(256), 0, stream,
                     lat, llb, nl0g, nl0b, plg, plb);
  hipLaunchKernelGGL(mgemm_k<0>, dim3(16), dim3(256), 0, stream,
                     (const void*)llb, WqT, (void*)qb, 512, 512, 768,
                     nof, 0, nof, 0, 1, nos, nof, nof);
  hipLaunchKernelGGL(mgemm_k<0>, dim3(32), dim3(256), 0, stream,
                     (const void*)llb, WkvT, (void*)kvll, 512, 1024, 768,
                     nof, 0, nof, 0, 1, nos, nof, nof);
  if (use_xm){
    // LN once -> bf16 xm, then plain bf16 GEMM
    hipLaunchKernelGGL(ln_x_k, dim3(32768), dim3(256), 0, stream, vf, xm, pmg, pmb);
    hipLaunchKernelGGL(mgemm_k<0>, dim3(2048), dim3(256), 0, stream,
                       (const void*)xm, WkvT, (void*)kvx, 32768, 1024, 768,
                       nof, 0, nof, 0, 1, nos, nof, nof);
  } else {
    hipLaunchKernelGGL(stats_x_k, dim3(32768), dim3(256), 0, stream, vf, stx);
    hipLaunchKernelGGL(mgemm_k<1>, dim3(2048), dim3(256), 0, stream,
                       (const void*)vf, WkvT, (void*)kvx, 32768, 1024, 768,
                       nof, 0, nof, 0, 1, stx, pmg, pmb);
  }
  hipLaunchKernelGGL(pattn_k, dim3(1024), dim3(256), 0, stream, qb, kvx, kvll, ob);
  hipLaunchKernelGGL(transp_k, dim3(384), dim3(256), 0, stream, Wo, WoT, 512, 768);
  hipLaunchKernelGGL(transp_k, dim3(1728), dim3(256), 0, stream, Wqkv, WqkvT, 768, 2304);
  hipLaunchKernelGGL(transp_k, dim3(576), dim3(256), 0, stream, Wout, WoutT, 768, 768);
  hipLaunchKernelGGL(transp_k, dim3(2304), dim3(256), 0, stream, Wfc, WfcT, 768, 3072);
  hipLaunchKernelGGL(transp_k, dim3(2304), dim3(256), 0, stream, Wpr, WprT, 3072, 768);
  hipLaunchKernelGGL(mgemm_k<0>, dim3(384), dim3(256), 0, stream,
                     (const void*)ob, WoT, (void*)yb, 8192, 768, 512,
                     nof, 0, nof, 1, 0, nos, nof, nof);
  hipLaunchKernelGGL(ln_f32_k, dim3(8192), dim3(256), 0, stream, yb, zb, ln1g, ln1b);
  hipLaunchKernelGGL(mgemm_k<0>, dim3(1152), dim3(256), 0, stream,
                     (const void*)zb, WqkvT, (void*)qkvb, 8192, 2304, 768,
                     bqkv, 0, nof, 0, 1, nos, nof, nof);
  hipLaunchKernelGGL(sattn_k, dim3(1536), dim3(256), 0, stream, qkvb, o2b);
  hipLaunchKernelGGL(mgemm_k<0>, dim3(384), dim3(256), 0, stream,
                     (const void*)o2b, WoutT, (void*)yb, 8192, 768, 768,
                     bout, 0, yb, 0, 0, nos, nof, nof);
  hipLaunchKernelGGL(ln_f32_k, dim3(8192), dim3(256), 0, stream, yb, zb, ln2g, ln2b);
  hipLaunchKernelGGL(mgemm_k<0>, dim3(1536), dim3(256), 0, stream,
                     (const void*)zb, WfcT, (void*)hb, 8192, 3072, 768,
                     bfc, 1, nof, 0, 1, nos, nof, nof);
  hipLaunchKernelGGL(mgemm_k<0>, dim3(384), dim3(256), 0, stream,
                     (const void*)hb, WprT, d_out, 8192, 768, 3072,
                     bpr, 0, yb, 0, 0, nos, nof, nof);
}

// Round 7
// 603.733 us; speedup vs baseline: 6.7509x; 1.0364x over previous
//
#include <hip/hip_runtime.h>
#include <hip/hip_bf16.h>
#include <cstdint>
#include <cstddef>

typedef unsigned short u16;
typedef __bf16 bhalf8 __attribute__((ext_vector_type(8)));
typedef float floatx4 __attribute__((ext_vector_type(4)));
typedef unsigned short u16x8 __attribute__((ext_vector_type(8)));

__device__ __forceinline__ float b2f(u16 u){
  union { uint32_t i; float f; } x; x.i = ((uint32_t)u) << 16; return x.f;
}
__device__ __forceinline__ u16 f2b(float f){
  uint32_t i = __float_as_uint(f);
  uint32_t r = (i + 0x7FFFu + ((i >> 16) & 1u)) >> 16;   // round-nearest-even
  return (u16)r;
}

// async global->LDS DMA, 16B per lane; LDS dest = wave-uniform base + lane*16
__device__ __forceinline__ void gload16(const u16* g, u16* l){
  __builtin_amdgcn_global_load_lds(
      (const __attribute__((address_space(1))) uint32_t*)g,
      (__attribute__((address_space(3))) uint32_t*)l, 16, 0, 0);
}

// ---- block-wide sum over 256 threads (4 waves) ----
__device__ __forceinline__ float block_sum256(float v, float* sh){
  #pragma unroll
  for (int o = 32; o > 0; o >>= 1) v += __shfl_down(v, o);
  __syncthreads();
  if ((threadIdx.x & 63u) == 0) sh[threadIdx.x >> 6] = v;
  __syncthreads();
  return sh[0] + sh[1] + sh[2] + sh[3];
}

// ---- per-row LN stats of visual_feat (fp32), rearranged row order ----
__global__ __launch_bounds__(256) void stats_x_k(
    const float* __restrict__ vf, float2* __restrict__ st)
{
  __shared__ float sh[4];
  const int r  = blockIdx.x;
  const int nn = r & 255, bt = r >> 8;
  const float* in = vf + ((size_t)nn * 128 + bt) * 768;
  const int t = threadIdx.x;
  float v0 = in[t], v1 = in[t + 256], v2 = in[t + 512];
  float mean = block_sum256(v0 + v1 + v2, sh) * (1.0f / 768.0f);
  float d0 = v0 - mean, d1 = v1 - mean, d2 = v2 - mean;
  float var = block_sum256(d0*d0 + d1*d1 + d2*d2, sh) * (1.0f / 768.0f);
  if (t == 0) st[r] = make_float2(mean, rsqrtf(var + 1e-5f));
}

// ---- full LN of visual_feat -> bf16 xm, rearranged row order ----
__global__ __launch_bounds__(256) void ln_x_k(
    const float* __restrict__ vf, u16* __restrict__ xm,
    const float* __restrict__ g, const float* __restrict__ b)
{
  __shared__ float sh[4];
  const int r  = blockIdx.x;             // r = bt*256 + nn
  const int nn = r & 255, bt = r >> 8;
  const float* in = vf + ((size_t)nn * 128 + bt) * 768;
  const int t = threadIdx.x;
  float v[3];
  #pragma unroll
  for (int i = 0; i < 3; i++) v[i] = in[t + 256 * i];
  float mean = block_sum256(v[0] + v[1] + v[2], sh) * (1.0f / 768.0f);
  float d0 = v[0] - mean, d1 = v[1] - mean, d2 = v[2] - mean;
  float var = block_sum256(d0*d0 + d1*d1 + d2*d2, sh) * (1.0f / 768.0f);
  float rs = rsqrtf(var + 1e-5f);
  #pragma unroll
  for (int i = 0; i < 3; i++){
    int c = t + 256 * i;
    xm[(size_t)r * 768 + c] = f2b((v[i] - mean) * rs * g[c] + b[c]);
  }
}

// ---- double LayerNorm of latents (fp32 in) -> bf16 ----
__global__ __launch_bounds__(256) void ln_lat2_k(
    const float* __restrict__ lat, u16* __restrict__ ll,
    const float* __restrict__ g0, const float* __restrict__ b0,
    const float* __restrict__ g1, const float* __restrict__ b1)
{
  __shared__ float sh[4];
  const int r = blockIdx.x;
  const int t = threadIdx.x;
  const float* in = lat + (size_t)r * 768;
  float v[3];
  #pragma unroll
  for (int i = 0; i < 3; i++) v[i] = in[t + 256 * i];
  #pragma unroll
  for (int pass = 0; pass < 2; ++pass){
    float mean = block_sum256(v[0] + v[1] + v[2], sh) * (1.0f / 768.0f);
    float d0 = v[0] - mean, d1 = v[1] - mean, d2 = v[2] - mean;
    float var = block_sum256(d0*d0 + d1*d1 + d2*d2, sh) * (1.0f / 768.0f);
    float rs = rsqrtf(var + 1e-5f);
    const float* g = pass ? g1 : g0;
    const float* b = pass ? b1 : b0;
    #pragma unroll
    for (int i = 0; i < 3; i++){
      int c = t + 256 * i;
      v[i] = (v[i] - mean) * rs * g[c] + b[c];
    }
  }
  #pragma unroll
  for (int i = 0; i < 3; i++) ll[(size_t)r * 768 + t + 256 * i] = f2b(v[i]);
}

// ---- LN of fp32 ws rows -> bf16 ----
__global__ __launch_bounds__(256) void ln_f32_k(
    const float* __restrict__ y, u16* __restrict__ z,
    const float* __restrict__ g, const float* __restrict__ b)
{
  __shared__ float sh[4];
  const int r = blockIdx.x;
  const float* in = y + (size_t)r * 768;
  const int t = threadIdx.x;
  float v[3];
  #pragma unroll
  for (int i = 0; i < 3; i++) v[i] = in[t + 256 * i];
  float mean = block_sum256(v[0] + v[1] + v[2], sh) * (1.0f / 768.0f);
  float d0 = v[0] - mean, d1 = v[1] - mean, d2 = v[2] - mean;
  float var = block_sum256(d0*d0 + d1*d1 + d2*d2, sh) * (1.0f / 768.0f);
  float rs = rsqrtf(var + 1e-5f);
  #pragma unroll
  for (int i = 0; i < 3; i++){
    int c = t + 256 * i;
    z[(size_t)r * 768 + c] = f2b((v[i] - mean) * rs * g[c] + b[c]);
  }
}

// ---- weight transpose + bf16 convert: src (K,N) f32 -> dst (N,K) bf16 ----
__global__ __launch_bounds__(256) void transp_k(
    const float* __restrict__ src, u16* __restrict__ dst, int K, int N)
{
  __shared__ u16 sh[32][33];
  const int nb = N >> 5;
  const int bx = blockIdx.x % nb, byy = blockIdx.x / nb;
  const int tx = threadIdx.x & 31, ty = threadIdx.x >> 5;
  #pragma unroll
  for (int i = 0; i < 4; i++){
    int k = byy * 32 + ty + i * 8, n = bx * 32 + tx;
    sh[tx][ty + i * 8] = f2b(src[(size_t)k * N + n]);
  }
  __syncthreads();
  #pragma unroll
  for (int i = 0; i < 4; i++){
    int n = bx * 32 + ty + i * 8, k = byy * 32 + tx;
    dst[(size_t)n * K + k] = sh[ty + i * 8][tx];
  }
}

// ---- MFMA GEMM: C[M,N] = act(A@B + bias) + addsrc ----
// XCD-grouping swizzle: grid divisible by 8. AMODE 0: A bf16 (M,K), staged via
// global_load_lds (DMA). AMODE 1: A fp32 vf + fused LN + row remap (reg-staged).
// LDS linear [128][32] — ds_read_b128 frag pattern is conflict-minimal (8 lanes
// per bank-quad = b128 floor), so no pad/swizzle needed.
template<int AMODE>
__global__ __launch_bounds__(256) void mgemm_k(
    const void* __restrict__ A, const u16* __restrict__ BT, void* __restrict__ C,
    int M, int N, int K,
    const float* __restrict__ bias, int act,
    const float* addsrc, int rowperm, int outbf16,
    const float2* __restrict__ stx, const float* __restrict__ gam,
    const float* __restrict__ bet)
{
  __shared__ __align__(16) u16 As[128][32];
  __shared__ __align__(16) u16 Bs[128][32];
  const int nb = N >> 7;
  const int swz = ((blockIdx.x & 7) * (gridDim.x >> 3)) + (blockIdx.x >> 3);
  const int bx = swz % nb, by = swz / nb;
  const int tid  = threadIdx.x;
  const int wave = tid >> 6, lane = tid & 63;
  const int wr = (wave >> 1) * 64, wc = (wave & 1) * 64;
  const int l15 = lane & 15, l4 = lane >> 4;
  const int srow = lane >> 2, sseg = lane & 3;   // DMA staging decomposition
  const int sr = tid >> 2, sq = (tid & 3) * 8;   // reg staging (AMODE 1)

  const u16*   Abf = (const u16*)A;
  const float* Af  = (const float*)A;

  int   asrc[2]; float mn[2], rs[2];
  if (AMODE == 1){
    #pragma unroll
    for (int p = 0; p < 2; p++){
      int gm = by * 128 + sr + p * 64;
      asrc[p] = (gm & 255) * 128 + (gm >> 8);
      float2 s = stx[gm]; mn[p] = s.x; rs[p] = s.y;
    }
  }

  floatx4 acc[4][4];
  #pragma unroll
  for (int i = 0; i < 4; i++)
    #pragma unroll
    for (int j = 0; j < 4; j++) acc[i][j] = (floatx4){0.f, 0.f, 0.f, 0.f};

  for (int k0 = 0; k0 < K; k0 += 32){
    if (AMODE == 0){
      #pragma unroll
      for (int c = 0; c < 2; c++){
        const int ch = wave * 2 + c;            // chunk 0..7: rows [ch*16, +16)
        const int ga = by * 128 + ch * 16 + srow;
        gload16(Abf + (size_t)ga * K + k0 + sseg * 8, &As[ch * 16][0]);
        const int gb = bx * 128 + ch * 16 + srow;
        gload16(BT  + (size_t)gb * K + k0 + sseg * 8, &Bs[ch * 16][0]);
      }
    } else {
      #pragma unroll
      for (int p = 0; p < 2; p++){
        const int r = sr + p * 64;
        const float* ap = Af + (size_t)asrc[p] * K + k0 + sq;
        float4 f0 = *(const float4*)ap, f1 = *(const float4*)(ap + 4);
        float4 g0 = *(const float4*)(gam + k0 + sq), g1 = *(const float4*)(gam + k0 + sq + 4);
        float4 e0 = *(const float4*)(bet + k0 + sq), e1 = *(const float4*)(bet + k0 + sq + 4);
        u16x8 v;
        v[0] = f2b((f0.x - mn[p]) * rs[p] * g0.x + e0.x);
        v[1] = f2b((f0.y - mn[p]) * rs[p] * g0.y + e0.y);
        v[2] = f2b((f0.z - mn[p]) * rs[p] * g0.z + e0.z);
        v[3] = f2b((f0.w - mn[p]) * rs[p] * g0.w + e0.w);
        v[4] = f2b((f1.x - mn[p]) * rs[p] * g1.x + e1.x);
        v[5] = f2b((f1.y - mn[p]) * rs[p] * g1.y + e1.y);
        v[6] = f2b((f1.z - mn[p]) * rs[p] * g1.z + e1.z);
        v[7] = f2b((f1.w - mn[p]) * rs[p] * g1.w + e1.w);
        *(u16x8*)(&As[r][sq]) = v;
      }
      #pragma unroll
      for (int c = 0; c < 2; c++){
        const int ch = wave * 2 + c;
        const int gb = bx * 128 + ch * 16 + srow;
        gload16(BT + (size_t)gb * K + k0 + sseg * 8, &Bs[ch * 16][0]);
      }
    }
    __syncthreads();                   // compiler drains vmcnt/lgkmcnt here
    bhalf8 af[4], bfv[4];
    #pragma unroll
    for (int i = 0; i < 4; i++){
      af[i]  = *(const bhalf8*)(&As[wr + i * 16 + l15][l4 * 8]);
      bfv[i] = *(const bhalf8*)(&Bs[wc + i * 16 + l15][l4 * 8]);
    }
    #pragma unroll
    for (int i = 0; i < 4; i++)
      #pragma unroll
      for (int j = 0; j < 4; j++)
        acc[i][j] = __builtin_amdgcn_mfma_f32_16x16x32_bf16(af[i], bfv[j], acc[i][j], 0, 0, 0);
    __syncthreads();                   // frag reads done before next DMA
  }

  const int gm0 = by * 128 + wr, gn0 = bx * 128 + wc;
  #pragma unroll
  for (int i = 0; i < 4; i++){
    #pragma unroll
    for (int r = 0; r < 4; r++){
      int gm = gm0 + i * 16 + l4 * 4 + r;
      int orow = rowperm ? ((gm & 63) * 128 + (gm >> 6)) : gm;
      #pragma unroll
      for (int j = 0; j < 4; j++){
        int gn = gn0 + j * 16 + l15;
        float v = acc[i][j][r];
        if (bias) v += bias[gn];
        if (act)  v = v * (1.0f / (1.0f + expf(-1.702f * v)));  // QuickGELU
        if (addsrc) v += addsrc[(size_t)orow * N + gn];
        if (outbf16) ((u16*)C)[(size_t)orow * N + gn] = f2b(v);
        else         ((float*)C)[(size_t)orow * N + gn] = v;
      }
    }
  }
}

// ---- MFMA Perceiver attention: block=(bt,head), 4 waves x 16 q-rows ----
__global__ __launch_bounds__(256) void pattn_k(
    const u16* __restrict__ q, const u16* __restrict__ kvx,
    const u16* __restrict__ kvll, u16* __restrict__ o)
{
  __shared__ __align__(16) u16 Ks[64][72];
  __shared__ __align__(16) u16 Vs[64][72];
  __shared__ __align__(16) u16 Ps[64][72];
  const int blk = blockIdx.x;            // bt*8 + h
  const int hh = blk & 7, bt = blk >> 3;
  const int tt = bt & 7;
  const int tid = threadIdx.x;
  const int wv = tid >> 6, ln = tid & 63;
  const int l15 = ln & 15, lg = ln >> 4;
  const int i0 = wv * 16;
  const int sj = tid >> 2, sc = (tid & 3) * 16;

  bhalf8 qf[2];
  {
    const u16* qp = q + ((size_t)(tt * 64 + i0 + l15)) * 512 + hh * 64 + lg * 8;
    qf[0] = *(const bhalf8*)(qp);
    qf[1] = *(const bhalf8*)(qp + 32);
  }

  floatx4 sacc[20];
  #pragma unroll
  for (int t = 0; t < 20; t++) sacc[t] = (floatx4){0.f,0.f,0.f,0.f};

  for (int ch = 0; ch < 5; ++ch){
    const u16* src = (ch < 4)
        ? (kvx  + ((size_t)(bt * 256 + ch * 64 + sj)) * 1024 + hh * 64 + sc)
        : (kvll + ((size_t)(tt * 64 + sj)) * 1024 + hh * 64 + sc);
    u16x8 k0 = *(const u16x8*)(src);
    u16x8 k1 = *(const u16x8*)(src + 8);
    __syncthreads();
    *(u16x8*)(&Ks[sj][sc])     = k0;
    *(u16x8*)(&Ks[sj][sc + 8]) = k1;
    __syncthreads();
    #pragma unroll
    for (int jt = 0; jt < 4; jt++){
      bhalf8 kf0 = *(const bhalf8*)(&Ks[jt*16 + l15][lg*8]);
      bhalf8 kf1 = *(const bhalf8*)(&Ks[jt*16 + l15][32 + lg*8]);
      sacc[ch*4+jt] = __builtin_amdgcn_mfma_f32_16x16x32_bf16(qf[0], kf0, sacc[ch*4+jt], 0,0,0);
      sacc[ch*4+jt] = __builtin_amdgcn_mfma_f32_16x16x32_bf16(qf[1], kf1, sacc[ch*4+jt], 0,0,0);
    }
  }

  float inv_l[4];
  float mx[4];
  #pragma unroll
  for (int r = 0; r < 4; r++){
    float m = -1e30f;
    #pragma unroll
    for (int t = 0; t < 20; t++) m = fmaxf(m, sacc[t][r]);
    m = fmaxf(m, __shfl_xor(m, 1));
    m = fmaxf(m, __shfl_xor(m, 2));
    m = fmaxf(m, __shfl_xor(m, 4));
    m = fmaxf(m, __shfl_xor(m, 8));
    mx[r] = m;
  }
  #pragma unroll
  for (int r = 0; r < 4; r++){
    float s = 0.f;
    #pragma unroll
    for (int t = 0; t < 20; t++){
      float p = expf(0.125f * (sacc[t][r] - mx[r]));
      sacc[t][r] = p;
      s += p;
    }
    s += __shfl_xor(s, 1); s += __shfl_xor(s, 2);
    s += __shfl_xor(s, 4); s += __shfl_xor(s, 8);
    inv_l[r] = 1.0f / s;
  }

  floatx4 oacc[4];
  #pragma unroll
  for (int dt = 0; dt < 4; dt++) oacc[dt] = (floatx4){0.f,0.f,0.f,0.f};
  for (int ch = 0; ch < 5; ++ch){
    const u16* src = (ch < 4)
        ? (kvx  + ((size_t)(bt * 256 + ch * 64 + sj)) * 1024 + 512 + hh * 64 + sc)
        : (kvll + ((size_t)(tt * 64 + sj)) * 1024 + 512 + hh * 64 + sc);
    u16x8 v0 = *(const u16x8*)(src);
    u16x8 v1 = *(const u16x8*)(src + 8);
    __syncthreads();
    #pragma unroll
    for (int e = 0; e < 8; e++) Vs[sc + e][sj]     = v0[e];
    #pragma unroll
    for (int e = 0; e < 8; e++) Vs[sc + 8 + e][sj] = v1[e];
    #pragma unroll
    for (int jt = 0; jt < 4; jt++){
      #pragma unroll
      for (int r = 0; r < 4; r++)
        Ps[i0 + 4*lg + r][jt*16 + l15] = f2b(sacc[ch*4+jt][r]);
    }
    __syncthreads();
    #pragma unroll
    for (int kk = 0; kk < 2; kk++){
      bhalf8 pf = *(const bhalf8*)(&Ps[i0 + l15][kk*32 + lg*8]);
      #pragma unroll
      for (int dt = 0; dt < 4; dt++){
        bhalf8 vfr = *(const bhalf8*)(&Vs[dt*16 + l15][kk*32 + lg*8]);
        oacc[dt] = __builtin_amdgcn_mfma_f32_16x16x32_bf16(pf, vfr, oacc[dt], 0,0,0);
      }
    }
  }

  u16* op = o + ((size_t)(bt*64 + i0 + 4*lg)) * 512 + hh*64 + l15;
  #pragma unroll
  for (int dt = 0; dt < 4; dt++)
    #pragma unroll
    for (int r = 0; r < 4; r++)
      op[(size_t)r * 512 + dt*16] = f2b(oacc[dt][r] * inv_l[r]);
}

// ---- MFMA self-attention: block=(bt,head), 4 waves x 16 q-rows, 64 keys ----
__global__ __launch_bounds__(256) void sattn_k(
    const u16* __restrict__ qkv, u16* __restrict__ o2)
{
  __shared__ __align__(16) u16 Ks[64][72];
  __shared__ __align__(16) u16 Vs[64][72];
  __shared__ __align__(16) u16 Ps[64][72];
  const int blk = blockIdx.x;
  const int hh = blk % 12, bt = blk / 12;
  const int tid = threadIdx.x;
  const int wv = tid >> 6, ln = tid & 63;
  const int l15 = ln & 15, lg = ln >> 4;
  const int i0 = wv * 16;
  const int sj = tid >> 2, sc = (tid & 3) * 16;

  const u16* kp = qkv + ((size_t)sj * 128 + bt) * 2304 + 768 + hh * 64 + sc;
  u16x8 k0 = *(const u16x8*)(kp);
  u16x8 k1 = *(const u16x8*)(kp + 8);
  u16x8 v0 = *(const u16x8*)(kp + 768);
  u16x8 v1 = *(const u16x8*)(kp + 776);
  *(u16x8*)(&Ks[sj][sc])     = k0;
  *(u16x8*)(&Ks[sj][sc + 8]) = k1;
  #pragma unroll
  for (int e = 0; e < 8; e++) Vs[sc + e][sj]     = v0[e];
  #pragma unroll
  for (int e = 0; e < 8; e++) Vs[sc + 8 + e][sj] = v1[e];

  bhalf8 qf[2];
  {
    const u16* qp = qkv + ((size_t)(i0 + l15) * 128 + bt) * 2304 + hh * 64 + lg * 8;
    qf[0] = *(const bhalf8*)(qp);
    qf[1] = *(const bhalf8*)(qp + 32);
  }
  __syncthreads();

  floatx4 sacc[4];
  #pragma unroll
  for (int t = 0; t < 4; t++) sacc[t] = (floatx4){0.f,0.f,0.f,0.f};
  #pragma unroll
  for (int jt = 0; jt < 4; jt++){
    bhalf8 kf0 = *(const bhalf8*)(&Ks[jt*16 + l15][lg*8]);
    bhalf8 kf1 = *(const bhalf8*)(&Ks[jt*16 + l15][32 + lg*8]);
    sacc[jt] = __builtin_amdgcn_mfma_f32_16x16x32_bf16(qf[0], kf0, sacc[jt], 0,0,0);
    sacc[jt] = __builtin_amdgcn_mfma_f32_16x16x32_bf16(qf[1], kf1, sacc[jt], 0,0,0);
  }

  float inv_l[4];
  #pragma unroll
  for (int r = 0; r < 4; r++){
    float m = -1e30f;
    #pragma unroll
    for (int t = 0; t < 4; t++) m = fmaxf(m, sacc[t][r]);
    m = fmaxf(m, __shfl_xor(m, 1));
    m = fmaxf(m, __shfl_xor(m, 2));
    m = fmaxf(m, __shfl_xor(m, 4));
    m = fmaxf(m, __shfl_xor(m, 8));
    float s = 0.f;
    #pragma unroll
    for (int t = 0; t < 4; t++){
      float p = expf(0.125f * (sacc[t][r] - m));
      sacc[t][r] = p;
      s += p;
    }
    s += __shfl_xor(s, 1); s += __shfl_xor(s, 2);
    s += __shfl_xor(s, 4); s += __shfl_xor(s, 8);
    inv_l[r] = 1.0f / s;
  }

  #pragma unroll
  for (int jt = 0; jt < 4; jt++){
    #pragma unroll
    for (int r = 0; r < 4; r++)
      Ps[i0 + 4*lg + r][jt*16 + l15] = f2b(sacc[jt][r]);
  }
  __syncthreads();

  floatx4 oacc[4];
  #pragma unroll
  for (int dt = 0; dt < 4; dt++) oacc[dt] = (floatx4){0.f,0.f,0.f,0.f};
  #pragma unroll
  for (int kk = 0; kk < 2; kk++){
    bhalf8 pf = *(const bhalf8*)(&Ps[i0 + l15][kk*32 + lg*8]);
    #pragma unroll
    for (int dt = 0; dt < 4; dt++){
      bhalf8 vfr = *(const bhalf8*)(&Vs[dt*16 + l15][kk*32 + lg*8]);
      oacc[dt] = __builtin_amdgcn_mfma_f32_16x16x32_bf16(pf, vfr, oacc[dt], 0,0,0);
    }
  }

  u16* op = o2 + ((size_t)((i0 + 4*lg) * 128 + bt)) * 768 + hh*64 + l15;
  #pragma unroll
  for (int dt = 0; dt < 4; dt++)
    #pragma unroll
    for (int r = 0; r < 4; r++)
      op[(size_t)r * 128 * 768 + dt*16] = f2b(oacc[dt][r] * inv_l[r]);
}

extern "C" void kernel_launch(void* const* d_in, const int* in_sizes, int n_in,
                              void* d_out, int out_size, void* d_ws, size_t ws_size,
                              hipStream_t stream)
{
  const float* vf   = (const float*)d_in[0];
  const float* lat  = (const float*)d_in[1];
  const float* nl0g = (const float*)d_in[2];
  const float* nl0b = (const float*)d_in[3];
  const float* pmg  = (const float*)d_in[4];
  const float* pmb  = (const float*)d_in[5];
  const float* plg  = (const float*)d_in[6];
  const float* plb  = (const float*)d_in[7];
  const float* Wq   = (const float*)d_in[8];
  const float* Wkv  = (const float*)d_in[9];
  const float* Wo   = (const float*)d_in[10];
  const float* ln1g = (const float*)d_in[11];
  const float* ln1b = (const float*)d_in[12];
  const float* Wqkv = (const float*)d_in[13];
  const float* bqkv = (const float*)d_in[14];
  const float* Wout = (const float*)d_in[15];
  const float* bout = (const float*)d_in[16];
  const float* ln2g = (const float*)d_in[17];
  const float* ln2b = (const float*)d_in[18];
  const float* Wfc  = (const float*)d_in[19];
  const float* bfc  = (const float*)d_in[20];
  const float* Wpr  = (const float*)d_in[21];
  const float* bpr  = (const float*)d_in[22];

  // ---- ws layout: base high-water 104,857,600 B; optional xm at 117.4M ----
  char* ws = (char*)d_ws;
  u16*    kvx   = (u16*)(ws + 0);          // 67,108,864 (dead after pattn)
  u16*    qkvb  = (u16*)(ws + 0);          // 37,748,736 (dead after sattn)
  u16*    o2b   = (u16*)(ws + 37748736);   // 12,582,912 (dead after Wout gemm)
  u16*    hb    = (u16*)(ws + 0);          // 50,331,648
  u16*    WoT   = (u16*)(ws + 50331648);
  u16*    WqkvT = (u16*)(ws + 51118080);
  u16*    WoutT = (u16*)(ws + 54657024);
  u16*    WfcT  = (u16*)(ws + 55836672);
  u16*    WprT  = (u16*)(ws + 60555264);   // ends 65,273,856
  u16*    WqT   = (u16*)(ws + 67108864);
  u16*    WkvT  = (u16*)(ws + 67895296);   // ends 69,468,160
  float*  yb    = (float*)(ws + 67108864); // written after WqT/WkvT dead
  u16*    llb   = (u16*)(ws + 92274688);
  float2* stx   = (float2*)(ws + 93061120);
  u16*    qb    = (u16*)(ws + 93323264);
  u16*    kvll  = (u16*)(ws + 94371840);
  u16*    ob    = (u16*)(ws + 95420416);   // ends 103,809,024
  u16*    zb    = (u16*)(ws + 92274688);   // overlays ll..ob when dead
  u16*    xm    = (u16*)(ws + 117440512);  // 50,331,648, ends 167,772,160
  const bool use_xm = (ws_size >= 167772160ull);

  const float* nof = nullptr;
  const float2* nos = nullptr;

  hipLaunchKernelGGL(transp_k, dim3(384), dim3(256), 0, stream, Wq, WqT, 768, 512);
  hipLaunchKernelGGL(transp_k, dim3(768), dim3(256), 0, stream, Wkv, WkvT, 768, 1024);
  hipLaunchKernelGGL(ln_lat2_k, dim3(512), dim3(256), 0, stream,
                     lat, llb, nl0g, nl0b, plg, plb);
  hipLaunchKernelGGL(mgemm_k<0>, dim3(16), dim3(256), 0, stream,
                     (const void*)llb, WqT, (void*)qb, 512, 512, 768,
                     nof, 0, nof, 0, 1, nos, nof, nof);
  hipLaunchKernelGGL(mgemm_k<0>, dim3(32), dim3(256), 0, stream,
                     (const void*)llb, WkvT, (void*)kvll, 512, 1024, 768,
                     nof, 0, nof, 0, 1, nos, nof, nof);
  if (use_xm){
    hipLaunchKernelGGL(ln_x_k, dim3(32768), dim3(256), 0, stream, vf, xm, pmg, pmb);
    hipLaunchKernelGGL(mgemm_k<0>, dim3(2048), dim3(256), 0, stream,
                       (const void*)xm, WkvT, (void*)kvx, 32768, 1024, 768,
                       nof, 0, nof, 0, 1, nos, nof, nof);
  } else {
    hipLaunchKernelGGL(stats_x_k, dim3(32768), dim3(256), 0, stream, vf, stx);
    hipLaunchKernelGGL(mgemm_k<1>, dim3(2048), dim3(256), 0, stream,
                       (const void*)vf, WkvT, (void*)kvx, 32768, 1024, 768,
                       nof, 0, nof, 0, 1, stx, pmg, pmb);
  }
  hipLaunchKernelGGL(pattn_k, dim3(1024), dim3(256), 0, stream, qb, kvx, kvll, ob);
  hipLaunchKernelGGL(transp_k, dim3(384), dim3(256), 0, stream, Wo, WoT, 512, 768);
  hipLaunchKernelGGL(transp_k, dim3(1728), dim3(256), 0, stream, Wqkv, WqkvT, 768, 2304);
  hipLaunchKernelGGL(transp_k, dim3(576), dim3(256), 0, stream, Wout, WoutT, 768, 768);
  hipLaunchKernelGGL(transp_k, dim3(2304), dim3(256), 0, stream, Wfc, WfcT, 768, 3072);
  hipLaunchKernelGGL(transp_k, dim3(2304), dim3(256), 0, stream, Wpr, WprT, 3072, 768);
  hipLaunchKernelGGL(mgemm_k<0>, dim3(384), dim3(256), 0, stream,
                     (const void*)ob, WoT, (void*)yb, 8192, 768, 512,
                     nof, 0, nof, 1, 0, nos, nof, nof);
  hipLaunchKernelGGL(ln_f32_k, dim3(8192), dim3(256), 0, stream, yb, zb, ln1g, ln1b);
  hipLaunchKernelGGL(mgemm_k<0>, dim3(1152), dim3(256), 0, stream,
                     (const void*)zb, WqkvT, (void*)qkvb, 8192, 2304, 768,
                     bqkv, 0, nof, 0, 1, nos, nof, nof);
  hipLaunchKernelGGL(sattn_k, dim3(1536), dim3(256), 0, stream, qkvb, o2b);
  hipLaunchKernelGGL(mgemm_k<0>, dim3(384), dim3(256), 0, stream,
                     (const void*)o2b, WoutT, (void*)yb, 8192, 768, 768,
                     bout, 0, yb, 0, 0, nos, nof, nof);
  hipLaunchKernelGGL(ln_f32_k, dim3(8192), dim3(256), 0, stream, yb, zb, ln2g, ln2b);
  hipLaunchKernelGGL(mgemm_k<0>, dim3(1536), dim3(256), 0, stream,
                     (const void*)zb, WfcT, (void*)hb, 8192, 3072, 768,
                     bfc, 1, nof, 0, 1, nos, nof, nof);
  hipLaunchKernelGGL(mgemm_k<0>, dim3(384), dim3(256), 0, stream,
                     (const void*)hb, WprT, d_out, 8192, 768, 3072,
                     bpr, 0, yb, 0, 0, nos, nof, nof);
}

// Round 8
// 561.556 us; speedup vs baseline: 7.2579x; 1.0751x over previous
//
#include <hip/hip_runtime.h>
#include <hip/hip_bf16.h>
#include <cstdint>
#include <cstddef>

typedef unsigned short u16;
typedef __bf16 bhalf8 __attribute__((ext_vector_type(8)));
typedef float floatx4 __attribute__((ext_vector_type(4)));
typedef unsigned short u16x8 __attribute__((ext_vector_type(8)));

__device__ __forceinline__ float b2f(u16 u){
  union { uint32_t i; float f; } x; x.i = ((uint32_t)u) << 16; return x.f;
}
__device__ __forceinline__ u16 f2b(float f){
  uint32_t i = __float_as_uint(f);
  uint32_t r = (i + 0x7FFFu + ((i >> 16) & 1u)) >> 16;   // round-nearest-even
  return (u16)r;
}

// async global->LDS DMA, 16B per lane; LDS dest = wave-uniform base + lane*16
__device__ __forceinline__ void gload16(const u16* g, u16* l){
  __builtin_amdgcn_global_load_lds(
      (const __attribute__((address_space(1))) uint32_t*)g,
      (__attribute__((address_space(3))) uint32_t*)l, 16, 0, 0);
}

// ---- block-wide sum over 256 threads (4 waves) ----
__device__ __forceinline__ float block_sum256(float v, float* sh){
  #pragma unroll
  for (int o = 32; o > 0; o >>= 1) v += __shfl_down(v, o);
  __syncthreads();
  if ((threadIdx.x & 63u) == 0) sh[threadIdx.x >> 6] = v;
  __syncthreads();
  return sh[0] + sh[1] + sh[2] + sh[3];
}

// ---- per-row LN stats of visual_feat (fp32), rearranged row order ----
__global__ __launch_bounds__(256) void stats_x_k(
    const float* __restrict__ vf, float2* __restrict__ st)
{
  __shared__ float sh[4];
  const int r  = blockIdx.x;
  const int nn = r & 255, bt = r >> 8;
  const float* in = vf + ((size_t)nn * 128 + bt) * 768;
  const int t = threadIdx.x;
  float v0 = in[t], v1 = in[t + 256], v2 = in[t + 512];
  float mean = block_sum256(v0 + v1 + v2, sh) * (1.0f / 768.0f);
  float d0 = v0 - mean, d1 = v1 - mean, d2 = v2 - mean;
  float var = block_sum256(d0*d0 + d1*d1 + d2*d2, sh) * (1.0f / 768.0f);
  if (t == 0) st[r] = make_float2(mean, rsqrtf(var + 1e-5f));
}

// ---- full LN of visual_feat -> bf16 xm, rearranged row order ----
__global__ __launch_bounds__(256) void ln_x_k(
    const float* __restrict__ vf, u16* __restrict__ xm,
    const float* __restrict__ g, const float* __restrict__ b)
{
  __shared__ float sh[4];
  const int r  = blockIdx.x;             // r = bt*256 + nn
  const int nn = r & 255, bt = r >> 8;
  const float* in = vf + ((size_t)nn * 128 + bt) * 768;
  const int t = threadIdx.x;
  float v[3];
  #pragma unroll
  for (int i = 0; i < 3; i++) v[i] = in[t + 256 * i];
  float mean = block_sum256(v[0] + v[1] + v[2], sh) * (1.0f / 768.0f);
  float d0 = v[0] - mean, d1 = v[1] - mean, d2 = v[2] - mean;
  float var = block_sum256(d0*d0 + d1*d1 + d2*d2, sh) * (1.0f / 768.0f);
  float rs = rsqrtf(var + 1e-5f);
  #pragma unroll
  for (int i = 0; i < 3; i++){
    int c = t + 256 * i;
    xm[(size_t)r * 768 + c] = f2b((v[i] - mean) * rs * g[c] + b[c]);
  }
}

// ---- double LayerNorm of latents (fp32 in) -> bf16 ----
__global__ __launch_bounds__(256) void ln_lat2_k(
    const float* __restrict__ lat, u16* __restrict__ ll,
    const float* __restrict__ g0, const float* __restrict__ b0,
    const float* __restrict__ g1, const float* __restrict__ b1)
{
  __shared__ float sh[4];
  const int r = blockIdx.x;
  const int t = threadIdx.x;
  const float* in = lat + (size_t)r * 768;
  float v[3];
  #pragma unroll
  for (int i = 0; i < 3; i++) v[i] = in[t + 256 * i];
  #pragma unroll
  for (int pass = 0; pass < 2; ++pass){
    float mean = block_sum256(v[0] + v[1] + v[2], sh) * (1.0f / 768.0f);
    float d0 = v[0] - mean, d1 = v[1] - mean, d2 = v[2] - mean;
    float var = block_sum256(d0*d0 + d1*d1 + d2*d2, sh) * (1.0f / 768.0f);
    float rs = rsqrtf(var + 1e-5f);
    const float* g = pass ? g1 : g0;
    const float* b = pass ? b1 : b0;
    #pragma unroll
    for (int i = 0; i < 3; i++){
      int c = t + 256 * i;
      v[i] = (v[i] - mean) * rs * g[c] + b[c];
    }
  }
  #pragma unroll
  for (int i = 0; i < 3; i++) ll[(size_t)r * 768 + t + 256 * i] = f2b(v[i]);
}

// ---- LN of fp32 ws rows -> bf16 ----
__global__ __launch_bounds__(256) void ln_f32_k(
    const float* __restrict__ y, u16* __restrict__ z,
    const float* __restrict__ g, const float* __restrict__ b)
{
  __shared__ float sh[4];
  const int r = blockIdx.x;
  const float* in = y + (size_t)r * 768;
  const int t = threadIdx.x;
  float v[3];
  #pragma unroll
  for (int i = 0; i < 3; i++) v[i] = in[t + 256 * i];
  float mean = block_sum256(v[0] + v[1] + v[2], sh) * (1.0f / 768.0f);
  float d0 = v[0] - mean, d1 = v[1] - mean, d2 = v[2] - mean;
  float var = block_sum256(d0*d0 + d1*d1 + d2*d2, sh) * (1.0f / 768.0f);
  float rs = rsqrtf(var + 1e-5f);
  #pragma unroll
  for (int i = 0; i < 3; i++){
    int c = t + 256 * i;
    z[(size_t)r * 768 + c] = f2b((v[i] - mean) * rs * g[c] + b[c]);
  }
}

// ---- weight transpose + bf16 convert: src (K,N) f32 -> dst (N,K) bf16 ----
__global__ __launch_bounds__(256) void transp_k(
    const float* __restrict__ src, u16* __restrict__ dst, int K, int N)
{
  __shared__ u16 sh[32][33];
  const int nb = N >> 5;
  const int bx = blockIdx.x % nb, byy = blockIdx.x / nb;
  const int tx = threadIdx.x & 31, ty = threadIdx.x >> 5;
  #pragma unroll
  for (int i = 0; i < 4; i++){
    int k = byy * 32 + ty + i * 8, n = bx * 32 + tx;
    sh[tx][ty + i * 8] = f2b(src[(size_t)k * N + n]);
  }
  __syncthreads();
  #pragma unroll
  for (int i = 0; i < 4; i++){
    int n = bx * 32 + ty + i * 8, k = byy * 32 + tx;
    dst[(size_t)n * K + k] = sh[ty + i * 8][tx];
  }
}

// ---- MFMA GEMM, 2-phase pipelined (T3/T4 minimum recipe) ----
// AMODE 0: A bf16, DMA-staged, double-buffered LDS, counted vmcnt(4) — the
// prefetch's 4 DMAs stay in flight across both barriers (never drain to 0).
// AMODE 1 (fallback): fp32 vf + fused LN, full-drain structure (proven R5).
template<int AMODE>
__global__ __launch_bounds__(256) void mgemm_k(
    const void* __restrict__ A, const u16* __restrict__ BT, void* __restrict__ C,
    int M, int N, int K,
    const float* __restrict__ bias, int act,
    const float* addsrc, int rowperm, int outbf16,
    const float2* __restrict__ stx, const float* __restrict__ gam,
    const float* __restrict__ bet)
{
  __shared__ __align__(16) u16 As[2][128][32];
  __shared__ __align__(16) u16 Bs[2][128][32];
  const int nb = N >> 7;
  const int swz = ((blockIdx.x & 7) * (gridDim.x >> 3)) + (blockIdx.x >> 3);
  const int bx = swz % nb, by = swz / nb;
  const int tid  = threadIdx.x;
  const int wave = tid >> 6, lane = tid & 63;
  const int wr = (wave >> 1) * 64, wc = (wave & 1) * 64;
  const int l15 = lane & 15, l4 = lane >> 4;
  const int srow = lane >> 2, sseg = lane & 3;   // DMA staging decomposition
  const int sr = tid >> 2, sq = (tid & 3) * 8;   // reg staging (AMODE 1)

  const u16*   Abf = (const u16*)A;
  const float* Af  = (const float*)A;

  floatx4 acc[4][4];
  #pragma unroll
  for (int i = 0; i < 4; i++)
    #pragma unroll
    for (int j = 0; j < 4; j++) acc[i][j] = (floatx4){0.f, 0.f, 0.f, 0.f};

  auto stage = [&](int buf, int k0){
    #pragma unroll
    for (int c = 0; c < 2; c++){
      const int ch = wave * 2 + c;              // chunk: rows [ch*16, +16)
      gload16(Abf + (size_t)(by * 128 + ch * 16 + srow) * K + k0 + sseg * 8,
              &As[buf][ch * 16][0]);
      gload16(BT  + (size_t)(bx * 128 + ch * 16 + srow) * K + k0 + sseg * 8,
              &Bs[buf][ch * 16][0]);
    }
  };
  auto domfma = [&](int buf){
    bhalf8 af[4], bfv[4];
    #pragma unroll
    for (int i = 0; i < 4; i++){
      af[i]  = *(const bhalf8*)(&As[buf][wr + i * 16 + l15][l4 * 8]);
      bfv[i] = *(const bhalf8*)(&Bs[buf][wc + i * 16 + l15][l4 * 8]);
    }
    #pragma unroll
    for (int i = 0; i < 4; i++)
      #pragma unroll
      for (int j = 0; j < 4; j++)
        acc[i][j] = __builtin_amdgcn_mfma_f32_16x16x32_bf16(af[i], bfv[j], acc[i][j], 0, 0, 0);
  };

  if (AMODE == 0){
    stage(0, 0);
    const int nk = K >> 5;
    for (int kt = 0; kt < nk; ++kt){
      const int cur = kt & 1;
      if (kt + 1 < nk){
        stage(cur ^ 1, (kt + 1) << 5);          // prefetch next K-tile
        asm volatile("s_waitcnt vmcnt(4)" ::: "memory");  // wait cur only
      } else {
        asm volatile("s_waitcnt vmcnt(0)" ::: "memory");  // tail: drain
      }
      __builtin_amdgcn_s_barrier();             // cur tile visible to all
      domfma(cur);
      __builtin_amdgcn_s_barrier();             // reads done before overwrite
    }
  } else {
    int   asrc[2]; float mn[2], rs[2];
    #pragma unroll
    for (int p = 0; p < 2; p++){
      int gm = by * 128 + sr + p * 64;
      asrc[p] = (gm & 255) * 128 + (gm >> 8);
      float2 s = stx[gm]; mn[p] = s.x; rs[p] = s.y;
    }
    for (int k0 = 0; k0 < K; k0 += 32){
      #pragma unroll
      for (int p = 0; p < 2; p++){
        const int r = sr + p * 64;
        const float* ap = Af + (size_t)asrc[p] * K + k0 + sq;
        float4 f0 = *(const float4*)ap, f1 = *(const float4*)(ap + 4);
        float4 g0 = *(const float4*)(gam + k0 + sq), g1 = *(const float4*)(gam + k0 + sq + 4);
        float4 e0 = *(const float4*)(bet + k0 + sq), e1 = *(const float4*)(bet + k0 + sq + 4);
        u16x8 v;
        v[0] = f2b((f0.x - mn[p]) * rs[p] * g0.x + e0.x);
        v[1] = f2b((f0.y - mn[p]) * rs[p] * g0.y + e0.y);
        v[2] = f2b((f0.z - mn[p]) * rs[p] * g0.z + e0.z);
        v[3] = f2b((f0.w - mn[p]) * rs[p] * g0.w + e0.w);
        v[4] = f2b((f1.x - mn[p]) * rs[p] * g1.x + e1.x);
        v[5] = f2b((f1.y - mn[p]) * rs[p] * g1.y + e1.y);
        v[6] = f2b((f1.z - mn[p]) * rs[p] * g1.z + e1.z);
        v[7] = f2b((f1.w - mn[p]) * rs[p] * g1.w + e1.w);
        *(u16x8*)(&As[0][r][sq]) = v;
      }
      #pragma unroll
      for (int c = 0; c < 2; c++){
        const int ch = wave * 2 + c;
        gload16(BT + (size_t)(bx * 128 + ch * 16 + srow) * K + k0 + sseg * 8,
                &Bs[0][ch * 16][0]);
      }
      __syncthreads();
      domfma(0);
      __syncthreads();
    }
  }

  const int gm0 = by * 128 + wr, gn0 = bx * 128 + wc;
  #pragma unroll
  for (int i = 0; i < 4; i++){
    #pragma unroll
    for (int r = 0; r < 4; r++){
      int gm = gm0 + i * 16 + l4 * 4 + r;
      int orow = rowperm ? ((gm & 63) * 128 + (gm >> 6)) : gm;
      #pragma unroll
      for (int j = 0; j < 4; j++){
        int gn = gn0 + j * 16 + l15;
        float v = acc[i][j][r];
        if (bias) v += bias[gn];
        if (act)  v = v * (1.0f / (1.0f + expf(-1.702f * v)));  // QuickGELU
        if (addsrc) v += addsrc[(size_t)orow * N + gn];
        if (outbf16) ((u16*)C)[(size_t)orow * N + gn] = f2b(v);
        else         ((float*)C)[(size_t)orow * N + gn] = v;
      }
    }
  }
}

// ---- MFMA Perceiver attention: block=(bt,head), 4 waves x 16 q-rows ----
__global__ __launch_bounds__(256) void pattn_k(
    const u16* __restrict__ q, const u16* __restrict__ kvx,
    const u16* __restrict__ kvll, u16* __restrict__ o)
{
  __shared__ __align__(16) u16 Ks[64][72];
  __shared__ __align__(16) u16 Vs[64][72];
  __shared__ __align__(16) u16 Ps[64][72];
  const int blk = blockIdx.x;            // bt*8 + h
  const int hh = blk & 7, bt = blk >> 3;
  const int tt = bt & 7;
  const int tid = threadIdx.x;
  const int wv = tid >> 6, ln = tid & 63;
  const int l15 = ln & 15, lg = ln >> 4;
  const int i0 = wv * 16;
  const int sj = tid >> 2, sc = (tid & 3) * 16;

  bhalf8 qf[2];
  {
    const u16* qp = q + ((size_t)(tt * 64 + i0 + l15)) * 512 + hh * 64 + lg * 8;
    qf[0] = *(const bhalf8*)(qp);
    qf[1] = *(const bhalf8*)(qp + 32);
  }

  floatx4 sacc[20];
  #pragma unroll
  for (int t = 0; t < 20; t++) sacc[t] = (floatx4){0.f,0.f,0.f,0.f};

  for (int ch = 0; ch < 5; ++ch){
    const u16* src = (ch < 4)
        ? (kvx  + ((size_t)(bt * 256 + ch * 64 + sj)) * 1024 + hh * 64 + sc)
        : (kvll + ((size_t)(tt * 64 + sj)) * 1024 + hh * 64 + sc);
    u16x8 k0 = *(const u16x8*)(src);
    u16x8 k1 = *(const u16x8*)(src + 8);
    __syncthreads();
    *(u16x8*)(&Ks[sj][sc])     = k0;
    *(u16x8*)(&Ks[sj][sc + 8]) = k1;
    __syncthreads();
    #pragma unroll
    for (int jt = 0; jt < 4; jt++){
      bhalf8 kf0 = *(const bhalf8*)(&Ks[jt*16 + l15][lg*8]);
      bhalf8 kf1 = *(const bhalf8*)(&Ks[jt*16 + l15][32 + lg*8]);
      sacc[ch*4+jt] = __builtin_amdgcn_mfma_f32_16x16x32_bf16(qf[0], kf0, sacc[ch*4+jt], 0,0,0);
      sacc[ch*4+jt] = __builtin_amdgcn_mfma_f32_16x16x32_bf16(qf[1], kf1, sacc[ch*4+jt], 0,0,0);
    }
  }

  float inv_l[4];
  float mx[4];
  #pragma unroll
  for (int r = 0; r < 4; r++){
    float m = -1e30f;
    #pragma unroll
    for (int t = 0; t < 20; t++) m = fmaxf(m, sacc[t][r]);
    m = fmaxf(m, __shfl_xor(m, 1));
    m = fmaxf(m, __shfl_xor(m, 2));
    m = fmaxf(m, __shfl_xor(m, 4));
    m = fmaxf(m, __shfl_xor(m, 8));
    mx[r] = m;
  }
  #pragma unroll
  for (int r = 0; r < 4; r++){
    float s = 0.f;
    #pragma unroll
    for (int t = 0; t < 20; t++){
      float p = expf(0.125f * (sacc[t][r] - mx[r]));
      sacc[t][r] = p;
      s += p;
    }
    s += __shfl_xor(s, 1); s += __shfl_xor(s, 2);
    s += __shfl_xor(s, 4); s += __shfl_xor(s, 8);
    inv_l[r] = 1.0f / s;
  }

  floatx4 oacc[4];
  #pragma unroll
  for (int dt = 0; dt < 4; dt++) oacc[dt] = (floatx4){0.f,0.f,0.f,0.f};
  for (int ch = 0; ch < 5; ++ch){
    const u16* src = (ch < 4)
        ? (kvx  + ((size_t)(bt * 256 + ch * 64 + sj)) * 1024 + 512 + hh * 64 + sc)
        : (kvll + ((size_t)(tt * 64 + sj)) * 1024 + 512 + hh * 64 + sc);
    u16x8 v0 = *(const u16x8*)(src);
    u16x8 v1 = *(const u16x8*)(src + 8);
    __syncthreads();
    #pragma unroll
    for (int e = 0; e < 8; e++) Vs[sc + e][sj]     = v0[e];
    #pragma unroll
    for (int e = 0; e < 8; e++) Vs[sc + 8 + e][sj] = v1[e];
    #pragma unroll
    for (int jt = 0; jt < 4; jt++){
      #pragma unroll
      for (int r = 0; r < 4; r++)
        Ps[i0 + 4*lg + r][jt*16 + l15] = f2b(sacc[ch*4+jt][r]);
    }
    __syncthreads();
    #pragma unroll
    for (int kk = 0; kk < 2; kk++){
      bhalf8 pf = *(const bhalf8*)(&Ps[i0 + l15][kk*32 + lg*8]);
      #pragma unroll
      for (int dt = 0; dt < 4; dt++){
        bhalf8 vfr = *(const bhalf8*)(&Vs[dt*16 + l15][kk*32 + lg*8]);
        oacc[dt] = __builtin_amdgcn_mfma_f32_16x16x32_bf16(pf, vfr, oacc[dt], 0,0,0);
      }
    }
  }

  u16* op = o + ((size_t)(bt*64 + i0 + 4*lg)) * 512 + hh*64 + l15;
  #pragma unroll
  for (int dt = 0; dt < 4; dt++)
    #pragma unroll
    for (int r = 0; r < 4; r++)
      op[(size_t)r * 512 + dt*16] = f2b(oacc[dt][r] * inv_l[r]);
}

// ---- MFMA self-attention: block=(bt,head), 4 waves x 16 q-rows, 64 keys ----
__global__ __launch_bounds__(256) void sattn_k(
    const u16* __restrict__ qkv, u16* __restrict__ o2)
{
  __shared__ __align__(16) u16 Ks[64][72];
  __shared__ __align__(16) u16 Vs[64][72];
  __shared__ __align__(16) u16 Ps[64][72];
  const int blk = blockIdx.x;
  const int hh = blk % 12, bt = blk / 12;
  const int tid = threadIdx.x;
  const int wv = tid >> 6, ln = tid & 63;
  const int l15 = ln & 15, lg = ln >> 4;
  const int i0 = wv * 16;
  const int sj = tid >> 2, sc = (tid & 3) * 16;

  const u16* kp = qkv + ((size_t)sj * 128 + bt) * 2304 + 768 + hh * 64 + sc;
  u16x8 k0 = *(const u16x8*)(kp);
  u16x8 k1 = *(const u16x8*)(kp + 8);
  u16x8 v0 = *(const u16x8*)(kp + 768);
  u16x8 v1 = *(const u16x8*)(kp + 776);
  *(u16x8*)(&Ks[sj][sc])     = k0;
  *(u16x8*)(&Ks[sj][sc + 8]) = k1;
  #pragma unroll
  for (int e = 0; e < 8; e++) Vs[sc + e][sj]     = v0[e];
  #pragma unroll
  for (int e = 0; e < 8; e++) Vs[sc + 8 + e][sj] = v1[e];

  bhalf8 qf[2];
  {
    const u16* qp = qkv + ((size_t)(i0 + l15) * 128 + bt) * 2304 + hh * 64 + lg * 8;
    qf[0] = *(const bhalf8*)(qp);
    qf[1] = *(const bhalf8*)(qp + 32);
  }
  __syncthreads();

  floatx4 sacc[4];
  #pragma unroll
  for (int t = 0; t < 4; t++) sacc[t] = (floatx4){0.f,0.f,0.f,0.f};
  #pragma unroll
  for (int jt = 0; jt < 4; jt++){
    bhalf8 kf0 = *(const bhalf8*)(&Ks[jt*16 + l15][lg*8]);
    bhalf8 kf1 = *(const bhalf8*)(&Ks[jt*16 + l15][32 + lg*8]);
    sacc[jt] = __builtin_amdgcn_mfma_f32_16x16x32_bf16(qf[0], kf0, sacc[jt], 0,0,0);
    sacc[jt] = __builtin_amdgcn_mfma_f32_16x16x32_bf16(qf[1], kf1, sacc[jt], 0,0,0);
  }

  float inv_l[4];
  #pragma unroll
  for (int r = 0; r < 4; r++){
    float m = -1e30f;
    #pragma unroll
    for (int t = 0; t < 4; t++) m = fmaxf(m, sacc[t][r]);
    m = fmaxf(m, __shfl_xor(m, 1));
    m = fmaxf(m, __shfl_xor(m, 2));
    m = fmaxf(m, __shfl_xor(m, 4));
    m = fmaxf(m, __shfl_xor(m, 8));
    float s = 0.f;
    #pragma unroll
    for (int t = 0; t < 4; t++){
      float p = expf(0.125f * (sacc[t][r] - m));
      sacc[t][r] = p;
      s += p;
    }
    s += __shfl_xor(s, 1); s += __shfl_xor(s, 2);
    s += __shfl_xor(s, 4); s += __shfl_xor(s, 8);
    inv_l[r] = 1.0f / s;
  }

  #pragma unroll
  for (int jt = 0; jt < 4; jt++){
    #pragma unroll
    for (int r = 0; r < 4; r++)
      Ps[i0 + 4*lg + r][jt*16 + l15] = f2b(sacc[jt][r]);
  }
  __syncthreads();

  floatx4 oacc[4];
  #pragma unroll
  for (int dt = 0; dt < 4; dt++) oacc[dt] = (floatx4){0.f,0.f,0.f,0.f};
  #pragma unroll
  for (int kk = 0; kk < 2; kk++){
    bhalf8 pf = *(const bhalf8*)(&Ps[i0 + l15][kk*32 + lg*8]);
    #pragma unroll
    for (int dt = 0; dt < 4; dt++){
      bhalf8 vfr = *(const bhalf8*)(&Vs[dt*16 + l15][kk*32 + lg*8]);
      oacc[dt] = __builtin_amdgcn_mfma_f32_16x16x32_bf16(pf, vfr, oacc[dt], 0,0,0);
    }
  }

  u16* op = o2 + ((size_t)((i0 + 4*lg) * 128 + bt)) * 768 + hh*64 + l15;
  #pragma unroll
  for (int dt = 0; dt < 4; dt++)
    #pragma unroll
    for (int r = 0; r < 4; r++)
      op[(size_t)r * 128 * 768 + dt*16] = f2b(oacc[dt][r] * inv_l[r]);
}

extern "C" void kernel_launch(void* const* d_in, const int* in_sizes, int n_in,
                              void* d_out, int out_size, void* d_ws, size_t ws_size,
                              hipStream_t stream)
{
  const float* vf   = (const float*)d_in[0];
  const float* lat  = (const float*)d_in[1];
  const float* nl0g = (const float*)d_in[2];
  const float* nl0b = (const float*)d_in[3];
  const float* pmg  = (const float*)d_in[4];
  const float* pmb  = (const float*)d_in[5];
  const float* plg  = (const float*)d_in[6];
  const float* plb  = (const float*)d_in[7];
  const float* Wq   = (const float*)d_in[8];
  const float* Wkv  = (const float*)d_in[9];
  const float* Wo   = (const float*)d_in[10];
  const float* ln1g = (const float*)d_in[11];
  const float* ln1b = (const float*)d_in[12];
  const float* Wqkv = (const float*)d_in[13];
  const float* bqkv = (const float*)d_in[14];
  const float* Wout = (const float*)d_in[15];
  const float* bout = (const float*)d_in[16];
  const float* ln2g = (const float*)d_in[17];
  const float* ln2b = (const float*)d_in[18];
  const float* Wfc  = (const float*)d_in[19];
  const float* bfc  = (const float*)d_in[20];
  const float* Wpr  = (const float*)d_in[21];
  const float* bpr  = (const float*)d_in[22];

  // ---- ws layout: base high-water 104,857,600 B; optional xm at 117.4M ----
  char* ws = (char*)d_ws;
  u16*    kvx   = (u16*)(ws + 0);          // 67,108,864 (dead after pattn)
  u16*    qkvb  = (u16*)(ws + 0);          // 37,748,736 (dead after sattn)
  u16*    o2b   = (u16*)(ws + 37748736);   // 12,582,912 (dead after Wout gemm)
  u16*    hb    = (u16*)(ws + 0);          // 50,331,648
  u16*    WoT   = (u16*)(ws + 50331648);
  u16*    WqkvT = (u16*)(ws + 51118080);
  u16*    WoutT = (u16*)(ws + 54657024);
  u16*    WfcT  = (u16*)(ws + 55836672);
  u16*    WprT  = (u16*)(ws + 60555264);   // ends 65,273,856
  u16*    WqT   = (u16*)(ws + 67108864);
  u16*    WkvT  = (u16*)(ws + 67895296);   // ends 69,468,160
  float*  yb    = (float*)(ws + 67108864); // written after WqT/WkvT dead
  u16*    llb   = (u16*)(ws + 92274688);
  float2* stx   = (float2*)(ws + 93061120);
  u16*    qb    = (u16*)(ws + 93323264);
  u16*    kvll  = (u16*)(ws + 94371840);
  u16*    ob    = (u16*)(ws + 95420416);   // ends 103,809,024
  u16*    zb    = (u16*)(ws + 92274688);   // overlays ll..ob when dead
  u16*    xm    = (u16*)(ws + 117440512);  // 50,331,648, ends 167,772,160
  const bool use_xm = (ws_size >= 167772160ull);

  const float* nof = nullptr;
  const float2* nos = nullptr;

  hipLaunchKernelGGL(transp_k, dim3(384), dim3(256), 0, stream, Wq, WqT, 768, 512);
  hipLaunchKernelGGL(transp_k, dim3(768), dim3(256), 0, stream, Wkv, WkvT, 768, 1024);
  hipLaunchKernelGGL(ln_lat2_k, dim3(512), dim3(256), 0, stream,
                     lat, llb, nl0g, nl0b, plg, plb);
  hipLaunchKernelGGL(mgemm_k<0>, dim3(16), dim3(256), 0, stream,
                     (const void*)llb, WqT, (void*)qb, 512, 512, 768,
                     nof, 0, nof, 0, 1, nos, nof, nof);
  hipLaunchKernelGGL(mgemm_k<0>, dim3(32), dim3(256), 0, stream,
                     (const void*)llb, WkvT, (void*)kvll, 512, 1024, 768,
                     nof, 0, nof, 0, 1, nos, nof, nof);
  if (use_xm){
    hipLaunchKernelGGL(ln_x_k, dim3(32768), dim3(256), 0, stream, vf, xm, pmg, pmb);
    hipLaunchKernelGGL(mgemm_k<0>, dim3(2048), dim3(256), 0, stream,
                       (const void*)xm, WkvT, (void*)kvx, 32768, 1024, 768,
                       nof, 0, nof, 0, 1, nos, nof, nof);
  } else {
    hipLaunchKernelGGL(stats_x_k, dim3(32768), dim3(256), 0, stream, vf, stx);
    hipLaunchKernelGGL(mgemm_k<1>, dim3(2048), dim3(256), 0, stream,
                       (const void*)vf, WkvT, (void*)kvx, 32768, 1024, 768,
                       nof, 0, nof, 0, 1, stx, pmg, pmb);
  }
  hipLaunchKernelGGL(pattn_k, dim3(1024), dim3(256), 0, stream, qb, kvx, kvll, ob);
  hipLaunchKernelGGL(transp_k, dim3(384), dim3(256), 0, stream, Wo, WoT, 512, 768);
  hipLaunchKernelGGL(transp_k, dim3(1728), dim3(256), 0, stream, Wqkv, WqkvT, 768, 2304);
  hipLaunchKernelGGL(transp_k, dim3(576), dim3(256), 0, stream, Wout, WoutT, 768, 768);
  hipLaunchKernelGGL(transp_k, dim3(2304), dim3(256), 0, stream, Wfc, WfcT, 768, 3072);
  hipLaunchKernelGGL(transp_k, dim3(2304), dim3(256), 0, stream, Wpr, WprT, 3072, 768);
  hipLaunchKernelGGL(mgemm_k<0>, dim3(384), dim3(256), 0, stream,
                     (const void*)ob, WoT, (void*)yb, 8192, 768, 512,
                     nof, 0, nof, 1, 0, nos, nof, nof);
  hipLaunchKernelGGL(ln_f32_k, dim3(8192), dim3(256), 0, stream, yb, zb, ln1g, ln1b);
  hipLaunchKernelGGL(mgemm_k<0>, dim3(1152), dim3(256), 0, stream,
                     (const void*)zb, WqkvT, (void*)qkvb, 8192, 2304, 768,
                     bqkv, 0, nof, 0, 1, nos, nof, nof);
  hipLaunchKernelGGL(sattn_k, dim3(1536), dim3(256), 0, stream, qkvb, o2b);
  hipLaunchKernelGGL(mgemm_k<0>, dim3(384), dim3(256), 0, stream,
                     (const void*)o2b, WoutT, (void*)yb, 8192, 768, 768,
                     bout, 0, yb, 0, 0, nos, nof, nof);
  hipLaunchKernelGGL(ln_f32_k, dim3(8192), dim3(256), 0, stream, yb, zb, ln2g, ln2b);
  hipLaunchKernelGGL(mgemm_k<0>, dim3(1536), dim3(256), 0, stream,
                     (const void*)zb, WfcT, (void*)hb, 8192, 3072, 768,
                     bfc, 1, nof, 0, 1, nos, nof, nof);
  hipLaunchKernelGGL(mgemm_k<0>, dim3(384), dim3(256), 0, stream,
                     (const void*)hb, WprT, d_out, 8192, 768, 3072,
                     bpr, 0, yb, 0, 0, nos, nof, nof);
}

// Round 9
// 561.390 us; speedup vs baseline: 7.2601x; 1.0003x over previous
//
#include <hip/hip_runtime.h>
#include <hip/hip_bf16.h>
#include <cstdint>
#include <cstddef>

typedef unsigned short u16;
typedef __bf16 bhalf8 __attribute__((ext_vector_type(8)));
typedef float floatx4 __attribute__((ext_vector_type(4)));
typedef unsigned short u16x8 __attribute__((ext_vector_type(8)));

__device__ __forceinline__ float b2f(u16 u){
  union { uint32_t i; float f; } x; x.i = ((uint32_t)u) << 16; return x.f;
}
__device__ __forceinline__ u16 f2b(float f){
  uint32_t i = __float_as_uint(f);
  uint32_t r = (i + 0x7FFFu + ((i >> 16) & 1u)) >> 16;   // round-nearest-even
  return (u16)r;
}

// async global->LDS DMA, 16B per lane; LDS dest = wave-uniform base + lane*16
__device__ __forceinline__ void gload16(const u16* g, u16* l){
  __builtin_amdgcn_global_load_lds(
      (const __attribute__((address_space(1))) uint32_t*)g,
      (__attribute__((address_space(3))) uint32_t*)l, 16, 0, 0);
}

// ---- block-wide sum over 256 threads (4 waves) ----
__device__ __forceinline__ float block_sum256(float v, float* sh){
  #pragma unroll
  for (int o = 32; o > 0; o >>= 1) v += __shfl_down(v, o);
  __syncthreads();
  if ((threadIdx.x & 63u) == 0) sh[threadIdx.x >> 6] = v;
  __syncthreads();
  return sh[0] + sh[1] + sh[2] + sh[3];
}

// ---- per-row LN stats of visual_feat (fp32), rearranged row order ----
__global__ __launch_bounds__(256) void stats_x_k(
    const float* __restrict__ vf, float2* __restrict__ st)
{
  __shared__ float sh[4];
  const int r  = blockIdx.x;
  const int nn = r & 255, bt = r >> 8;
  const float* in = vf + ((size_t)nn * 128 + bt) * 768;
  const int t = threadIdx.x;
  float v0 = in[t], v1 = in[t + 256], v2 = in[t + 512];
  float mean = block_sum256(v0 + v1 + v2, sh) * (1.0f / 768.0f);
  float d0 = v0 - mean, d1 = v1 - mean, d2 = v2 - mean;
  float var = block_sum256(d0*d0 + d1*d1 + d2*d2, sh) * (1.0f / 768.0f);
  if (t == 0) st[r] = make_float2(mean, rsqrtf(var + 1e-5f));
}

// ---- full LN of visual_feat -> bf16 xm, rearranged row order ----
__global__ __launch_bounds__(256) void ln_x_k(
    const float* __restrict__ vf, u16* __restrict__ xm,
    const float* __restrict__ g, const float* __restrict__ b)
{
  __shared__ float sh[4];
  const int r  = blockIdx.x;             // r = bt*256 + nn
  const int nn = r & 255, bt = r >> 8;
  const float* in = vf + ((size_t)nn * 128 + bt) * 768;
  const int t = threadIdx.x;
  float v[3];
  #pragma unroll
  for (int i = 0; i < 3; i++) v[i] = in[t + 256 * i];
  float mean = block_sum256(v[0] + v[1] + v[2], sh) * (1.0f / 768.0f);
  float d0 = v[0] - mean, d1 = v[1] - mean, d2 = v[2] - mean;
  float var = block_sum256(d0*d0 + d1*d1 + d2*d2, sh) * (1.0f / 768.0f);
  float rs = rsqrtf(var + 1e-5f);
  #pragma unroll
  for (int i = 0; i < 3; i++){
    int c = t + 256 * i;
    xm[(size_t)r * 768 + c] = f2b((v[i] - mean) * rs * g[c] + b[c]);
  }
}

// ---- double LayerNorm of latents (fp32 in) -> bf16 ----
__global__ __launch_bounds__(256) void ln_lat2_k(
    const float* __restrict__ lat, u16* __restrict__ ll,
    const float* __restrict__ g0, const float* __restrict__ b0,
    const float* __restrict__ g1, const float* __restrict__ b1)
{
  __shared__ float sh[4];
  const int r = blockIdx.x;
  const int t = threadIdx.x;
  const float* in = lat + (size_t)r * 768;
  float v[3];
  #pragma unroll
  for (int i = 0; i < 3; i++) v[i] = in[t + 256 * i];
  #pragma unroll
  for (int pass = 0; pass < 2; ++pass){
    float mean = block_sum256(v[0] + v[1] + v[2], sh) * (1.0f / 768.0f);
    float d0 = v[0] - mean, d1 = v[1] - mean, d2 = v[2] - mean;
    float var = block_sum256(d0*d0 + d1*d1 + d2*d2, sh) * (1.0f / 768.0f);
    float rs = rsqrtf(var + 1e-5f);
    const float* g = pass ? g1 : g0;
    const float* b = pass ? b1 : b0;
    #pragma unroll
    for (int i = 0; i < 3; i++){
      int c = t + 256 * i;
      v[i] = (v[i] - mean) * rs * g[c] + b[c];
    }
  }
  #pragma unroll
  for (int i = 0; i < 3; i++) ll[(size_t)r * 768 + t + 256 * i] = f2b(v[i]);
}

// ---- LN of fp32 ws rows -> bf16 ----
__global__ __launch_bounds__(256) void ln_f32_k(
    const float* __restrict__ y, u16* __restrict__ z,
    const float* __restrict__ g, const float* __restrict__ b)
{
  __shared__ float sh[4];
  const int r = blockIdx.x;
  const float* in = y + (size_t)r * 768;
  const int t = threadIdx.x;
  float v[3];
  #pragma unroll
  for (int i = 0; i < 3; i++) v[i] = in[t + 256 * i];
  float mean = block_sum256(v[0] + v[1] + v[2], sh) * (1.0f / 768.0f);
  float d0 = v[0] - mean, d1 = v[1] - mean, d2 = v[2] - mean;
  float var = block_sum256(d0*d0 + d1*d1 + d2*d2, sh) * (1.0f / 768.0f);
  float rs = rsqrtf(var + 1e-5f);
  #pragma unroll
  for (int i = 0; i < 3; i++){
    int c = t + 256 * i;
    z[(size_t)r * 768 + c] = f2b((v[i] - mean) * rs * g[c] + b[c]);
  }
}

// ---- weight transpose + bf16 convert: src (K,N) f32 -> dst (N,K) bf16 ----
__global__ __launch_bounds__(256) void transp_k(
    const float* __restrict__ src, u16* __restrict__ dst, int K, int N)
{
  __shared__ u16 sh[32][33];
  const int nb = N >> 5;
  const int bx = blockIdx.x % nb, byy = blockIdx.x / nb;
  const int tx = threadIdx.x & 31, ty = threadIdx.x >> 5;
  #pragma unroll
  for (int i = 0; i < 4; i++){
    int k = byy * 32 + ty + i * 8, n = bx * 32 + tx;
    sh[tx][ty + i * 8] = f2b(src[(size_t)k * N + n]);
  }
  __syncthreads();
  #pragma unroll
  for (int i = 0; i < 4; i++){
    int n = bx * 32 + ty + i * 8, k = byy * 32 + tx;
    dst[(size_t)n * K + k] = sh[ty + i * 8][tx];
  }
}

// ---- MFMA GEMM, 2-phase pipelined (T3/T4 minimum recipe) ----
// AMODE 0: A bf16, DMA-staged, double-buffered LDS, counted vmcnt(4) — the
// prefetch's 4 DMAs stay in flight across both barriers (never drain to 0).
// AMODE 1 (fallback): fp32 vf + fused LN, full-drain structure (proven R5).
template<int AMODE>
__global__ __launch_bounds__(256) void mgemm_k(
    const void* __restrict__ A, const u16* __restrict__ BT, void* __restrict__ C,
    int M, int N, int K,
    const float* __restrict__ bias, int act,
    const float* addsrc, int rowperm, int outbf16,
    const float2* __restrict__ stx, const float* __restrict__ gam,
    const float* __restrict__ bet)
{
  __shared__ __align__(16) u16 As[2][128][32];
  __shared__ __align__(16) u16 Bs[2][128][32];
  const int nb = N >> 7;
  const int swz = ((blockIdx.x & 7) * (gridDim.x >> 3)) + (blockIdx.x >> 3);
  const int bx = swz % nb, by = swz / nb;
  const int tid  = threadIdx.x;
  const int wave = tid >> 6, lane = tid & 63;
  const int wr = (wave >> 1) * 64, wc = (wave & 1) * 64;
  const int l15 = lane & 15, l4 = lane >> 4;
  const int srow = lane >> 2, sseg = lane & 3;   // DMA staging decomposition
  const int sr = tid >> 2, sq = (tid & 3) * 8;   // reg staging (AMODE 1)

  const u16*   Abf = (const u16*)A;
  const float* Af  = (const float*)A;

  floatx4 acc[4][4];
  #pragma unroll
  for (int i = 0; i < 4; i++)
    #pragma unroll
    for (int j = 0; j < 4; j++) acc[i][j] = (floatx4){0.f, 0.f, 0.f, 0.f};

  auto stage = [&](int buf, int k0){
    #pragma unroll
    for (int c = 0; c < 2; c++){
      const int ch = wave * 2 + c;              // chunk: rows [ch*16, +16)
      gload16(Abf + (size_t)(by * 128 + ch * 16 + srow) * K + k0 + sseg * 8,
              &As[buf][ch * 16][0]);
      gload16(BT  + (size_t)(bx * 128 + ch * 16 + srow) * K + k0 + sseg * 8,
              &Bs[buf][ch * 16][0]);
    }
  };
  auto domfma = [&](int buf){
    bhalf8 af[4], bfv[4];
    #pragma unroll
    for (int i = 0; i < 4; i++){
      af[i]  = *(const bhalf8*)(&As[buf][wr + i * 16 + l15][l4 * 8]);
      bfv[i] = *(const bhalf8*)(&Bs[buf][wc + i * 16 + l15][l4 * 8]);
    }
    #pragma unroll
    for (int i = 0; i < 4; i++)
      #pragma unroll
      for (int j = 0; j < 4; j++)
        acc[i][j] = __builtin_amdgcn_mfma_f32_16x16x32_bf16(af[i], bfv[j], acc[i][j], 0, 0, 0);
  };

  if (AMODE == 0){
    stage(0, 0);
    const int nk = K >> 5;
    for (int kt = 0; kt < nk; ++kt){
      const int cur = kt & 1;
      if (kt + 1 < nk){
        stage(cur ^ 1, (kt + 1) << 5);          // prefetch next K-tile
        asm volatile("s_waitcnt vmcnt(4)" ::: "memory");  // wait cur only
      } else {
        asm volatile("s_waitcnt vmcnt(0)" ::: "memory");  // tail: drain
      }
      __builtin_amdgcn_s_barrier();             // cur tile visible to all
      domfma(cur);
      __builtin_amdgcn_s_barrier();             // reads done before overwrite
    }
  } else {
    int   asrc[2]; float mn[2], rs[2];
    #pragma unroll
    for (int p = 0; p < 2; p++){
      int gm = by * 128 + sr + p * 64;
      asrc[p] = (gm & 255) * 128 + (gm >> 8);
      float2 s = stx[gm]; mn[p] = s.x; rs[p] = s.y;
    }
    for (int k0 = 0; k0 < K; k0 += 32){
      #pragma unroll
      for (int p = 0; p < 2; p++){
        const int r = sr + p * 64;
        const float* ap = Af + (size_t)asrc[p] * K + k0 + sq;
        float4 f0 = *(const float4*)ap, f1 = *(const float4*)(ap + 4);
        float4 g0 = *(const float4*)(gam + k0 + sq), g1 = *(const float4*)(gam + k0 + sq + 4);
        float4 e0 = *(const float4*)(bet + k0 + sq), e1 = *(const float4*)(bet + k0 + sq + 4);
        u16x8 v;
        v[0] = f2b((f0.x - mn[p]) * rs[p] * g0.x + e0.x);
        v[1] = f2b((f0.y - mn[p]) * rs[p] * g0.y + e0.y);
        v[2] = f2b((f0.z - mn[p]) * rs[p] * g0.z + e0.z);
        v[3] = f2b((f0.w - mn[p]) * rs[p] * g0.w + e0.w);
        v[4] = f2b((f1.x - mn[p]) * rs[p] * g1.x + e1.x);
        v[5] = f2b((f1.y - mn[p]) * rs[p] * g1.y + e1.y);
        v[6] = f2b((f1.z - mn[p]) * rs[p] * g1.z + e1.z);
        v[7] = f2b((f1.w - mn[p]) * rs[p] * g1.w + e1.w);
        *(u16x8*)(&As[0][r][sq]) = v;
      }
      #pragma unroll
      for (int c = 0; c < 2; c++){
        const int ch = wave * 2 + c;
        gload16(BT + (size_t)(bx * 128 + ch * 16 + srow) * K + k0 + sseg * 8,
                &Bs[0][ch * 16][0]);
      }
      __syncthreads();
      domfma(0);
      __syncthreads();
    }
  }

  const int gm0 = by * 128 + wr, gn0 = bx * 128 + wc;
  #pragma unroll
  for (int i = 0; i < 4; i++){
    #pragma unroll
    for (int r = 0; r < 4; r++){
      int gm = gm0 + i * 16 + l4 * 4 + r;
      int orow = rowperm ? ((gm & 63) * 128 + (gm >> 6)) : gm;
      #pragma unroll
      for (int j = 0; j < 4; j++){
        int gn = gn0 + j * 16 + l15;
        float v = acc[i][j][r];
        if (bias) v += bias[gn];
        if (act)  v = v * (1.0f / (1.0f + expf(-1.702f * v)));  // QuickGELU
        if (addsrc) v += addsrc[(size_t)orow * N + gn];
        if (outbf16) ((u16*)C)[(size_t)orow * N + gn] = f2b(v);
        else         ((float*)C)[(size_t)orow * N + gn] = v;
      }
    }
  }
}

// ---- MFMA Perceiver attention: block=(bt,head), 4 waves x 16 q-rows ----
__global__ __launch_bounds__(256) void pattn_k(
    const u16* __restrict__ q, const u16* __restrict__ kvx,
    const u16* __restrict__ kvll, u16* __restrict__ o)
{
  __shared__ __align__(16) u16 Ks[64][72];
  __shared__ __align__(16) u16 Vs[64][72];
  __shared__ __align__(16) u16 Ps[64][72];
  const int blk = blockIdx.x;            // bt*8 + h
  const int hh = blk & 7, bt = blk >> 3;
  const int tt = bt & 7;
  const int tid = threadIdx.x;
  const int wv = tid >> 6, ln = tid & 63;
  const int l15 = ln & 15, lg = ln >> 4;
  const int i0 = wv * 16;
  const int sj = tid >> 2, sc = (tid & 3) * 16;

  bhalf8 qf[2];
  {
    const u16* qp = q + ((size_t)(tt * 64 + i0 + l15)) * 512 + hh * 64 + lg * 8;
    qf[0] = *(const bhalf8*)(qp);
    qf[1] = *(const bhalf8*)(qp + 32);
  }

  floatx4 sacc[20];
  #pragma unroll
  for (int t = 0; t < 20; t++) sacc[t] = (floatx4){0.f,0.f,0.f,0.f};

  for (int ch = 0; ch < 5; ++ch){
    const u16* src = (ch < 4)
        ? (kvx  + ((size_t)(bt * 256 + ch * 64 + sj)) * 1024 + hh * 64 + sc)
        : (kvll + ((size_t)(tt * 64 + sj)) * 1024 + hh * 64 + sc);
    u16x8 k0 = *(const u16x8*)(src);
    u16x8 k1 = *(const u16x8*)(src + 8);
    __syncthreads();
    *(u16x8*)(&Ks[sj][sc])     = k0;
    *(u16x8*)(&Ks[sj][sc + 8]) = k1;
    __syncthreads();
    #pragma unroll
    for (int jt = 0; jt < 4; jt++){
      bhalf8 kf0 = *(const bhalf8*)(&Ks[jt*16 + l15][lg*8]);
      bhalf8 kf1 = *(const bhalf8*)(&Ks[jt*16 + l15][32 + lg*8]);
      sacc[ch*4+jt] = __builtin_amdgcn_mfma_f32_16x16x32_bf16(qf[0], kf0, sacc[ch*4+jt], 0,0,0);
      sacc[ch*4+jt] = __builtin_amdgcn_mfma_f32_16x16x32_bf16(qf[1], kf1, sacc[ch*4+jt], 0,0,0);
    }
  }

  float inv_l[4];
  float mx[4];
  #pragma unroll
  for (int r = 0; r < 4; r++){
    float m = -1e30f;
    #pragma unroll
    for (int t = 0; t < 20; t++) m = fmaxf(m, sacc[t][r]);
    m = fmaxf(m, __shfl_xor(m, 1));
    m = fmaxf(m, __shfl_xor(m, 2));
    m = fmaxf(m, __shfl_xor(m, 4));
    m = fmaxf(m, __shfl_xor(m, 8));
    mx[r] = m;
  }
  #pragma unroll
  for (int r = 0; r < 4; r++){
    float s = 0.f;
    #pragma unroll
    for (int t = 0; t < 20; t++){
      float p = expf(0.125f * (sacc[t][r] - mx[r]));
      sacc[t][r] = p;
      s += p;
    }
    s += __shfl_xor(s, 1); s += __shfl_xor(s, 2);
    s += __shfl_xor(s, 4); s += __shfl_xor(s, 8);
    inv_l[r] = 1.0f / s;
  }

  floatx4 oacc[4];
  #pragma unroll
  for (int dt = 0; dt < 4; dt++) oacc[dt] = (floatx4){0.f,0.f,0.f,0.f};
  for (int ch = 0; ch < 5; ++ch){
    const u16* src = (ch < 4)
        ? (kvx  + ((size_t)(bt * 256 + ch * 64 + sj)) * 1024 + 512 + hh * 64 + sc)
        : (kvll + ((size_t)(tt * 64 + sj)) * 1024 + 512 + hh * 64 + sc);
    u16x8 v0 = *(const u16x8*)(src);
    u16x8 v1 = *(const u16x8*)(src + 8);
    __syncthreads();
    #pragma unroll
    for (int e = 0; e < 8; e++) Vs[sc + e][sj]     = v0[e];
    #pragma unroll
    for (int e = 0; e < 8; e++) Vs[sc + 8 + e][sj] = v1[e];
    #pragma unroll
    for (int jt = 0; jt < 4; jt++){
      #pragma unroll
      for (int r = 0; r < 4; r++)
        Ps[i0 + 4*lg + r][jt*16 + l15] = f2b(sacc[ch*4+jt][r]);
    }
    __syncthreads();
    #pragma unroll
    for (int kk = 0; kk < 2; kk++){
      bhalf8 pf = *(const bhalf8*)(&Ps[i0 + l15][kk*32 + lg*8]);
      #pragma unroll
      for (int dt = 0; dt < 4; dt++){
        bhalf8 vfr = *(const bhalf8*)(&Vs[dt*16 + l15][kk*32 + lg*8]);
        oacc[dt] = __builtin_amdgcn_mfma_f32_16x16x32_bf16(pf, vfr, oacc[dt], 0,0,0);
      }
    }
  }

  u16* op = o + ((size_t)(bt*64 + i0 + 4*lg)) * 512 + hh*64 + l15;
  #pragma unroll
  for (int dt = 0; dt < 4; dt++)
    #pragma unroll
    for (int r = 0; r < 4; r++)
      op[(size_t)r * 512 + dt*16] = f2b(oacc[dt][r] * inv_l[r]);
}

// ---- MFMA self-attention: block=(bt,head), 4 waves x 16 q-rows, 64 keys ----
__global__ __launch_bounds__(256) void sattn_k(
    const u16* __restrict__ qkv, u16* __restrict__ o2)
{
  __shared__ __align__(16) u16 Ks[64][72];
  __shared__ __align__(16) u16 Vs[64][72];
  __shared__ __align__(16) u16 Ps[64][72];
  const int blk = blockIdx.x;
  const int hh = blk % 12, bt = blk / 12;
  const int tid = threadIdx.x;
  const int wv = tid >> 6, ln = tid & 63;
  const int l15 = ln & 15, lg = ln >> 4;
  const int i0 = wv * 16;
  const int sj = tid >> 2, sc = (tid & 3) * 16;

  const u16* kp = qkv + ((size_t)sj * 128 + bt) * 2304 + 768 + hh * 64 + sc;
  u16x8 k0 = *(const u16x8*)(kp);
  u16x8 k1 = *(const u16x8*)(kp + 8);
  u16x8 v0 = *(const u16x8*)(kp + 768);
  u16x8 v1 = *(const u16x8*)(kp + 776);
  *(u16x8*)(&Ks[sj][sc])     = k0;
  *(u16x8*)(&Ks[sj][sc + 8]) = k1;
  #pragma unroll
  for (int e = 0; e < 8; e++) Vs[sc + e][sj]     = v0[e];
  #pragma unroll
  for (int e = 0; e < 8; e++) Vs[sc + 8 + e][sj] = v1[e];

  bhalf8 qf[2];
  {
    const u16* qp = qkv + ((size_t)(i0 + l15) * 128 + bt) * 2304 + hh * 64 + lg * 8;
    qf[0] = *(const bhalf8*)(qp);
    qf[1] = *(const bhalf8*)(qp + 32);
  }
  __syncthreads();

  floatx4 sacc[4];
  #pragma unroll
  for (int t = 0; t < 4; t++) sacc[t] = (floatx4){0.f,0.f,0.f,0.f};
  #pragma unroll
  for (int jt = 0; jt < 4; jt++){
    bhalf8 kf0 = *(const bhalf8*)(&Ks[jt*16 + l15][lg*8]);
    bhalf8 kf1 = *(const bhalf8*)(&Ks[jt*16 + l15][32 + lg*8]);
    sacc[jt] = __builtin_amdgcn_mfma_f32_16x16x32_bf16(qf[0], kf0, sacc[jt], 0,0,0);
    sacc[jt] = __builtin_amdgcn_mfma_f32_16x16x32_bf16(qf[1], kf1, sacc[jt], 0,0,0);
  }

  float inv_l[4];
  #pragma unroll
  for (int r = 0; r < 4; r++){
    float m = -1e30f;
    #pragma unroll
    for (int t = 0; t < 4; t++) m = fmaxf(m, sacc[t][r]);
    m = fmaxf(m, __shfl_xor(m, 1));
    m = fmaxf(m, __shfl_xor(m, 2));
    m = fmaxf(m, __shfl_xor(m, 4));
    m = fmaxf(m, __shfl_xor(m, 8));
    float s = 0.f;
    #pragma unroll
    for (int t = 0; t < 4; t++){
      float p = expf(0.125f * (sacc[t][r] - m));
      sacc[t][r] = p;
      s += p;
    }
    s += __shfl_xor(s, 1); s += __shfl_xor(s, 2);
    s += __shfl_xor(s, 4); s += __shfl_xor(s, 8);
    inv_l[r] = 1.0f / s;
  }

  #pragma unroll
  for (int jt = 0; jt < 4; jt++){
    #pragma unroll
    for (int r = 0; r < 4; r++)
      Ps[i0 + 4*lg + r][jt*16 + l15] = f2b(sacc[jt][r]);
  }
  __syncthreads();

  floatx4 oacc[4];
  #pragma unroll
  for (int dt = 0; dt < 4; dt++) oacc[dt] = (floatx4){0.f,0.f,0.f,0.f};
  #pragma unroll
  for (int kk = 0; kk < 2; kk++){
    bhalf8 pf = *(const bhalf8*)(&Ps[i0 + l15][kk*32 + lg*8]);
    #pragma unroll
    for (int dt = 0; dt < 4; dt++){
      bhalf8 vfr = *(const bhalf8*)(&Vs[dt*16 + l15][kk*32 + lg*8]);
      oacc[dt] = __builtin_amdgcn_mfma_f32_16x16x32_bf16(pf, vfr, oacc[dt], 0,0,0);
    }
  }

  u16* op = o2 + ((size_t)((i0 + 4*lg) * 128 + bt)) * 768 + hh*64 + l15;
  #pragma unroll
  for (int dt = 0; dt < 4; dt++)
    #pragma unroll
    for (int r = 0; r < 4; r++)
      op[(size_t)r * 128 * 768 + dt*16] = f2b(oacc[dt][r] * inv_l[r]);
}

extern "C" void kernel_launch(void* const* d_in, const int* in_sizes, int n_in,
                              void* d_out, int out_size, void* d_ws, size_t ws_size,
                              hipStream_t stream)
{
  const float* vf   = (const float*)d_in[0];
  const float* lat  = (const float*)d_in[1];
  const float* nl0g = (const float*)d_in[2];
  const float* nl0b = (const float*)d_in[3];
  const float* pmg  = (const float*)d_in[4];
  const float* pmb  = (const float*)d_in[5];
  const float* plg  = (const float*)d_in[6];
  const float* plb  = (const float*)d_in[7];
  const float* Wq   = (const float*)d_in[8];
  const float* Wkv  = (const float*)d_in[9];
  const float* Wo   = (const float*)d_in[10];
  const float* ln1g = (const float*)d_in[11];
  const float* ln1b = (const float*)d_in[12];
  const float* Wqkv = (const float*)d_in[13];
  const float* bqkv = (const float*)d_in[14];
  const float* Wout = (const float*)d_in[15];
  const float* bout = (const float*)d_in[16];
  const float* ln2g = (const float*)d_in[17];
  const float* ln2b = (const float*)d_in[18];
  const float* Wfc  = (const float*)d_in[19];
  const float* bfc  = (const float*)d_in[20];
  const float* Wpr  = (const float*)d_in[21];
  const float* bpr  = (const float*)d_in[22];

  // ---- ws layout: base high-water 104,857,600 B; optional xm at 117.4M ----
  char* ws = (char*)d_ws;
  u16*    kvx   = (u16*)(ws + 0);          // 67,108,864 (dead after pattn)
  u16*    qkvb  = (u16*)(ws + 0);          // 37,748,736 (dead after sattn)
  u16*    o2b   = (u16*)(ws + 37748736);   // 12,582,912 (dead after Wout gemm)
  u16*    hb    = (u16*)(ws + 0);          // 50,331,648
  u16*    WoT   = (u16*)(ws + 50331648);
  u16*    WqkvT = (u16*)(ws + 51118080);
  u16*    WoutT = (u16*)(ws + 54657024);
  u16*    WfcT  = (u16*)(ws + 55836672);
  u16*    WprT  = (u16*)(ws + 60555264);   // ends 65,273,856
  u16*    WqT   = (u16*)(ws + 67108864);
  u16*    WkvT  = (u16*)(ws + 67895296);   // ends 69,468,160
  float*  yb    = (float*)(ws + 67108864); // written after WqT/WkvT dead
  u16*    llb   = (u16*)(ws + 92274688);
  float2* stx   = (float2*)(ws + 93061120);
  u16*    qb    = (u16*)(ws + 93323264);
  u16*    kvll  = (u16*)(ws + 94371840);
  u16*    ob    = (u16*)(ws + 95420416);   // ends 103,809,024
  u16*    zb    = (u16*)(ws + 92274688);   // overlays ll..ob when dead
  u16*    xm    = (u16*)(ws + 117440512);  // 50,331,648, ends 167,772,160
  const bool use_xm = (ws_size >= 167772160ull);

  const float* nof = nullptr;
  const float2* nos = nullptr;

  hipLaunchKernelGGL(transp_k, dim3(384), dim3(256), 0, stream, Wq, WqT, 768, 512);
  hipLaunchKernelGGL(transp_k, dim3(768), dim3(256), 0, stream, Wkv, WkvT, 768, 1024);
  hipLaunchKernelGGL(ln_lat2_k, dim3(512), dim3(256), 0, stream,
                     lat, llb, nl0g, nl0b, plg, plb);
  hipLaunchKernelGGL(mgemm_k<0>, dim3(16), dim3(256), 0, stream,
                     (const void*)llb, WqT, (void*)qb, 512, 512, 768,
                     nof, 0, nof, 0, 1, nos, nof, nof);
  hipLaunchKernelGGL(mgemm_k<0>, dim3(32), dim3(256), 0, stream,
                     (const void*)llb, WkvT, (void*)kvll, 512, 1024, 768,
                     nof, 0, nof, 0, 1, nos, nof, nof);
  if (use_xm){
    hipLaunchKernelGGL(ln_x_k, dim3(32768), dim3(256), 0, stream, vf, xm, pmg, pmb);
    hipLaunchKernelGGL(mgemm_k<0>, dim3(2048), dim3(256), 0, stream,
                       (const void*)xm, WkvT, (void*)kvx, 32768, 1024, 768,
                       nof, 0, nof, 0, 1, nos, nof, nof);
  } else {
    hipLaunchKernelGGL(stats_x_k, dim3(32768), dim3(256), 0, stream, vf, stx);
    hipLaunchKernelGGL(mgemm_k<1>, dim3(2048), dim3(256), 0, stream,
                       (const void*)vf, WkvT, (void*)kvx, 32768, 1024, 768,
                       nof, 0, nof, 0, 1, stx, pmg, pmb);
  }
  hipLaunchKernelGGL(pattn_k, dim3(1024), dim3(256), 0, stream, qb, kvx, kvll, ob);
  hipLaunchKernelGGL(transp_k, dim3(384), dim3(256), 0, stream, Wo, WoT, 512, 768);
  hipLaunchKernelGGL(transp_k, dim3(1728), dim3(256), 0, stream, Wqkv, WqkvT, 768, 2304);
  hipLaunchKernelGGL(transp_k, dim3(576), dim3(256), 0, stream, Wout, WoutT, 768, 768);
  hipLaunchKernelGGL(transp_k, dim3(2304), dim3(256), 0, stream, Wfc, WfcT, 768, 3072);
  hipLaunchKernelGGL(transp_k, dim3(2304), dim3(256), 0, stream, Wpr, WprT, 3072, 768);
  hipLaunchKernelGGL(mgemm_k<0>, dim3(384), dim3(256), 0, stream,
                     (const void*)ob, WoT, (void*)yb, 8192, 768, 512,
                     nof, 0, nof, 1, 0, nos, nof, nof);
  hipLaunchKernelGGL(ln_f32_k, dim3(8192), dim3(256), 0, stream, yb, zb, ln1g, ln1b);
  hipLaunchKernelGGL(mgemm_k<0>, dim3(1152), dim3(256), 0, stream,
                     (const void*)zb, WqkvT, (void*)qkvb, 8192, 2304, 768,
                     bqkv, 0, nof, 0, 1, nos, nof, nof);
  hipLaunchKernelGGL(sattn_k, dim3(1536), dim3(256), 0, stream, qkvb, o2b);
  hipLaunchKernelGGL(mgemm_k<0>, dim3(384), dim3(256), 0, stream,
                     (const void*)o2b, WoutT, (void*)yb, 8192, 768, 768,
                     bout, 0, yb, 0, 0, nos, nof, nof);
  hipLaunchKernelGGL(ln_f32_k, dim3(8192), dim3(256), 0, stream, yb, zb, ln2g, ln2b);
  hipLaunchKernelGGL(mgemm_k<0>, dim3(1536), dim3(256), 0, stream,
                     (const void*)zb, WfcT, (void*)hb, 8192, 3072, 768,
                     bfc, 1, nof, 0, 1, nos, nof, nof);
  hipLaunchKernelGGL(mgemm_k<0>, dim3(384), dim3(256), 0, stream,
                     (const void*)hb, WprT, d_out, 8192, 768, 3072,
                     bpr, 0, yb, 0, 0, nos, nof, nof);
}

// Round 10
// 557.930 us; speedup vs baseline: 7.3051x; 1.0062x over previous
//
#include <hip/hip_runtime.h>
#include <hip/hip_bf16.h>
#include <cstdint>
#include <cstddef>

typedef unsigned short u16;
typedef __bf16 bhalf8 __attribute__((ext_vector_type(8)));
typedef float floatx4 __attribute__((ext_vector_type(4)));
typedef unsigned short u16x8 __attribute__((ext_vector_type(8)));

__device__ __forceinline__ float b2f(u16 u){
  union { uint32_t i; float f; } x; x.i = ((uint32_t)u) << 16; return x.f;
}
__device__ __forceinline__ u16 f2b(float f){
  uint32_t i = __float_as_uint(f);
  uint32_t r = (i + 0x7FFFu + ((i >> 16) & 1u)) >> 16;   // round-nearest-even
  return (u16)r;
}

// async global->LDS DMA, 16B per lane; LDS dest = wave-uniform base + lane*16
__device__ __forceinline__ void gload16(const u16* g, u16* l){
  __builtin_amdgcn_global_load_lds(
      (const __attribute__((address_space(1))) uint32_t*)g,
      (__attribute__((address_space(3))) uint32_t*)l, 16, 0, 0);
}

// ---- block-wide sum over 256 threads (4 waves) ----
__device__ __forceinline__ float block_sum256(float v, float* sh){
  #pragma unroll
  for (int o = 32; o > 0; o >>= 1) v += __shfl_down(v, o);
  __syncthreads();
  if ((threadIdx.x & 63u) == 0) sh[threadIdx.x >> 6] = v;
  __syncthreads();
  return sh[0] + sh[1] + sh[2] + sh[3];
}

// ---- per-row LN stats of visual_feat (fp32), rearranged row order ----
__global__ __launch_bounds__(256) void stats_x_k(
    const float* __restrict__ vf, float2* __restrict__ st)
{
  __shared__ float sh[4];
  const int r  = blockIdx.x;
  const int nn = r & 255, bt = r >> 8;
  const float* in = vf + ((size_t)nn * 128 + bt) * 768;
  const int t = threadIdx.x;
  float v0 = in[t], v1 = in[t + 256], v2 = in[t + 512];
  float mean = block_sum256(v0 + v1 + v2, sh) * (1.0f / 768.0f);
  float d0 = v0 - mean, d1 = v1 - mean, d2 = v2 - mean;
  float var = block_sum256(d0*d0 + d1*d1 + d2*d2, sh) * (1.0f / 768.0f);
  if (t == 0) st[r] = make_float2(mean, rsqrtf(var + 1e-5f));
}

// ---- full LN of visual_feat -> bf16 xm, rearranged row order ----
__global__ __launch_bounds__(256) void ln_x_k(
    const float* __restrict__ vf, u16* __restrict__ xm,
    const float* __restrict__ g, const float* __restrict__ b)
{
  __shared__ float sh[4];
  const int r  = blockIdx.x;             // r = bt*256 + nn
  const int nn = r & 255, bt = r >> 8;
  const float* in = vf + ((size_t)nn * 128 + bt) * 768;
  const int t = threadIdx.x;
  float v[3];
  #pragma unroll
  for (int i = 0; i < 3; i++) v[i] = in[t + 256 * i];
  float mean = block_sum256(v[0] + v[1] + v[2], sh) * (1.0f / 768.0f);
  float d0 = v[0] - mean, d1 = v[1] - mean, d2 = v[2] - mean;
  float var = block_sum256(d0*d0 + d1*d1 + d2*d2, sh) * (1.0f / 768.0f);
  float rs = rsqrtf(var + 1e-5f);
  #pragma unroll
  for (int i = 0; i < 3; i++){
    int c = t + 256 * i;
    xm[(size_t)r * 768 + c] = f2b((v[i] - mean) * rs * g[c] + b[c]);
  }
}

// ---- double LayerNorm of latents (fp32 in) -> bf16 ----
__global__ __launch_bounds__(256) void ln_lat2_k(
    const float* __restrict__ lat, u16* __restrict__ ll,
    const float* __restrict__ g0, const float* __restrict__ b0,
    const float* __restrict__ g1, const float* __restrict__ b1)
{
  __shared__ float sh[4];
  const int r = blockIdx.x;
  const int t = threadIdx.x;
  const float* in = lat + (size_t)r * 768;
  float v[3];
  #pragma unroll
  for (int i = 0; i < 3; i++) v[i] = in[t + 256 * i];
  #pragma unroll
  for (int pass = 0; pass < 2; ++pass){
    float mean = block_sum256(v[0] + v[1] + v[2], sh) * (1.0f / 768.0f);
    float d0 = v[0] - mean, d1 = v[1] - mean, d2 = v[2] - mean;
    float var = block_sum256(d0*d0 + d1*d1 + d2*d2, sh) * (1.0f / 768.0f);
    float rs = rsqrtf(var + 1e-5f);
    const float* g = pass ? g1 : g0;
    const float* b = pass ? b1 : b0;
    #pragma unroll
    for (int i = 0; i < 3; i++){
      int c = t + 256 * i;
      v[i] = (v[i] - mean) * rs * g[c] + b[c];
    }
  }
  #pragma unroll
  for (int i = 0; i < 3; i++) ll[(size_t)r * 768 + t + 256 * i] = f2b(v[i]);
}

// ---- LN of fp32 ws rows -> bf16 ----
__global__ __launch_bounds__(256) void ln_f32_k(
    const float* __restrict__ y, u16* __restrict__ z,
    const float* __restrict__ g, const float* __restrict__ b)
{
  __shared__ float sh[4];
  const int r = blockIdx.x;
  const float* in = y + (size_t)r * 768;
  const int t = threadIdx.x;
  float v[3];
  #pragma unroll
  for (int i = 0; i < 3; i++) v[i] = in[t + 256 * i];
  float mean = block_sum256(v[0] + v[1] + v[2], sh) * (1.0f / 768.0f);
  float d0 = v[0] - mean, d1 = v[1] - mean, d2 = v[2] - mean;
  float var = block_sum256(d0*d0 + d1*d1 + d2*d2, sh) * (1.0f / 768.0f);
  float rs = rsqrtf(var + 1e-5f);
  #pragma unroll
  for (int i = 0; i < 3; i++){
    int c = t + 256 * i;
    z[(size_t)r * 768 + c] = f2b((v[i] - mean) * rs * g[c] + b[c]);
  }
}

// ---- weight transpose + bf16 convert: src (K,N) f32 -> dst (N,K) bf16 ----
__global__ __launch_bounds__(256) void transp_k(
    const float* __restrict__ src, u16* __restrict__ dst, int K, int N)
{
  __shared__ u16 sh[32][33];
  const int nb = N >> 5;
  const int bx = blockIdx.x % nb, byy = blockIdx.x / nb;
  const int tx = threadIdx.x & 31, ty = threadIdx.x >> 5;
  #pragma unroll
  for (int i = 0; i < 4; i++){
    int k = byy * 32 + ty + i * 8, n = bx * 32 + tx;
    sh[tx][ty + i * 8] = f2b(src[(size_t)k * N + n]);
  }
  __syncthreads();
  #pragma unroll
  for (int i = 0; i < 4; i++){
    int n = bx * 32 + ty + i * 8, k = byy * 32 + tx;
    dst[(size_t)n * K + k] = sh[ty + i * 8][tx];
  }
}

// ---- MFMA GEMM, 2-phase pipelined (T3/T4 minimum recipe) ----
// AMODE 0: A bf16, DMA-staged, double-buffered LDS, counted vmcnt(4) — the
// prefetch's 4 DMAs stay in flight across both barriers (never drain to 0).
// AMODE 1 (fallback): fp32 vf + fused LN, full-drain structure (proven R5).
template<int AMODE>
__global__ __launch_bounds__(256) void mgemm_k(
    const void* __restrict__ A, const u16* __restrict__ BT, void* __restrict__ C,
    int M, int N, int K,
    const float* __restrict__ bias, int act,
    const float* addsrc, int rowperm, int outbf16,
    const float2* __restrict__ stx, const float* __restrict__ gam,
    const float* __restrict__ bet)
{
  __shared__ __align__(16) u16 As[2][128][32];
  __shared__ __align__(16) u16 Bs[2][128][32];
  const int nb = N >> 7;
  const int swz = ((blockIdx.x & 7) * (gridDim.x >> 3)) + (blockIdx.x >> 3);
  const int bx = swz % nb, by = swz / nb;
  const int tid  = threadIdx.x;
  const int wave = tid >> 6, lane = tid & 63;
  const int wr = (wave >> 1) * 64, wc = (wave & 1) * 64;
  const int l15 = lane & 15, l4 = lane >> 4;
  const int srow = lane >> 2, sseg = lane & 3;   // DMA staging decomposition
  const int sr = tid >> 2, sq = (tid & 3) * 8;   // reg staging (AMODE 1)

  const u16*   Abf = (const u16*)A;
  const float* Af  = (const float*)A;

  floatx4 acc[4][4];
  #pragma unroll
  for (int i = 0; i < 4; i++)
    #pragma unroll
    for (int j = 0; j < 4; j++) acc[i][j] = (floatx4){0.f, 0.f, 0.f, 0.f};

  auto stage = [&](int buf, int k0){
    #pragma unroll
    for (int c = 0; c < 2; c++){
      const int ch = wave * 2 + c;              // chunk: rows [ch*16, +16)
      gload16(Abf + (size_t)(by * 128 + ch * 16 + srow) * K + k0 + sseg * 8,
              &As[buf][ch * 16][0]);
      gload16(BT  + (size_t)(bx * 128 + ch * 16 + srow) * K + k0 + sseg * 8,
              &Bs[buf][ch * 16][0]);
    }
  };
  auto domfma = [&](int buf){
    bhalf8 af[4], bfv[4];
    #pragma unroll
    for (int i = 0; i < 4; i++){
      af[i]  = *(const bhalf8*)(&As[buf][wr + i * 16 + l15][l4 * 8]);
      bfv[i] = *(const bhalf8*)(&Bs[buf][wc + i * 16 + l15][l4 * 8]);
    }
    #pragma unroll
    for (int i = 0; i < 4; i++)
      #pragma unroll
      for (int j = 0; j < 4; j++)
        acc[i][j] = __builtin_amdgcn_mfma_f32_16x16x32_bf16(af[i], bfv[j], acc[i][j], 0, 0, 0);
  };

  if (AMODE == 0){
    stage(0, 0);
    const int nk = K >> 5;
    for (int kt = 0; kt < nk; ++kt){
      const int cur = kt & 1;
      if (kt + 1 < nk){
        stage(cur ^ 1, (kt + 1) << 5);          // prefetch next K-tile
        asm volatile("s_waitcnt vmcnt(4)" ::: "memory");  // wait cur only
      } else {
        asm volatile("s_waitcnt vmcnt(0)" ::: "memory");  // tail: drain
      }
      __builtin_amdgcn_s_barrier();             // cur tile visible to all
      domfma(cur);
      __builtin_amdgcn_s_barrier();             // reads done before overwrite
    }
  } else {
    int   asrc[2]; float mn[2], rs[2];
    #pragma unroll
    for (int p = 0; p < 2; p++){
      int gm = by * 128 + sr + p * 64;
      asrc[p] = (gm & 255) * 128 + (gm >> 8);
      float2 s = stx[gm]; mn[p] = s.x; rs[p] = s.y;
    }
    for (int k0 = 0; k0 < K; k0 += 32){
      #pragma unroll
      for (int p = 0; p < 2; p++){
        const int r = sr + p * 64;
        const float* ap = Af + (size_t)asrc[p] * K + k0 + sq;
        float4 f0 = *(const float4*)ap, f1 = *(const float4*)(ap + 4);
        float4 g0 = *(const float4*)(gam + k0 + sq), g1 = *(const float4*)(gam + k0 + sq + 4);
        float4 e0 = *(const float4*)(bet + k0 + sq), e1 = *(const float4*)(bet + k0 + sq + 4);
        u16x8 v;
        v[0] = f2b((f0.x - mn[p]) * rs[p] * g0.x + e0.x);
        v[1] = f2b((f0.y - mn[p]) * rs[p] * g0.y + e0.y);
        v[2] = f2b((f0.z - mn[p]) * rs[p] * g0.z + e0.z);
        v[3] = f2b((f0.w - mn[p]) * rs[p] * g0.w + e0.w);
        v[4] = f2b((f1.x - mn[p]) * rs[p] * g1.x + e1.x);
        v[5] = f2b((f1.y - mn[p]) * rs[p] * g1.y + e1.y);
        v[6] = f2b((f1.z - mn[p]) * rs[p] * g1.z + e1.z);
        v[7] = f2b((f1.w - mn[p]) * rs[p] * g1.w + e1.w);
        *(u16x8*)(&As[0][r][sq]) = v;
      }
      #pragma unroll
      for (int c = 0; c < 2; c++){
        const int ch = wave * 2 + c;
        gload16(BT + (size_t)(bx * 128 + ch * 16 + srow) * K + k0 + sseg * 8,
                &Bs[0][ch * 16][0]);
      }
      __syncthreads();
      domfma(0);
      __syncthreads();
    }
  }

  const int gm0 = by * 128 + wr, gn0 = bx * 128 + wc;
  #pragma unroll
  for (int i = 0; i < 4; i++){
    #pragma unroll
    for (int r = 0; r < 4; r++){
      int gm = gm0 + i * 16 + l4 * 4 + r;
      int orow = rowperm ? ((gm & 63) * 128 + (gm >> 6)) : gm;
      #pragma unroll
      for (int j = 0; j < 4; j++){
        int gn = gn0 + j * 16 + l15;
        float v = acc[i][j][r];
        if (bias) v += bias[gn];
        if (act)  v = v * (1.0f / (1.0f + expf(-1.702f * v)));  // QuickGELU
        if (addsrc) v += addsrc[(size_t)orow * N + gn];
        if (outbf16) ((u16*)C)[(size_t)orow * N + gn] = f2b(v);
        else         ((float*)C)[(size_t)orow * N + gn] = v;
      }
    }
  }
}

// ---- MFMA Perceiver attention: block=(bt,head), 4 waves x 16 q-rows ----
__global__ __launch_bounds__(256) void pattn_k(
    const u16* __restrict__ q, const u16* __restrict__ kvx,
    const u16* __restrict__ kvll, u16* __restrict__ o)
{
  __shared__ __align__(16) u16 Ks[64][72];
  __shared__ __align__(16) u16 Vs[64][72];
  __shared__ __align__(16) u16 Ps[64][72];
  const int blk = blockIdx.x;            // bt*8 + h
  const int hh = blk & 7, bt = blk >> 3;
  const int tt = bt & 7;
  const int tid = threadIdx.x;
  const int wv = tid >> 6, ln = tid & 63;
  const int l15 = ln & 15, lg = ln >> 4;
  const int i0 = wv * 16;
  const int sj = tid >> 2, sc = (tid & 3) * 16;

  bhalf8 qf[2];
  {
    const u16* qp = q + ((size_t)(tt * 64 + i0 + l15)) * 512 + hh * 64 + lg * 8;
    qf[0] = *(const bhalf8*)(qp);
    qf[1] = *(const bhalf8*)(qp + 32);
  }

  floatx4 sacc[20];
  #pragma unroll
  for (int t = 0; t < 20; t++) sacc[t] = (floatx4){0.f,0.f,0.f,0.f};

  for (int ch = 0; ch < 5; ++ch){
    const u16* src = (ch < 4)
        ? (kvx  + ((size_t)(bt * 256 + ch * 64 + sj)) * 1024 + hh * 64 + sc)
        : (kvll + ((size_t)(tt * 64 + sj)) * 1024 + hh * 64 + sc);
    u16x8 k0 = *(const u16x8*)(src);
    u16x8 k1 = *(const u16x8*)(src + 8);
    __syncthreads();
    *(u16x8*)(&Ks[sj][sc])     = k0;
    *(u16x8*)(&Ks[sj][sc + 8]) = k1;
    __syncthreads();
    #pragma unroll
    for (int jt = 0; jt < 4; jt++){
      bhalf8 kf0 = *(const bhalf8*)(&Ks[jt*16 + l15][lg*8]);
      bhalf8 kf1 = *(const bhalf8*)(&Ks[jt*16 + l15][32 + lg*8]);
      sacc[ch*4+jt] = __builtin_amdgcn_mfma_f32_16x16x32_bf16(qf[0], kf0, sacc[ch*4+jt], 0,0,0);
      sacc[ch*4+jt] = __builtin_amdgcn_mfma_f32_16x16x32_bf16(qf[1], kf1, sacc[ch*4+jt], 0,0,0);
    }
  }

  float inv_l[4];
  float mx[4];
  #pragma unroll
  for (int r = 0; r < 4; r++){
    float m = -1e30f;
    #pragma unroll
    for (int t = 0; t < 20; t++) m = fmaxf(m, sacc[t][r]);
    m = fmaxf(m, __shfl_xor(m, 1));
    m = fmaxf(m, __shfl_xor(m, 2));
    m = fmaxf(m, __shfl_xor(m, 4));
    m = fmaxf(m, __shfl_xor(m, 8));
    mx[r] = m;
  }
  #pragma unroll
  for (int r = 0; r < 4; r++){
    float s = 0.f;
    #pragma unroll
    for (int t = 0; t < 20; t++){
      float p = expf(0.125f * (sacc[t][r] - mx[r]));
      sacc[t][r] = p;
      s += p;
    }
    s += __shfl_xor(s, 1); s += __shfl_xor(s, 2);
    s += __shfl_xor(s, 4); s += __shfl_xor(s, 8);
    inv_l[r] = 1.0f / s;
  }

  floatx4 oacc[4];
  #pragma unroll
  for (int dt = 0; dt < 4; dt++) oacc[dt] = (floatx4){0.f,0.f,0.f,0.f};
  for (int ch = 0; ch < 5; ++ch){
    const u16* src = (ch < 4)
        ? (kvx  + ((size_t)(bt * 256 + ch * 64 + sj)) * 1024 + 512 + hh * 64 + sc)
        : (kvll + ((size_t)(tt * 64 + sj)) * 1024 + 512 + hh * 64 + sc);
    u16x8 v0 = *(const u16x8*)(src);
    u16x8 v1 = *(const u16x8*)(src + 8);
    __syncthreads();
    #pragma unroll
    for (int e = 0; e < 8; e++) Vs[sc + e][sj]     = v0[e];
    #pragma unroll
    for (int e = 0; e < 8; e++) Vs[sc + 8 + e][sj] = v1[e];
    #pragma unroll
    for (int jt = 0; jt < 4; jt++){
      #pragma unroll
      for (int r = 0; r < 4; r++)
        Ps[i0 + 4*lg + r][jt*16 + l15] = f2b(sacc[ch*4+jt][r]);
    }
    __syncthreads();
    #pragma unroll
    for (int kk = 0; kk < 2; kk++){
      bhalf8 pf = *(const bhalf8*)(&Ps[i0 + l15][kk*32 + lg*8]);
      #pragma unroll
      for (int dt = 0; dt < 4; dt++){
        bhalf8 vfr = *(const bhalf8*)(&Vs[dt*16 + l15][kk*32 + lg*8]);
        oacc[dt] = __builtin_amdgcn_mfma_f32_16x16x32_bf16(pf, vfr, oacc[dt], 0,0,0);
      }
    }
  }

  u16* op = o + ((size_t)(bt*64 + i0 + 4*lg)) * 512 + hh*64 + l15;
  #pragma unroll
  for (int dt = 0; dt < 4; dt++)
    #pragma unroll
    for (int r = 0; r < 4; r++)
      op[(size_t)r * 512 + dt*16] = f2b(oacc[dt][r] * inv_l[r]);
}

// ---- MFMA self-attention: block=(bt,head), 4 waves x 16 q-rows, 64 keys ----
__global__ __launch_bounds__(256) void sattn_k(
    const u16* __restrict__ qkv, u16* __restrict__ o2)
{
  __shared__ __align__(16) u16 Ks[64][72];
  __shared__ __align__(16) u16 Vs[64][72];
  __shared__ __align__(16) u16 Ps[64][72];
  const int blk = blockIdx.x;
  const int hh = blk % 12, bt = blk / 12;
  const int tid = threadIdx.x;
  const int wv = tid >> 6, ln = tid & 63;
  const int l15 = ln & 15, lg = ln >> 4;
  const int i0 = wv * 16;
  const int sj = tid >> 2, sc = (tid & 3) * 16;

  const u16* kp = qkv + ((size_t)sj * 128 + bt) * 2304 + 768 + hh * 64 + sc;
  u16x8 k0 = *(const u16x8*)(kp);
  u16x8 k1 = *(const u16x8*)(kp + 8);
  u16x8 v0 = *(const u16x8*)(kp + 768);
  u16x8 v1 = *(const u16x8*)(kp + 776);
  *(u16x8*)(&Ks[sj][sc])     = k0;
  *(u16x8*)(&Ks[sj][sc + 8]) = k1;
  #pragma unroll
  for (int e = 0; e < 8; e++) Vs[sc + e][sj]     = v0[e];
  #pragma unroll
  for (int e = 0; e < 8; e++) Vs[sc + 8 + e][sj] = v1[e];

  bhalf8 qf[2];
  {
    const u16* qp = qkv + ((size_t)(i0 + l15) * 128 + bt) * 2304 + hh * 64 + lg * 8;
    qf[0] = *(const bhalf8*)(qp);
    qf[1] = *(const bhalf8*)(qp + 32);
  }
  __syncthreads();

  floatx4 sacc[4];
  #pragma unroll
  for (int t = 0; t < 4; t++) sacc[t] = (floatx4){0.f,0.f,0.f,0.f};
  #pragma unroll
  for (int jt = 0; jt < 4; jt++){
    bhalf8 kf0 = *(const bhalf8*)(&Ks[jt*16 + l15][lg*8]);
    bhalf8 kf1 = *(const bhalf8*)(&Ks[jt*16 + l15][32 + lg*8]);
    sacc[jt] = __builtin_amdgcn_mfma_f32_16x16x32_bf16(qf[0], kf0, sacc[jt], 0,0,0);
    sacc[jt] = __builtin_amdgcn_mfma_f32_16x16x32_bf16(qf[1], kf1, sacc[jt], 0,0,0);
  }

  float inv_l[4];
  #pragma unroll
  for (int r = 0; r < 4; r++){
    float m = -1e30f;
    #pragma unroll
    for (int t = 0; t < 4; t++) m = fmaxf(m, sacc[t][r]);
    m = fmaxf(m, __shfl_xor(m, 1));
    m = fmaxf(m, __shfl_xor(m, 2));
    m = fmaxf(m, __shfl_xor(m, 4));
    m = fmaxf(m, __shfl_xor(m, 8));
    float s = 0.f;
    #pragma unroll
    for (int t = 0; t < 4; t++){
      float p = expf(0.125f * (sacc[t][r] - m));
      sacc[t][r] = p;
      s += p;
    }
    s += __shfl_xor(s, 1); s += __shfl_xor(s, 2);
    s += __shfl_xor(s, 4); s += __shfl_xor(s, 8);
    inv_l[r] = 1.0f / s;
  }

  #pragma unroll
  for (int jt = 0; jt < 4; jt++){
    #pragma unroll
    for (int r = 0; r < 4; r++)
      Ps[i0 + 4*lg + r][jt*16 + l15] = f2b(sacc[jt][r]);
  }
  __syncthreads();

  floatx4 oacc[4];
  #pragma unroll
  for (int dt = 0; dt < 4; dt++) oacc[dt] = (floatx4){0.f,0.f,0.f,0.f};
  #pragma unroll
  for (int kk = 0; kk < 2; kk++){
    bhalf8 pf = *(const bhalf8*)(&Ps[i0 + l15][kk*32 + lg*8]);
    #pragma unroll
    for (int dt = 0; dt < 4; dt++){
      bhalf8 vfr = *(const bhalf8*)(&Vs[dt*16 + l15][kk*32 + lg*8]);
      oacc[dt] = __builtin_amdgcn_mfma_f32_16x16x32_bf16(pf, vfr, oacc[dt], 0,0,0);
    }
  }

  u16* op = o2 + ((size_t)((i0 + 4*lg) * 128 + bt)) * 768 + hh*64 + l15;
  #pragma unroll
  for (int dt = 0; dt < 4; dt++)
    #pragma unroll
    for (int r = 0; r < 4; r++)
      op[(size_t)r * 128 * 768 + dt*16] = f2b(oacc[dt][r] * inv_l[r]);
}

extern "C" void kernel_launch(void* const* d_in, const int* in_sizes, int n_in,
                              void* d_out, int out_size, void* d_ws, size_t ws_size,
                              hipStream_t stream)
{
  const float* vf   = (const float*)d_in[0];
  const float* lat  = (const float*)d_in[1];
  const float* nl0g = (const float*)d_in[2];
  const float* nl0b = (const float*)d_in[3];
  const float* pmg  = (const float*)d_in[4];
  const float* pmb  = (const float*)d_in[5];
  const float* plg  = (const float*)d_in[6];
  const float* plb  = (const float*)d_in[7];
  const float* Wq   = (const float*)d_in[8];
  const float* Wkv  = (const float*)d_in[9];
  const float* Wo   = (const float*)d_in[10];
  const float* ln1g = (const float*)d_in[11];
  const float* ln1b = (const float*)d_in[12];
  const float* Wqkv = (const float*)d_in[13];
  const float* bqkv = (const float*)d_in[14];
  const float* Wout = (const float*)d_in[15];
  const float* bout = (const float*)d_in[16];
  const float* ln2g = (const float*)d_in[17];
  const float* ln2b = (const float*)d_in[18];
  const float* Wfc  = (const float*)d_in[19];
  const float* bfc  = (const float*)d_in[20];
  const float* Wpr  = (const float*)d_in[21];
  const float* bpr  = (const float*)d_in[22];

  // ---- ws layout: base high-water 104,857,600 B; optional xm at 117.4M ----
  char* ws = (char*)d_ws;
  u16*    kvx   = (u16*)(ws + 0);          // 67,108,864 (dead after pattn)
  u16*    qkvb  = (u16*)(ws + 0);          // 37,748,736 (dead after sattn)
  u16*    o2b   = (u16*)(ws + 37748736);   // 12,582,912 (dead after Wout gemm)
  u16*    hb    = (u16*)(ws + 0);          // 50,331,648
  u16*    WoT   = (u16*)(ws + 50331648);
  u16*    WqkvT = (u16*)(ws + 51118080);
  u16*    WoutT = (u16*)(ws + 54657024);
  u16*    WfcT  = (u16*)(ws + 55836672);
  u16*    WprT  = (u16*)(ws + 60555264);   // ends 65,273,856
  u16*    WqT   = (u16*)(ws + 67108864);
  u16*    WkvT  = (u16*)(ws + 67895296);   // ends 69,468,160
  float*  yb    = (float*)(ws + 67108864); // written after WqT/WkvT dead
  u16*    llb   = (u16*)(ws + 92274688);
  float2* stx   = (float2*)(ws + 93061120);
  u16*    qb    = (u16*)(ws + 93323264);
  u16*    kvll  = (u16*)(ws + 94371840);
  u16*    ob    = (u16*)(ws + 95420416);   // ends 103,809,024
  u16*    zb    = (u16*)(ws + 92274688);   // overlays ll..ob when dead
  u16*    xm    = (u16*)(ws + 117440512);  // 50,331,648, ends 167,772,160
  const bool use_xm = (ws_size >= 167772160ull);

  const float* nof = nullptr;
  const float2* nos = nullptr;

  hipLaunchKernelGGL(transp_k, dim3(384), dim3(256), 0, stream, Wq, WqT, 768, 512);
  hipLaunchKernelGGL(transp_k, dim3(768), dim3(256), 0, stream, Wkv, WkvT, 768, 1024);
  hipLaunchKernelGGL(ln_lat2_k, dim3(512), dim3(256), 0, stream,
                     lat, llb, nl0g, nl0b, plg, plb);
  hipLaunchKernelGGL(mgemm_k<0>, dim3(16), dim3(256), 0, stream,
                     (const void*)llb, WqT, (void*)qb, 512, 512, 768,
                     nof, 0, nof, 0, 1, nos, nof, nof);
  hipLaunchKernelGGL(mgemm_k<0>, dim3(32), dim3(256), 0, stream,
                     (const void*)llb, WkvT, (void*)kvll, 512, 1024, 768,
                     nof, 0, nof, 0, 1, nos, nof, nof);
  if (use_xm){
    hipLaunchKernelGGL(ln_x_k, dim3(32768), dim3(256), 0, stream, vf, xm, pmg, pmb);
    hipLaunchKernelGGL(mgemm_k<0>, dim3(2048), dim3(256), 0, stream,
                       (const void*)xm, WkvT, (void*)kvx, 32768, 1024, 768,
                       nof, 0, nof, 0, 1, nos, nof, nof);
  } else {
    hipLaunchKernelGGL(stats_x_k, dim3(32768), dim3(256), 0, stream, vf, stx);
    hipLaunchKernelGGL(mgemm_k<1>, dim3(2048), dim3(256), 0, stream,
                       (const void*)vf, WkvT, (void*)kvx, 32768, 1024, 768,
                       nof, 0, nof, 0, 1, stx, pmg, pmb);
  }
  hipLaunchKernelGGL(pattn_k, dim3(1024), dim3(256), 0, stream, qb, kvx, kvll, ob);
  hipLaunchKernelGGL(transp_k, dim3(384), dim3(256), 0, stream, Wo, WoT, 512, 768);
  hipLaunchKernelGGL(transp_k, dim3(1728), dim3(256), 0, stream, Wqkv, WqkvT, 768, 2304);
  hipLaunchKernelGGL(transp_k, dim3(576), dim3(256), 0, stream, Wout, WoutT, 768, 768);
  hipLaunchKernelGGL(transp_k, dim3(2304), dim3(256), 0, stream, Wfc, WfcT, 768, 3072);
  hipLaunchKernelGGL(transp_k, dim3(2304), dim3(256), 0, stream, Wpr, WprT, 3072, 768);
  hipLaunchKernelGGL(mgemm_k<0>, dim3(384), dim3(256), 0, stream,
                     (const void*)ob, WoT, (void*)yb, 8192, 768, 512,
                     nof, 0, nof, 1, 0, nos, nof, nof);
  hipLaunchKernelGGL(ln_f32_k, dim3(8192), dim3(256), 0, stream, yb, zb, ln1g, ln1b);
  hipLaunchKernelGGL(mgemm_k<0>, dim3(1152), dim3(256), 0, stream,
                     (const void*)zb, WqkvT, (void*)qkvb, 8192, 2304, 768,
                     bqkv, 0, nof, 0, 1, nos, nof, nof);
  hipLaunchKernelGGL(sattn_k, dim3(1536), dim3(256), 0, stream, qkvb, o2b);
  hipLaunchKernelGGL(mgemm_k<0>, dim3(384), dim3(256), 0, stream,
                     (const void*)o2b, WoutT, (void*)yb, 8192, 768, 768,
                     bout, 0, yb, 0, 0, nos, nof, nof);
  hipLaunchKernelGGL(ln_f32_k, dim3(8192), dim3(256), 0, stream, yb, zb, ln2g, ln2b);
  hipLaunchKernelGGL(mgemm_k<0>, dim3(1536), dim3(256), 0, stream,
                     (const void*)zb, WfcT, (void*)hb, 8192, 3072, 768,
                     bfc, 1, nof, 0, 1, nos, nof, nof);
  hipLaunchKernelGGL(mgemm_k<0>, dim3(384), dim3(256), 0, stream,
                     (const void*)hb, WprT, d_out, 8192, 768, 3072,
                     bpr, 0, yb, 0, 0, nos, nof, nof);
}